// Round 3
// baseline (9349.917 us; speedup 1.0000x reference)
//
#include <hip/hip_runtime.h>

#define NLK 65536
#define NN (NLK * 4)        // 262144 nodes
#define DYNF 32
#define STATF 8
#define GG 64
#define EUP 4194304
#define EIN 1048576
#define EFB 1048576

#define BROWS 512           // rows per bucket
#define BCAP 10240          // staged edges per bucket (mean 8192 for EUP, +22 sigma)

// ---- per-list offsets --------------------------------------------------
// norm/cnt space: [up: NN][inner: 4*NLK][fwd: 3*2NLK][bwd: 3*2NLK]
#define NS_UP    0
#define NS_IN(l) (NN + (l) * NLK)
#define NS_F(l)  (NN + 4 * NLK + (l) * 2 * NLK)
#define NS_B(l)  (NN + 10 * NLK + (l) * 2 * NLK)
#define NS_TOT   (NN + 16 * NLK)                        // 1,310,720

// row_ptr space (each list gets n+1)
#define RP_UP    0
#define RP_IN(l) ((NN + 1) + (l) * (NLK + 1))
#define RP_F(l)  ((NN + 1) + 4 * (NLK + 1) + (l) * (2 * NLK + 1))
#define RP_B(l)  ((NN + 1) + 4 * (NLK + 1) + 3 * (2 * NLK + 1) + (l) * (2 * NLK + 1))
#define RP_TOT   ((NN + 1) + 4 * (NLK + 1) + 6 * (2 * NLK + 1))

// col space
#define CO_UP    0
#define CO_IN(l) (EUP + (l) * EIN)
#define CO_F(l)  (EUP + 4 * EIN + (l) * EFB)
#define CO_B(l)  (EUP + 4 * EIN + 3 * EFB + (l) * EFB)
#define CO_TOT   (EUP + 4 * EIN + 6 * EFB)              // 14,680,064

#define NCUR (11 * 512)     // per-list cursor slices

static inline int cdiv(long a, int b) { return (int)((a + b - 1) / b); }

// ---- CSR build ---------------------------------------------------------

__global__ void fill_zero_kernel(int* p, int n) {
    int i = blockIdx.x * blockDim.x + threadIdx.x;
    if (i < n) p[i] = 0;
}

// Pass A: histogram (into cnt) + bucket-append packed (src<<9 | dst&511)
__global__ void bucket_a_kernel(const int* __restrict__ src, const int* __restrict__ dst, int E,
                                int* __restrict__ cnt, int* __restrict__ cursors,
                                int* __restrict__ staging) {
    int e = blockIdx.x * blockDim.x + threadIdx.x;
    if (e >= E) return;
    int d = dst[e];
    int s = src[e];
    atomicAdd(&cnt[d], 1);
    int b = d >> 9;
    int pos = atomicAdd(&cursors[b], 1);
    if (pos < BCAP) staging[(size_t)b * BCAP + pos] = (s << 9) | (d & (BROWS - 1));
}

// Pass B: one block per bucket; LDS slot counters; col write into bucket's range
__global__ void bucket_b_kernel(const int* __restrict__ staging, const int* __restrict__ cursors,
                                const int* __restrict__ rp, int* __restrict__ col) {
    __shared__ int lcnt[BROWS];
    int b = blockIdx.x;
    for (int i = threadIdx.x; i < BROWS; i += blockDim.x) lcnt[i] = 0;
    __syncthreads();
    int nb = cursors[b];
    if (nb > BCAP) nb = BCAP;
    const int* st = staging + (size_t)b * BCAP;
    for (int i = threadIdx.x; i < nb; i += blockDim.x) {
        int en = st[i];
        int dl = en & (BROWS - 1);
        int s = ((unsigned)en) >> 9;
        int slot = atomicAdd(&lcnt[dl], 1);
        col[rp[(b << 9) + dl] + slot] = s;
    }
}

// norm = rsqrt(cnt + 1)  (self-loop)
__global__ void norm_kernel(const int* __restrict__ cnt, float* __restrict__ norm, int n) {
    int i = blockIdx.x * blockDim.x + threadIdx.x;
    if (i < n) norm[i] = rsqrtf((float)(cnt[i] + 1));
}

// block-local exclusive scan (1024/block)
__global__ void scan1_kernel(const int* __restrict__ cnt, int* __restrict__ rp,
                             int* __restrict__ part, int n) {
    __shared__ int sh[1024];
    int t = threadIdx.x;
    int i = blockIdx.x * 1024 + t;
    int v = (i < n) ? cnt[i] : 0;
    sh[t] = v;
    __syncthreads();
    for (int off = 1; off < 1024; off <<= 1) {
        int u = (t >= off) ? sh[t - off] : 0;
        __syncthreads();
        sh[t] += u;
        __syncthreads();
    }
    if (i < n) rp[i] = sh[t] - v;
    if (t == 1023) part[blockIdx.x] = sh[1023];
}

__global__ void scan2_kernel(int* part, int m) {
    __shared__ int sh[256];
    int t = threadIdx.x;
    int v = (t < m) ? part[t] : 0;
    sh[t] = v;
    __syncthreads();
    for (int off = 1; off < 256; off <<= 1) {
        int u = (t >= off) ? sh[t - off] : 0;
        __syncthreads();
        sh[t] += u;
        __syncthreads();
    }
    if (t < m) part[t] = sh[t] - v;
}

__global__ void scan3_kernel(int* __restrict__ rp, const int* __restrict__ part, int n, int E) {
    int i = blockIdx.x * blockDim.x + threadIdx.x;
    if (i < n) rp[i] += part[i >> 10];
    if (i == 0) rp[n] = E;
}

// ---- conv --------------------------------------------------------------

// hs[r] = ((in_rows[r] ++ in_stat[r]) @ W) * norm[r]
__global__ void mm_scale_kernel(const float* __restrict__ in_rows, const float* __restrict__ in_stat,
                                const float* __restrict__ W, const float* __restrict__ norm,
                                float* __restrict__ hs, int nrows) {
    constexpr int FIN = DYNF + STATF;
    __shared__ float Ws[FIN * DYNF];
    for (int i = threadIdx.x; i < FIN * DYNF; i += blockDim.x) Ws[i] = W[i];
    __syncthreads();
    int r = blockIdx.x * blockDim.x + threadIdx.x;
    if (r >= nrows) return;
    float in[FIN];
    const float4* ip = (const float4*)(in_rows + (size_t)r * DYNF);
#pragma unroll
    for (int q = 0; q < DYNF / 4; q++) {
        float4 v = ip[q];
        in[q * 4 + 0] = v.x; in[q * 4 + 1] = v.y; in[q * 4 + 2] = v.z; in[q * 4 + 3] = v.w;
    }
    const float4* sp = (const float4*)(in_stat + (size_t)r * STATF);
#pragma unroll
    for (int q = 0; q < STATF / 4; q++) {
        float4 v = sp[q];
        in[DYNF + q * 4 + 0] = v.x; in[DYNF + q * 4 + 1] = v.y;
        in[DYNF + q * 4 + 2] = v.z; in[DYNF + q * 4 + 3] = v.w;
    }
    float o[DYNF];
#pragma unroll
    for (int j = 0; j < DYNF; j++) o[j] = 0.f;
#pragma unroll
    for (int k = 0; k < FIN; k++) {
        float a = in[k];
#pragma unroll
        for (int j = 0; j < DYNF; j++) o[j] = fmaf(a, Ws[k * DYNF + j], o[j]);
    }
    float nm = norm[r];
    float4* hp = (float4*)(hs + (size_t)r * DYNF);
#pragma unroll
    for (int q = 0; q < DYNF / 4; q++)
        hp[q] = make_float4(o[q * 4] * nm, o[q * 4 + 1] * nm, o[q * 4 + 2] * nm, o[q * 4 + 3] * nm);
}

// pull: out[r] = norm[r]*(hs[r] + sum_{e in row r} hs[col[e]]) + b   (8 thr/row)
__global__ void pull_kernel(const int* __restrict__ rp, const int* __restrict__ col,
                            const float* __restrict__ hs, const float* __restrict__ nrm,
                            const float* __restrict__ b, float* __restrict__ out,
                            int row_lo, int n_rows) {
    int tid = blockIdx.x * blockDim.x + threadIdx.x;
    int rr = tid >> 3;
    if (rr >= n_rows) return;
    int r = row_lo + rr;
    int q = (tid & 7) * 4;
    int e0 = rp[r], e1 = rp[r + 1];
    float4 acc = *(const float4*)(hs + (size_t)r * DYNF + q);   // self-loop
    for (int e = e0; e < e1; e++) {
        int s = col[e];
        float4 v = *(const float4*)(hs + (size_t)s * DYNF + q);
        acc.x += v.x; acc.y += v.y; acc.z += v.z; acc.w += v.w;
    }
    float nm = nrm[r];
    float4 bv = *(const float4*)(b + q);
    *(float4*)(out + (size_t)r * DYNF + q) =
        make_float4(fmaf(acc.x, nm, bv.x), fmaf(acc.y, nm, bv.y),
                    fmaf(acc.z, nm, bv.z), fmaf(acc.w, nm, bv.w));
}

// ---- up conv in 4-dim space --------------------------------------------

__global__ void xs_kernel(const float* __restrict__ x, const float* __restrict__ nrm,
                          float* __restrict__ xs, int n) {
    int r = blockIdx.x * blockDim.x + threadIdx.x;
    if (r >= n) return;
    float nm = nrm[r];
    float4 v = *(const float4*)(x + (size_t)r * 4);
    *(float4*)(xs + (size_t)r * 4) = make_float4(v.x * nm, v.y * nm, v.z * nm, v.w * nm);
}

__global__ void pull4_kernel(const int* __restrict__ rp, const int* __restrict__ col,
                             const float* __restrict__ xs, float* __restrict__ y, int n) {
    int r = blockIdx.x * blockDim.x + threadIdx.x;
    if (r >= n) return;
    int e0 = rp[r], e1 = rp[r + 1];
    float4 acc = *(const float4*)(xs + (size_t)r * 4);
    for (int e = e0; e < e1; e++) {
        int s = col[e];
        float4 v = *(const float4*)(xs + (size_t)s * 4);
        acc.x += v.x; acc.y += v.y; acc.z += v.z; acc.w += v.w;
    }
    *(float4*)(y + (size_t)r * 4) = acc;
}

// h[r] = norm[r]*(y[r] @ W_up) + b
__global__ void up_mm_kernel(const float* __restrict__ y, const float* __restrict__ W,
                             const float* __restrict__ nrm, const float* __restrict__ b,
                             float* __restrict__ h, int n) {
    __shared__ float Ws[4 * DYNF];
    __shared__ float bs[DYNF];
    for (int i = threadIdx.x; i < 4 * DYNF; i += blockDim.x) Ws[i] = W[i];
    for (int i = threadIdx.x; i < DYNF; i += blockDim.x) bs[i] = b[i];
    __syncthreads();
    int r = blockIdx.x * blockDim.x + threadIdx.x;
    if (r >= n) return;
    float4 v = *(const float4*)(y + (size_t)r * 4);
    float nm = nrm[r];
    float4* hp = (float4*)(h + (size_t)r * DYNF);
#pragma unroll
    for (int q = 0; q < DYNF / 4; q++) {
        float4 o;
        o.x = v.x * Ws[0 * DYNF + q * 4 + 0] + v.y * Ws[1 * DYNF + q * 4 + 0] +
              v.z * Ws[2 * DYNF + q * 4 + 0] + v.w * Ws[3 * DYNF + q * 4 + 0];
        o.y = v.x * Ws[0 * DYNF + q * 4 + 1] + v.y * Ws[1 * DYNF + q * 4 + 1] +
              v.z * Ws[2 * DYNF + q * 4 + 1] + v.w * Ws[3 * DYNF + q * 4 + 1];
        o.z = v.x * Ws[0 * DYNF + q * 4 + 2] + v.y * Ws[1 * DYNF + q * 4 + 2] +
              v.z * Ws[2 * DYNF + q * 4 + 2] + v.w * Ws[3 * DYNF + q * 4 + 2];
        o.w = v.x * Ws[0 * DYNF + q * 4 + 3] + v.y * Ws[1 * DYNF + q * 4 + 3] +
              v.z * Ws[2 * DYNF + q * 4 + 3] + v.w * Ws[3 * DYNF + q * 4 + 3];
        hp[q] = make_float4(fmaf(o.x, nm, bs[q * 4 + 0]), fmaf(o.y, nm, bs[q * 4 + 1]),
                            fmaf(o.z, nm, bs[q * 4 + 2]), fmaf(o.w, nm, bs[q * 4 + 3]));
    }
}

// ---- misc --------------------------------------------------------------

__global__ void relu_kernel(float* h, int n) {
    int i = blockIdx.x * blockDim.x + threadIdx.x;
    if (i < n) h[i] = fmaxf(h[i], 0.f);
}

__global__ void init_out_kernel(float* out, const float* __restrict__ lin_b) {
    int i = threadIdx.x;
    if (i < GG) out[i] = lin_b[0];
}

__global__ void pool_kernel(const float* __restrict__ h, const int* __restrict__ gids,
                            const float* __restrict__ linW, float* out) {
    __shared__ float part[GG];
    int t = threadIdx.x;
    if (t < GG) part[t] = 0.f;
    __syncthreads();
    int r = blockIdx.x * blockDim.x + t;
    float dotv = 0.f;
    const float4* hp = (const float4*)(h + (size_t)r * DYNF);
#pragma unroll
    for (int q = 0; q < 8; q++) {
        float4 v = hp[q];
        dotv += v.x * linW[q * 4 + 0] + v.y * linW[q * 4 + 1] +
                v.z * linW[q * 4 + 2] + v.w * linW[q * 4 + 3];
    }
    atomicAdd(&part[gids[r]], dotv);
    __syncthreads();
    if (t < GG) unsafeAtomicAdd(&out[t], part[t]);
}

// ------------------------------------------------------------------------

extern "C" void kernel_launch(void* const* d_in, const int* in_sizes, int n_in,
                              void* d_out, int out_size, void* d_ws, size_t ws_size,
                              hipStream_t stream) {
    const float* x     = (const float*)d_in[0];
    const float* stat  = (const float*)d_in[1];
    const int*   e_up  = (const int*)d_in[2];
    const int*   e_in  = (const int*)d_in[3];
    const int*   e_f   = (const int*)d_in[4];
    const int*   e_b   = (const int*)d_in[5];
    const int*   gids  = (const int*)d_in[6];
    const float* W_up  = (const float*)d_in[7];
    const float* b_up  = (const float*)d_in[8];
    const float* W_in  = (const float*)d_in[9];
    const float* b_in  = (const float*)d_in[10];
    const float* W_f   = (const float*)d_in[11];
    const float* b_f   = (const float*)d_in[12];
    const float* W_b   = (const float*)d_in[13];
    const float* b_b   = (const float*)d_in[14];
    const float* lin_W = (const float*)d_in[15];
    const float* lin_b = (const float*)d_in[16];
    float* out = (float*)d_out;

    // workspace carve (~155 MB)
    float* h      = (float*)d_ws;                       // NN*32
    float* hs_win = h + (size_t)NN * DYNF;              // 2*NLK*32
    float* xs     = hs_win + (size_t)2 * NLK * DYNF;    // NN*4
    float* y4     = xs + (size_t)NN * 4;                // NN*4
    float* norms  = y4 + (size_t)NN * 4;                // NS_TOT
    int*   cnt    = (int*)(norms + NS_TOT);             // NS_TOT
    int*   cursors= cnt + NS_TOT;                       // 11*512
    int*   rp     = cursors + NCUR;                     // RP_TOT
    int*   col    = rp + RP_TOT;                        // CO_TOT
    int*   staging= col + CO_TOT;                       // 512*BCAP
    int*   part   = staging + (size_t)512 * BCAP;       // 256

    // ---- describe the 11 distinct edge lists ----
    struct ListDesc { const int* src; const int* dst; int E; int n; int ns; int rpo; int co; };
    ListDesc LD[11];
    LD[0] = { e_up, e_up + EUP, EUP, NN, NS_UP, RP_UP, CO_UP };
    for (int l = 0; l < 4; l++)
        LD[1 + l] = { e_in + (size_t)(l * 2) * EIN, e_in + (size_t)(l * 2 + 1) * EIN,
                      EIN, NLK, NS_IN(l), RP_IN(l), CO_IN(l) };
    for (int l = 0; l < 3; l++)
        LD[5 + l] = { e_f + (size_t)(l * 2) * EFB, e_f + (size_t)(l * 2 + 1) * EFB,
                      EFB, 2 * NLK, NS_F(l), RP_F(l), CO_F(l) };
    for (int l = 0; l < 3; l++)
        LD[8 + l] = { e_b + (size_t)(l * 2) * EFB, e_b + (size_t)(l * 2 + 1) * EFB,
                      EFB, 2 * NLK, NS_B(l), RP_B(l), CO_B(l) };

    // ---- CSR build (bucketed 2-pass, once per launch) ----
    fill_zero_kernel<<<cdiv(NS_TOT + NCUR, 256), 256, 0, stream>>>(cnt, NS_TOT + NCUR);
    for (int i = 0; i < 11; i++) {
        int nbuck = LD[i].n / BROWS;
        int* cur = cursors + i * 512;
        bucket_a_kernel<<<cdiv(LD[i].E, 256), 256, 0, stream>>>(
            LD[i].src, LD[i].dst, LD[i].E, cnt + LD[i].ns, cur, staging);
        int nb = cdiv(LD[i].n, 1024);
        scan1_kernel<<<nb, 1024, 0, stream>>>(cnt + LD[i].ns, rp + LD[i].rpo, part, LD[i].n);
        scan2_kernel<<<1, 256, 0, stream>>>(part, nb);
        scan3_kernel<<<cdiv(LD[i].n, 256), 256, 0, stream>>>(rp + LD[i].rpo, part, LD[i].n, LD[i].E);
        bucket_b_kernel<<<nbuck, 256, 0, stream>>>(staging, cur, rp + LD[i].rpo, col + LD[i].co);
    }
    norm_kernel<<<cdiv(NS_TOT, 256), 256, 0, stream>>>(cnt, norms, NS_TOT);

    // ---- conv driver (non-up convs) ----
    auto conv = [&](const float* in_rows, const float* in_stat, const float* W,
                    const float* b, int li, int gbase, int nwin, int row_lo, int n_pull) {
        float* outw = h + (size_t)gbase * DYNF;
        const float* nrm = norms + LD[li].ns;
        mm_scale_kernel<<<cdiv(nwin, 256), 256, 0, stream>>>(in_rows, in_stat, W, nrm, hs_win, nwin);
        pull_kernel<<<cdiv((long)n_pull * 8, 256), 256, 0, stream>>>(
            rp + LD[li].rpo, col + LD[li].co, hs_win, nrm, b, outw, row_lo, n_pull);
    };

    auto inner = [&](int l) {
        int s = l * NLK;
        conv(h + (size_t)s * DYNF, stat + (size_t)s * STATF, W_in, b_in, 1 + l, s, NLK, 0, NLK);
    };
    auto fwd = [&](int l) {
        int s = l * NLK;
        conv(h + (size_t)s * DYNF, stat + (size_t)s * STATF, W_f, b_f, 5 + l, s, 2 * NLK, NLK, NLK);
    };
    auto bwd = [&](int lm1) {
        int s = lm1 * NLK;
        conv(h + (size_t)s * DYNF, stat + (size_t)s * STATF, W_b, b_b, 8 + lm1, s, 2 * NLK, 0, NLK);
    };

    // ---- up conv in 4-dim space: xs = x*norm; y = pull(xs); h = norm*(y@W)+b ----
    xs_kernel<<<cdiv(NN, 256), 256, 0, stream>>>(x, norms + NS_UP, xs, NN);
    pull4_kernel<<<cdiv(NN, 256), 256, 0, stream>>>(rp + RP_UP, col + CO_UP, xs, y4, NN);
    up_mm_kernel<<<cdiv(NN, 256), 256, 0, stream>>>(y4, W_up, norms + NS_UP, b_up, h, NN);

    for (int p = 0; p < 2; p++) {
        for (int l = 0; l < 4; l++) {
            inner(l);
            if (l < 3) fwd(l);
        }
        relu_kernel<<<cdiv((long)NN * DYNF, 256), 256, 0, stream>>>(h, NN * DYNF);
        for (int l = 3; l >= 1; l--) {
            bwd(l - 1);
            inner(l - 1);
        }
        relu_kernel<<<cdiv((long)NN * DYNF, 256), 256, 0, stream>>>(h, NN * DYNF);
    }

    init_out_kernel<<<1, 64, 0, stream>>>(out, lin_b);
    pool_kernel<<<NN / 256, 256, 0, stream>>>(h, gids, lin_W, out);
}

// Round 4
// 3124.614 us; speedup vs baseline: 2.9923x; 2.9923x over previous
//
#include <hip/hip_runtime.h>

#define NLK 65536
#define NN (NLK * 4)        // 262144 nodes
#define DYNF 32
#define STATF 8
#define GG 64
#define EUP 4194304
#define EIN 1048576
#define EFB 1048576

// cnt/norm space: [up: NN][inner: 4*NLK][fwd: 3*2NLK][bwd: 3*2NLK]
#define NS_UP    0
#define NS_IN(l) (NN + (l) * NLK)
#define NS_F(l)  (NN + 4 * NLK + (l) * 2 * NLK)
#define NS_B(l)  (NN + 10 * NLK + (l) * 2 * NLK)
#define NS_TOT   (NN + 16 * NLK)                    // 1,310,720

// head space (small lists only): [inner 4*NLK][fwd 3*2NLK][bwd 3*2NLK]
#define HD_IN(l) ((l) * NLK)
#define HD_F(l)  (4 * NLK + (l) * 2 * NLK)
#define HD_B(l)  (10 * NLK + (l) * 2 * NLK)
#define HD_TOT   (16 * NLK)                         // 1,048,576

// node space (int2 per edge, small lists only)
#define ND_IN(l) ((size_t)(l) * EIN)
#define ND_F(l)  ((size_t)4 * EIN + (size_t)(l) * EFB)
#define ND_B(l)  ((size_t)4 * EIN + (size_t)3 * EFB + (size_t)(l) * EFB)
#define ND_TOT   ((size_t)4 * EIN + (size_t)6 * EFB)   // 10,485,760

static inline int cdiv(long a, int b) { return (int)((a + b - 1) / b); }

// ---- build: fused histogram + linked-list chain (one pass per list) ----

__global__ void build_kernel(const int* __restrict__ src, const int* __restrict__ dst, int E,
                             int* __restrict__ cnt, int* __restrict__ head,
                             int2* __restrict__ node) {
    int e = blockIdx.x * blockDim.x + threadIdx.x;
    if (e >= E) return;
    int d = dst[e];
    int s = src[e];
    atomicAdd(&cnt[d], 1);
    int old = atomicExch(&head[d], e);
    node[e] = make_int2(s, old);
}

__global__ void hist_kernel(const int* __restrict__ dst, int E, int* __restrict__ cnt) {
    int i = blockIdx.x * blockDim.x + threadIdx.x;
    if (i < E) atomicAdd(&cnt[dst[i]], 1);
}

// norm = rsqrt(cnt + 1), in place (int -> float)
__global__ void norm_kernel(int* __restrict__ cntnorm, int n) {
    int i = blockIdx.x * blockDim.x + threadIdx.x;
    if (i < n) {
        int c = cntnorm[i];
        ((float*)cntnorm)[i] = rsqrtf((float)(c + 1));
    }
}

// ---- conv: dense row transform -----------------------------------------

// hs[r] = ((in_rows[r] ++ in_stat[r]) @ W) * norm[r]
__global__ void mm_scale_kernel(const float* __restrict__ in_rows, const float* __restrict__ in_stat,
                                const float* __restrict__ W, const float* __restrict__ norm,
                                float* __restrict__ hs, int nrows) {
    constexpr int FIN = DYNF + STATF;
    __shared__ float Ws[FIN * DYNF];
    for (int i = threadIdx.x; i < FIN * DYNF; i += blockDim.x) Ws[i] = W[i];
    __syncthreads();
    int r = blockIdx.x * blockDim.x + threadIdx.x;
    if (r >= nrows) return;
    float in[FIN];
    const float4* ip = (const float4*)(in_rows + (size_t)r * DYNF);
#pragma unroll
    for (int q = 0; q < DYNF / 4; q++) {
        float4 v = ip[q];
        in[q * 4 + 0] = v.x; in[q * 4 + 1] = v.y; in[q * 4 + 2] = v.z; in[q * 4 + 3] = v.w;
    }
    const float4* sp = (const float4*)(in_stat + (size_t)r * STATF);
#pragma unroll
    for (int q = 0; q < STATF / 4; q++) {
        float4 v = sp[q];
        in[DYNF + q * 4 + 0] = v.x; in[DYNF + q * 4 + 1] = v.y;
        in[DYNF + q * 4 + 2] = v.z; in[DYNF + q * 4 + 3] = v.w;
    }
    float o[DYNF];
#pragma unroll
    for (int j = 0; j < DYNF; j++) o[j] = 0.f;
#pragma unroll
    for (int k = 0; k < FIN; k++) {
        float a = in[k];
#pragma unroll
        for (int j = 0; j < DYNF; j++) o[j] = fmaf(a, Ws[k * DYNF + j], o[j]);
    }
    float nm = norm[r];
    float4* hp = (float4*)(hs + (size_t)r * DYNF);
#pragma unroll
    for (int q = 0; q < DYNF / 4; q++)
        hp[q] = make_float4(o[q * 4] * nm, o[q * 4 + 1] * nm, o[q * 4 + 2] * nm, o[q * 4 + 3] * nm);
}

// ---- pull via chain traversal: 4 threads/row, 8 floats each ------------
// out[r] = norm[r]*(hs[r] + sum_chain hs[src]) + b

__global__ void pull_chain_kernel(const int* __restrict__ head, const int2* __restrict__ node,
                                  const float* __restrict__ hs, const float* __restrict__ nrm,
                                  const float* __restrict__ b, float* __restrict__ out,
                                  int row_lo, int n_rows) {
    int tid = blockIdx.x * blockDim.x + threadIdx.x;
    int rr = tid >> 2;
    if (rr >= n_rows) return;
    int r = row_lo + rr;
    int q = (tid & 3) * 8;
    const float4* selfp = (const float4*)(hs + (size_t)r * DYNF + q);
    float4 a0 = selfp[0];
    float4 a1 = selfp[1];
    int e = head[r];
    int2 nd = make_int2(0, -1);
    if (e >= 0) nd = node[e];
    while (e >= 0) {
        int s = nd.x;
        int en = nd.y;
        int2 ndn = make_int2(0, -1);
        if (en >= 0) ndn = node[en];            // prefetch next hop
        const float4* rp = (const float4*)(hs + (size_t)s * DYNF + q);
        float4 v0 = rp[0];
        float4 v1 = rp[1];
        a0.x += v0.x; a0.y += v0.y; a0.z += v0.z; a0.w += v0.w;
        a1.x += v1.x; a1.y += v1.y; a1.z += v1.z; a1.w += v1.w;
        e = en;
        nd = ndn;
    }
    float nm = nrm[r];
    float4 b0 = *(const float4*)(b + q);
    float4 b1 = *(const float4*)(b + q + 4);
    float4* op = (float4*)(out + (size_t)r * DYNF + q);
    op[0] = make_float4(fmaf(a0.x, nm, b0.x), fmaf(a0.y, nm, b0.y),
                        fmaf(a0.z, nm, b0.z), fmaf(a0.w, nm, b0.w));
    op[1] = make_float4(fmaf(a1.x, nm, b1.x), fmaf(a1.y, nm, b1.y),
                        fmaf(a1.z, nm, b1.z), fmaf(a1.w, nm, b1.w));
}

// ---- up conv in 4-dim space (push atomics, no CSR) ---------------------

// xs[r] = y4[r] = x[r]*norm[r]   (y4 init = self-loop term)
__global__ void xs_y4_kernel(const float* __restrict__ x, const float* __restrict__ nrm,
                             float* __restrict__ xs, float* __restrict__ y4, int n) {
    int r = blockIdx.x * blockDim.x + threadIdx.x;
    if (r >= n) return;
    float nm = nrm[r];
    float4 v = *(const float4*)(x + (size_t)r * 4);
    float4 w = make_float4(v.x * nm, v.y * nm, v.z * nm, v.w * nm);
    *(float4*)(xs + (size_t)r * 4) = w;
    *(float4*)(y4 + (size_t)r * 4) = w;
}

__global__ void push4_kernel(const int* __restrict__ src, const int* __restrict__ dst, int E,
                             const float* __restrict__ xs, float* y) {
    int e = blockIdx.x * blockDim.x + threadIdx.x;
    if (e >= E) return;
    int s = src[e];
    int d = dst[e];
    float4 v = *(const float4*)(xs + (size_t)s * 4);
    float* a = y + (size_t)d * 4;
    unsafeAtomicAdd(a + 0, v.x);
    unsafeAtomicAdd(a + 1, v.y);
    unsafeAtomicAdd(a + 2, v.z);
    unsafeAtomicAdd(a + 3, v.w);
}

// h[r] = norm[r]*(y[r] @ W_up) + b
__global__ void up_mm_kernel(const float* __restrict__ y, const float* __restrict__ W,
                             const float* __restrict__ nrm, const float* __restrict__ b,
                             float* __restrict__ h, int n) {
    __shared__ float Ws[4 * DYNF];
    __shared__ float bs[DYNF];
    for (int i = threadIdx.x; i < 4 * DYNF; i += blockDim.x) Ws[i] = W[i];
    for (int i = threadIdx.x; i < DYNF; i += blockDim.x) bs[i] = b[i];
    __syncthreads();
    int r = blockIdx.x * blockDim.x + threadIdx.x;
    if (r >= n) return;
    float4 v = *(const float4*)(y + (size_t)r * 4);
    float nm = nrm[r];
    float4* hp = (float4*)(h + (size_t)r * DYNF);
#pragma unroll
    for (int q = 0; q < DYNF / 4; q++) {
        float4 o;
        o.x = v.x * Ws[0 * DYNF + q * 4 + 0] + v.y * Ws[1 * DYNF + q * 4 + 0] +
              v.z * Ws[2 * DYNF + q * 4 + 0] + v.w * Ws[3 * DYNF + q * 4 + 0];
        o.y = v.x * Ws[0 * DYNF + q * 4 + 1] + v.y * Ws[1 * DYNF + q * 4 + 1] +
              v.z * Ws[2 * DYNF + q * 4 + 1] + v.w * Ws[3 * DYNF + q * 4 + 1];
        o.z = v.x * Ws[0 * DYNF + q * 4 + 2] + v.y * Ws[1 * DYNF + q * 4 + 2] +
              v.z * Ws[2 * DYNF + q * 4 + 2] + v.w * Ws[3 * DYNF + q * 4 + 2];
        o.w = v.x * Ws[0 * DYNF + q * 4 + 3] + v.y * Ws[1 * DYNF + q * 4 + 3] +
              v.z * Ws[2 * DYNF + q * 4 + 3] + v.w * Ws[3 * DYNF + q * 4 + 3];
        hp[q] = make_float4(fmaf(o.x, nm, bs[q * 4 + 0]), fmaf(o.y, nm, bs[q * 4 + 1]),
                            fmaf(o.z, nm, bs[q * 4 + 2]), fmaf(o.w, nm, bs[q * 4 + 3]));
    }
}

// ---- misc --------------------------------------------------------------

__global__ void relu_kernel(float* h, int n) {
    int i = blockIdx.x * blockDim.x + threadIdx.x;
    if (i < n) h[i] = fmaxf(h[i], 0.f);
}

__global__ void init_out_kernel(float* out, const float* __restrict__ lin_b) {
    int i = threadIdx.x;
    if (i < GG) out[i] = lin_b[0];
}

__global__ void pool_kernel(const float* __restrict__ h, const int* __restrict__ gids,
                            const float* __restrict__ linW, float* out) {
    __shared__ float part[GG];
    int t = threadIdx.x;
    if (t < GG) part[t] = 0.f;
    __syncthreads();
    int r = blockIdx.x * blockDim.x + t;
    float dotv = 0.f;
    const float4* hp = (const float4*)(h + (size_t)r * DYNF);
#pragma unroll
    for (int q = 0; q < 8; q++) {
        float4 v = hp[q];
        dotv += v.x * linW[q * 4 + 0] + v.y * linW[q * 4 + 1] +
                v.z * linW[q * 4 + 2] + v.w * linW[q * 4 + 3];
    }
    atomicAdd(&part[gids[r]], dotv);
    __syncthreads();
    if (t < GG) unsafeAtomicAdd(&out[t], part[t]);
}

// ------------------------------------------------------------------------

extern "C" void kernel_launch(void* const* d_in, const int* in_sizes, int n_in,
                              void* d_out, int out_size, void* d_ws, size_t ws_size,
                              hipStream_t stream) {
    const float* x     = (const float*)d_in[0];
    const float* stat  = (const float*)d_in[1];
    const int*   e_up  = (const int*)d_in[2];
    const int*   e_in  = (const int*)d_in[3];
    const int*   e_f   = (const int*)d_in[4];
    const int*   e_b   = (const int*)d_in[5];
    const int*   gids  = (const int*)d_in[6];
    const float* W_up  = (const float*)d_in[7];
    const float* b_up  = (const float*)d_in[8];
    const float* W_in  = (const float*)d_in[9];
    const float* b_in  = (const float*)d_in[10];
    const float* W_f   = (const float*)d_in[11];
    const float* b_f   = (const float*)d_in[12];
    const float* W_b   = (const float*)d_in[13];
    const float* b_b   = (const float*)d_in[14];
    const float* lin_W = (const float*)d_in[15];
    const float* lin_b = (const float*)d_in[16];
    float* out = (float*)d_out;

    // workspace carve (~144 MB)
    float* h      = (float*)d_ws;                        // NN*32 floats
    float* hs_win = h + (size_t)NN * DYNF;               // 2*NLK*32 floats
    float* xs     = hs_win;                              // alias (up phase only)
    float* y4     = hs_win + (size_t)NN * 4;             // alias (up phase only)
    int*   cnt    = (int*)(hs_win + (size_t)2 * NLK * DYNF); // NS_TOT (norms in place)
    float* norms  = (float*)cnt;
    int*   head   = cnt + NS_TOT;                        // HD_TOT
    int2*  node   = (int2*)(head + HD_TOT);              // ND_TOT int2

    // ---- build: memset + one fused pass per list ----
    hipMemsetAsync(cnt, 0, (size_t)NS_TOT * 4, stream);
    hipMemsetAsync(head, 0xFF, (size_t)HD_TOT * 4, stream);   // head = -1

    for (int l = 0; l < 4; l++)
        build_kernel<<<cdiv(EIN, 256), 256, 0, stream>>>(
            e_in + (size_t)(l * 2) * EIN, e_in + (size_t)(l * 2 + 1) * EIN, EIN,
            cnt + NS_IN(l), head + HD_IN(l), node + ND_IN(l));
    for (int l = 0; l < 3; l++)
        build_kernel<<<cdiv(EFB, 256), 256, 0, stream>>>(
            e_f + (size_t)(l * 2) * EFB, e_f + (size_t)(l * 2 + 1) * EFB, EFB,
            cnt + NS_F(l), head + HD_F(l), node + ND_F(l));
    for (int l = 0; l < 3; l++)
        build_kernel<<<cdiv(EFB, 256), 256, 0, stream>>>(
            e_b + (size_t)(l * 2) * EFB, e_b + (size_t)(l * 2 + 1) * EFB, EFB,
            cnt + NS_B(l), head + HD_B(l), node + ND_B(l));
    hist_kernel<<<cdiv(EUP, 256), 256, 0, stream>>>(e_up + EUP, EUP, cnt + NS_UP);

    norm_kernel<<<cdiv(NS_TOT, 256), 256, 0, stream>>>(cnt, NS_TOT);

    // ---- up conv in 4-dim space: xs = x*norm; y4 = xs + push(xs); h = norm*(y4@W)+b ----
    xs_y4_kernel<<<cdiv(NN, 256), 256, 0, stream>>>(x, norms + NS_UP, xs, y4, NN);
    push4_kernel<<<cdiv(EUP, 256), 256, 0, stream>>>(e_up, e_up + EUP, EUP, xs, y4);
    up_mm_kernel<<<cdiv(NN, 256), 256, 0, stream>>>(y4, W_up, norms + NS_UP, b_up, h, NN);

    // ---- window conv driver ----
    auto conv = [&](const float* in_rows, const float* in_stat, const float* W,
                    const float* bias, int ns, int hd, size_t ndo,
                    int gbase, int nwin, int row_lo, int n_pull) {
        mm_scale_kernel<<<cdiv(nwin, 256), 256, 0, stream>>>(
            in_rows, in_stat, W, norms + ns, hs_win, nwin);
        pull_chain_kernel<<<cdiv((long)n_pull * 4, 256), 256, 0, stream>>>(
            head + hd, node + ndo, hs_win, norms + ns, bias,
            h + (size_t)gbase * DYNF, row_lo, n_pull);
    };

    auto inner = [&](int l) {
        int s = l * NLK;
        conv(h + (size_t)s * DYNF, stat + (size_t)s * STATF, W_in, b_in,
             NS_IN(l), HD_IN(l), ND_IN(l), s, NLK, 0, NLK);
    };
    auto fwd = [&](int l) {
        int s = l * NLK;
        conv(h + (size_t)s * DYNF, stat + (size_t)s * STATF, W_f, b_f,
             NS_F(l), HD_F(l), ND_F(l), s, 2 * NLK, NLK, NLK);
    };
    auto bwd = [&](int lm1) {
        int s = lm1 * NLK;
        conv(h + (size_t)s * DYNF, stat + (size_t)s * STATF, W_b, b_b,
             NS_B(lm1), HD_B(lm1), ND_B(lm1), s, 2 * NLK, 0, NLK);
    };

    for (int p = 0; p < 2; p++) {
        for (int l = 0; l < 4; l++) {
            inner(l);
            if (l < 3) fwd(l);
        }
        relu_kernel<<<cdiv((long)NN * DYNF, 256), 256, 0, stream>>>(h, NN * DYNF);
        for (int l = 3; l >= 1; l--) {
            bwd(l - 1);
            inner(l - 1);
        }
        relu_kernel<<<cdiv((long)NN * DYNF, 256), 256, 0, stream>>>(h, NN * DYNF);
    }

    init_out_kernel<<<1, 64, 0, stream>>>(out, lin_b);
    pool_kernel<<<NN / 256, 256, 0, stream>>>(h, gids, lin_W, out);
}

// Round 5
// 2820.291 us; speedup vs baseline: 3.3152x; 1.1079x over previous
//
#include <hip/hip_runtime.h>

#define NLK 65536
#define NN (NLK * 4)        // 262144 nodes
#define DYNF 32
#define STATF 8
#define GG 64
#define EUP 4194304
#define EIN 1048576
#define EFB 1048576

// cnt/norm/head space: [up: NN][inner: 4*NLK][fwd: 3*2NLK][bwd: 3*2NLK]
#define NS_UP    0
#define NS_IN(l) (NN + (l) * NLK)
#define NS_F(l)  (NN + 4 * NLK + (l) * 2 * NLK)
#define NS_B(l)  (NN + 10 * NLK + (l) * 2 * NLK)
#define NS_TOT   (NN + 16 * NLK)                    // 1,310,720

// row_ptr space (each list gets n+1)
#define RP_UP    0
#define RP_IN(l) ((NN + 1) + (l) * (NLK + 1))
#define RP_F(l)  ((NN + 1) + 4 * (NLK + 1) + (l) * (2 * NLK + 1))
#define RP_B(l)  ((NN + 1) + 4 * (NLK + 1) + 3 * (2 * NLK + 1) + (l) * (2 * NLK + 1))
#define RP_TOT   ((NN + 1) + 4 * (NLK + 1) + 6 * (2 * NLK + 1))

// col space
#define CO_UP    0
#define CO_IN(l) (EUP + (l) * EIN)
#define CO_F(l)  (EUP + 4 * EIN + (l) * EFB)
#define CO_B(l)  (EUP + 4 * EIN + 3 * EFB + (l) * EFB)
#define CO_TOT   (EUP + 4 * EIN + 6 * EFB)          // 14,680,064

static inline int cdiv(long a, int b) { return (int)((a + b - 1) / b); }

// ---- build: fused histogram + linked-list chain (one pass per list) ----

__global__ void build_kernel(const int* __restrict__ src, const int* __restrict__ dst, int E,
                             int* __restrict__ cnt, int* __restrict__ head,
                             int2* __restrict__ node) {
    int e = blockIdx.x * blockDim.x + threadIdx.x;
    if (e >= E) return;
    int d = dst[e];
    int s = src[e];
    atomicAdd(&cnt[d], 1);
    int old = atomicExch(&head[d], e);
    node[e] = make_int2(s, old);
}

// walk chain, write col[rp[r]..] contiguously (full-line writes, no amplification)
__global__ void walk_kernel(const int* __restrict__ head, const int2* __restrict__ node,
                            const int* __restrict__ rp, int* __restrict__ col, int nrows) {
    int r = blockIdx.x * blockDim.x + threadIdx.x;
    if (r >= nrows) return;
    int e = head[r];
    int p = rp[r];
    while (e >= 0) {
        int2 nd = node[e];
        col[p++] = nd.x;
        e = nd.y;
    }
}

// norm = rsqrt(cnt + 1), in place (int -> float)
__global__ void norm_kernel(int* __restrict__ cntnorm, int n) {
    int i = blockIdx.x * blockDim.x + threadIdx.x;
    if (i < n) {
        int c = cntnorm[i];
        ((float*)cntnorm)[i] = rsqrtf((float)(c + 1));
    }
}

// ---- scans (rp = exclusive prefix of cnt) ------------------------------

__global__ void scan1_kernel(const int* __restrict__ cnt, int* __restrict__ rp,
                             int* __restrict__ part, int n) {
    __shared__ int sh[1024];
    int t = threadIdx.x;
    int i = blockIdx.x * 1024 + t;
    int v = (i < n) ? cnt[i] : 0;
    sh[t] = v;
    __syncthreads();
    for (int off = 1; off < 1024; off <<= 1) {
        int u = (t >= off) ? sh[t - off] : 0;
        __syncthreads();
        sh[t] += u;
        __syncthreads();
    }
    if (i < n) rp[i] = sh[t] - v;
    if (t == 1023) part[blockIdx.x] = sh[1023];
}

__global__ void scan2_kernel(int* part, int m) {
    __shared__ int sh[256];
    int t = threadIdx.x;
    int v = (t < m) ? part[t] : 0;
    sh[t] = v;
    __syncthreads();
    for (int off = 1; off < 256; off <<= 1) {
        int u = (t >= off) ? sh[t - off] : 0;
        __syncthreads();
        sh[t] += u;
        __syncthreads();
    }
    if (t < m) part[t] = sh[t] - v;
}

__global__ void scan3_kernel(int* __restrict__ rp, const int* __restrict__ part, int n, int E) {
    int i = blockIdx.x * blockDim.x + threadIdx.x;
    if (i < n) rp[i] += part[i >> 10];
    if (i == 0) rp[n] = E;
}

// ---- conv: dense row transform -----------------------------------------

// hs[r] = ((in_rows[r] ++ in_stat[r]) @ W) * norm[r]
__global__ void mm_scale_kernel(const float* __restrict__ in_rows, const float* __restrict__ in_stat,
                                const float* __restrict__ W, const float* __restrict__ norm,
                                float* __restrict__ hs, int nrows) {
    constexpr int FIN = DYNF + STATF;
    __shared__ float Ws[FIN * DYNF];
    for (int i = threadIdx.x; i < FIN * DYNF; i += blockDim.x) Ws[i] = W[i];
    __syncthreads();
    int r = blockIdx.x * blockDim.x + threadIdx.x;
    if (r >= nrows) return;
    float in[FIN];
    const float4* ip = (const float4*)(in_rows + (size_t)r * DYNF);
#pragma unroll
    for (int q = 0; q < DYNF / 4; q++) {
        float4 v = ip[q];
        in[q * 4 + 0] = v.x; in[q * 4 + 1] = v.y; in[q * 4 + 2] = v.z; in[q * 4 + 3] = v.w;
    }
    const float4* sp = (const float4*)(in_stat + (size_t)r * STATF);
#pragma unroll
    for (int q = 0; q < STATF / 4; q++) {
        float4 v = sp[q];
        in[DYNF + q * 4 + 0] = v.x; in[DYNF + q * 4 + 1] = v.y;
        in[DYNF + q * 4 + 2] = v.z; in[DYNF + q * 4 + 3] = v.w;
    }
    float o[DYNF];
#pragma unroll
    for (int j = 0; j < DYNF; j++) o[j] = 0.f;
#pragma unroll
    for (int k = 0; k < FIN; k++) {
        float a = in[k];
#pragma unroll
        for (int j = 0; j < DYNF; j++) o[j] = fmaf(a, Ws[k * DYNF + j], o[j]);
    }
    float nm = norm[r];
    float4* hp = (float4*)(hs + (size_t)r * DYNF);
#pragma unroll
    for (int q = 0; q < DYNF / 4; q++)
        hp[q] = make_float4(o[q * 4] * nm, o[q * 4 + 1] * nm, o[q * 4 + 2] * nm, o[q * 4 + 3] * nm);
}

// CSR pull: out[r] = norm[r]*(hs[r] + sum_{e in row r} hs[col[e]]) + b   (8 thr/row)
__global__ void pull_kernel(const int* __restrict__ rp, const int* __restrict__ col,
                            const float* __restrict__ hs, const float* __restrict__ nrm,
                            const float* __restrict__ b, float* __restrict__ out,
                            int row_lo, int n_rows) {
    int tid = blockIdx.x * blockDim.x + threadIdx.x;
    int rr = tid >> 3;
    if (rr >= n_rows) return;
    int r = row_lo + rr;
    int q = (tid & 7) * 4;
    int e0 = rp[r], e1 = rp[r + 1];
    float4 acc = *(const float4*)(hs + (size_t)r * DYNF + q);   // self-loop
    for (int e = e0; e < e1; e++) {
        int s = col[e];
        float4 v = *(const float4*)(hs + (size_t)s * DYNF + q);
        acc.x += v.x; acc.y += v.y; acc.z += v.z; acc.w += v.w;
    }
    float nm = nrm[r];
    float4 bv = *(const float4*)(b + q);
    *(float4*)(out + (size_t)r * DYNF + q) =
        make_float4(fmaf(acc.x, nm, bv.x), fmaf(acc.y, nm, bv.y),
                    fmaf(acc.z, nm, bv.z), fmaf(acc.w, nm, bv.w));
}

// ---- up conv in 4-dim space (CSR pull) ---------------------------------

__global__ void xs_kernel(const float* __restrict__ x, const float* __restrict__ nrm,
                          float* __restrict__ xs, int n) {
    int r = blockIdx.x * blockDim.x + threadIdx.x;
    if (r >= n) return;
    float nm = nrm[r];
    float4 v = *(const float4*)(x + (size_t)r * 4);
    *(float4*)(xs + (size_t)r * 4) = make_float4(v.x * nm, v.y * nm, v.z * nm, v.w * nm);
}

__global__ void pull4_kernel(const int* __restrict__ rp, const int* __restrict__ col,
                             const float* __restrict__ xs, float* __restrict__ y, int n) {
    int r = blockIdx.x * blockDim.x + threadIdx.x;
    if (r >= n) return;
    int e0 = rp[r], e1 = rp[r + 1];
    float4 acc = *(const float4*)(xs + (size_t)r * 4);
    for (int e = e0; e < e1; e++) {
        int s = col[e];
        float4 v = *(const float4*)(xs + (size_t)s * 4);
        acc.x += v.x; acc.y += v.y; acc.z += v.z; acc.w += v.w;
    }
    *(float4*)(y + (size_t)r * 4) = acc;
}

// h[r] = norm[r]*(y[r] @ W_up) + b
__global__ void up_mm_kernel(const float* __restrict__ y, const float* __restrict__ W,
                             const float* __restrict__ nrm, const float* __restrict__ b,
                             float* __restrict__ h, int n) {
    __shared__ float Ws[4 * DYNF];
    __shared__ float bs[DYNF];
    for (int i = threadIdx.x; i < 4 * DYNF; i += blockDim.x) Ws[i] = W[i];
    for (int i = threadIdx.x; i < DYNF; i += blockDim.x) bs[i] = b[i];
    __syncthreads();
    int r = blockIdx.x * blockDim.x + threadIdx.x;
    if (r >= n) return;
    float4 v = *(const float4*)(y + (size_t)r * 4);
    float nm = nrm[r];
    float4* hp = (float4*)(h + (size_t)r * DYNF);
#pragma unroll
    for (int q = 0; q < DYNF / 4; q++) {
        float4 o;
        o.x = v.x * Ws[0 * DYNF + q * 4 + 0] + v.y * Ws[1 * DYNF + q * 4 + 0] +
              v.z * Ws[2 * DYNF + q * 4 + 0] + v.w * Ws[3 * DYNF + q * 4 + 0];
        o.y = v.x * Ws[0 * DYNF + q * 4 + 1] + v.y * Ws[1 * DYNF + q * 4 + 1] +
              v.z * Ws[2 * DYNF + q * 4 + 1] + v.w * Ws[3 * DYNF + q * 4 + 1];
        o.z = v.x * Ws[0 * DYNF + q * 4 + 2] + v.y * Ws[1 * DYNF + q * 4 + 2] +
              v.z * Ws[2 * DYNF + q * 4 + 2] + v.w * Ws[3 * DYNF + q * 4 + 2];
        o.w = v.x * Ws[0 * DYNF + q * 4 + 3] + v.y * Ws[1 * DYNF + q * 4 + 3] +
              v.z * Ws[2 * DYNF + q * 4 + 3] + v.w * Ws[3 * DYNF + q * 4 + 3];
        hp[q] = make_float4(fmaf(o.x, nm, bs[q * 4 + 0]), fmaf(o.y, nm, bs[q * 4 + 1]),
                            fmaf(o.z, nm, bs[q * 4 + 2]), fmaf(o.w, nm, bs[q * 4 + 3]));
    }
}

// ---- misc --------------------------------------------------------------

__global__ void relu_kernel(float* h, int n) {
    int i = blockIdx.x * blockDim.x + threadIdx.x;
    if (i < n) h[i] = fmaxf(h[i], 0.f);
}

__global__ void init_out_kernel(float* out, const float* __restrict__ lin_b) {
    int i = threadIdx.x;
    if (i < GG) out[i] = lin_b[0];
}

__global__ void pool_kernel(const float* __restrict__ h, const int* __restrict__ gids,
                            const float* __restrict__ linW, float* out) {
    __shared__ float part[GG];
    int t = threadIdx.x;
    if (t < GG) part[t] = 0.f;
    __syncthreads();
    int r = blockIdx.x * blockDim.x + t;
    float dotv = 0.f;
    const float4* hp = (const float4*)(h + (size_t)r * DYNF);
#pragma unroll
    for (int q = 0; q < 8; q++) {
        float4 v = hp[q];
        dotv += v.x * linW[q * 4 + 0] + v.y * linW[q * 4 + 1] +
                v.z * linW[q * 4 + 2] + v.w * linW[q * 4 + 3];
    }
    atomicAdd(&part[gids[r]], dotv);
    __syncthreads();
    if (t < GG) unsafeAtomicAdd(&out[t], part[t]);
}

// ------------------------------------------------------------------------

extern "C" void kernel_launch(void* const* d_in, const int* in_sizes, int n_in,
                              void* d_out, int out_size, void* d_ws, size_t ws_size,
                              hipStream_t stream) {
    const float* x     = (const float*)d_in[0];
    const float* stat  = (const float*)d_in[1];
    const int*   e_up  = (const int*)d_in[2];
    const int*   e_in  = (const int*)d_in[3];
    const int*   e_f   = (const int*)d_in[4];
    const int*   e_b   = (const int*)d_in[5];
    const int*   gids  = (const int*)d_in[6];
    const float* W_up  = (const float*)d_in[7];
    const float* b_up  = (const float*)d_in[8];
    const float* W_in  = (const float*)d_in[9];
    const float* b_in  = (const float*)d_in[10];
    const float* W_f   = (const float*)d_in[11];
    const float* b_f   = (const float*)d_in[12];
    const float* W_b   = (const float*)d_in[13];
    const float* b_b   = (const float*)d_in[14];
    const float* lin_W = (const float*)d_in[15];
    const float* lin_b = (const float*)d_in[16];
    float* out = (float*)d_out;

    // workspace carve (~125 MB)
    float* h      = (float*)d_ws;                        // NN*32 floats (33.5 MB)
    int2*  node   = (int2*)h;                            // ALIAS: 4M int2 chain nodes (build phase only;
                                                         // h first written after all walks complete)
    float* hs_win = h + (size_t)NN * DYNF;               // 2*NLK*32 floats (16.7 MB)
    float* xs     = hs_win;                              // alias (up phase only): NN*4 floats
    float* y4     = hs_win + (size_t)NN * 4;             // alias (up phase only): NN*4 floats
    int*   cnt    = (int*)(hs_win + (size_t)2 * NLK * DYNF); // NS_TOT (norms in place after norm_kernel)
    float* norms  = (float*)cnt;
    int*   head   = cnt + NS_TOT;                        // NS_TOT
    int*   rp     = head + NS_TOT;                       // RP_TOT
    int*   col    = rp + RP_TOT;                         // CO_TOT
    int*   part   = col + CO_TOT;                        // 256

    // ---- the 11 distinct edge lists ----
    struct ListDesc { const int* src; const int* dst; int E; int n; int ns; int rpo; int co; };
    ListDesc LD[11];
    LD[0] = { e_up, e_up + EUP, EUP, NN, NS_UP, RP_UP, CO_UP };
    for (int l = 0; l < 4; l++)
        LD[1 + l] = { e_in + (size_t)(l * 2) * EIN, e_in + (size_t)(l * 2 + 1) * EIN,
                      EIN, NLK, NS_IN(l), RP_IN(l), CO_IN(l) };
    for (int l = 0; l < 3; l++)
        LD[5 + l] = { e_f + (size_t)(l * 2) * EFB, e_f + (size_t)(l * 2 + 1) * EFB,
                      EFB, 2 * NLK, NS_F(l), RP_F(l), CO_F(l) };
    for (int l = 0; l < 3; l++)
        LD[8 + l] = { e_b + (size_t)(l * 2) * EFB, e_b + (size_t)(l * 2 + 1) * EFB,
                      EFB, 2 * NLK, NS_B(l), RP_B(l), CO_B(l) };

    // ---- CSR build via chain+walk (node buffer reused across lists) ----
    hipMemsetAsync(cnt, 0, (size_t)NS_TOT * 4, stream);
    hipMemsetAsync(head, 0xFF, (size_t)NS_TOT * 4, stream);   // head = -1

    for (int i = 0; i < 11; i++) {
        build_kernel<<<cdiv(LD[i].E, 256), 256, 0, stream>>>(
            LD[i].src, LD[i].dst, LD[i].E, cnt + LD[i].ns, head + LD[i].ns, node);
        int nb = cdiv(LD[i].n, 1024);
        scan1_kernel<<<nb, 1024, 0, stream>>>(cnt + LD[i].ns, rp + LD[i].rpo, part, LD[i].n);
        scan2_kernel<<<1, 256, 0, stream>>>(part, nb);
        scan3_kernel<<<cdiv(LD[i].n, 256), 256, 0, stream>>>(rp + LD[i].rpo, part, LD[i].n, LD[i].E);
        walk_kernel<<<cdiv(LD[i].n, 256), 256, 0, stream>>>(
            head + LD[i].ns, node, rp + LD[i].rpo, col + LD[i].co, LD[i].n);
    }
    norm_kernel<<<cdiv(NS_TOT, 256), 256, 0, stream>>>(cnt, NS_TOT);

    // ---- up conv in 4-dim space: xs = x*norm; y4 = xs[r]+sum xs[col]; h = norm*(y4@W)+b ----
    xs_kernel<<<cdiv(NN, 256), 256, 0, stream>>>(x, norms + NS_UP, xs, NN);
    pull4_kernel<<<cdiv(NN, 256), 256, 0, stream>>>(rp + RP_UP, col + CO_UP, xs, y4, NN);
    up_mm_kernel<<<cdiv(NN, 256), 256, 0, stream>>>(y4, W_up, norms + NS_UP, b_up, h, NN);

    // ---- window conv driver ----
    auto conv = [&](const float* in_rows, const float* in_stat, const float* W,
                    const float* bias, int ns, int rpo, int co,
                    int gbase, int nwin, int row_lo, int n_pull) {
        mm_scale_kernel<<<cdiv(nwin, 256), 256, 0, stream>>>(
            in_rows, in_stat, W, norms + ns, hs_win, nwin);
        pull_kernel<<<cdiv((long)n_pull * 8, 256), 256, 0, stream>>>(
            rp + rpo, col + co, hs_win, norms + ns, bias,
            h + (size_t)gbase * DYNF, row_lo, n_pull);
    };

    auto inner = [&](int l) {
        int s = l * NLK;
        conv(h + (size_t)s * DYNF, stat + (size_t)s * STATF, W_in, b_in,
             NS_IN(l), RP_IN(l), CO_IN(l), s, NLK, 0, NLK);
    };
    auto fwd = [&](int l) {
        int s = l * NLK;
        conv(h + (size_t)s * DYNF, stat + (size_t)s * STATF, W_f, b_f,
             NS_F(l), RP_F(l), CO_F(l), s, 2 * NLK, NLK, NLK);
    };
    auto bwd = [&](int lm1) {
        int s = lm1 * NLK;
        conv(h + (size_t)s * DYNF, stat + (size_t)s * STATF, W_b, b_b,
             NS_B(lm1), RP_B(lm1), CO_B(lm1), s, 2 * NLK, 0, NLK);
    };

    for (int p = 0; p < 2; p++) {
        for (int l = 0; l < 4; l++) {
            inner(l);
            if (l < 3) fwd(l);
        }
        relu_kernel<<<cdiv((long)NN * DYNF, 256), 256, 0, stream>>>(h, NN * DYNF);
        for (int l = 3; l >= 1; l--) {
            bwd(l - 1);
            inner(l - 1);
        }
        relu_kernel<<<cdiv((long)NN * DYNF, 256), 256, 0, stream>>>(h, NN * DYNF);
    }

    init_out_kernel<<<1, 64, 0, stream>>>(out, lin_b);
    pool_kernel<<<NN / 256, 256, 0, stream>>>(h, gids, lin_W, out);
}

// Round 6
// 2467.481 us; speedup vs baseline: 3.7893x; 1.1430x over previous
//
#include <hip/hip_runtime.h>

#define NLK 65536
#define NN (NLK * 4)        // 262144 nodes
#define DYNF 32
#define STATF 8
#define GG 64
#define EUP 4194304
#define EIN 1048576
#define EFB 1048576

// cnt/norm/head space: [up: NN][inner: 4*NLK][fwd: 3*2NLK][bwd: 3*2NLK]
#define NS_UP    0
#define NS_IN(l) (NN + (l) * NLK)
#define NS_F(l)  (NN + 4 * NLK + (l) * 2 * NLK)
#define NS_B(l)  (NN + 10 * NLK + (l) * 2 * NLK)
#define NS_TOT   (NN + 16 * NLK)                    // 1,310,720

// row_ptr space (each list gets n+1)
#define RP_UP    0
#define RP_IN(l) ((NN + 1) + (l) * (NLK + 1))
#define RP_F(l)  ((NN + 1) + 4 * (NLK + 1) + (l) * (2 * NLK + 1))
#define RP_B(l)  ((NN + 1) + 4 * (NLK + 1) + 3 * (2 * NLK + 1) + (l) * (2 * NLK + 1))
#define RP_TOT   ((NN + 1) + 4 * (NLK + 1) + 6 * (2 * NLK + 1))

// col space
#define CO_UP    0
#define CO_IN(l) (EUP + (l) * EIN)
#define CO_F(l)  (EUP + 4 * EIN + (l) * EFB)
#define CO_B(l)  (EUP + 4 * EIN + 3 * EFB + (l) * EFB)
#define CO_TOT   (EUP + 4 * EIN + 6 * EFB)          // 14,680,064

static inline int cdiv(long a, int b) { return (int)((a + b - 1) / b); }

// ---- build: linked-list chain, ONE atomic per edge ---------------------

__global__ void build_kernel(const int* __restrict__ src, const int* __restrict__ dst, int E,
                             int* __restrict__ head, int* __restrict__ nsrc,
                             int* __restrict__ nnxt) {
    int e = blockIdx.x * blockDim.x + threadIdx.x;
    if (e >= E) return;
    int d = dst[e];
    nsrc[e] = src[e];
    nnxt[e] = atomicExch(&head[d], e);
}

// chain-length count (replaces per-edge atomicAdd histogram)
__global__ void count_kernel(const int* __restrict__ head, const int* __restrict__ nnxt,
                             int* __restrict__ cnt, int n) {
    int r = blockIdx.x * blockDim.x + threadIdx.x;
    if (r >= n) return;
    int c = 0;
    int e = head[r];
    while (e >= 0) { c++; e = nnxt[e]; }
    cnt[r] = c;
}

// walk chain, write col[rp[r]..] contiguously (full-line writes)
__global__ void walk_kernel(const int* __restrict__ head, const int* __restrict__ nsrc,
                            const int* __restrict__ nnxt, const int* __restrict__ rp,
                            int* __restrict__ col, int nrows) {
    int r = blockIdx.x * blockDim.x + threadIdx.x;
    if (r >= nrows) return;
    int e = head[r];
    int p = rp[r];
    while (e >= 0) {
        col[p++] = nsrc[e];
        e = nnxt[e];
    }
}

// norm = rsqrt(cnt + 1), in place (int -> float)
__global__ void norm_kernel(int* __restrict__ cntnorm, int n) {
    int i = blockIdx.x * blockDim.x + threadIdx.x;
    if (i < n) {
        int c = cntnorm[i];
        ((float*)cntnorm)[i] = rsqrtf((float)(c + 1));
    }
}

// ---- per-list scan: rp = exclusive prefix of cnt -----------------------

__global__ void scan1_kernel(const int* __restrict__ cnt, int* __restrict__ rp,
                             int* __restrict__ part, int n) {
    __shared__ int sh[1024];
    int t = threadIdx.x;
    int i = blockIdx.x * 1024 + t;
    int v = (i < n) ? cnt[i] : 0;
    sh[t] = v;
    __syncthreads();
    for (int off = 1; off < 1024; off <<= 1) {
        int u = (t >= off) ? sh[t - off] : 0;
        __syncthreads();
        sh[t] += u;
        __syncthreads();
    }
    if (i < n) rp[i] = sh[t] - v;
    if (t == 1023) part[blockIdx.x] = sh[1023];
}

__global__ void scan2_kernel(int* part, int m) {
    __shared__ int sh[256];
    int t = threadIdx.x;
    int v = (t < m) ? part[t] : 0;
    sh[t] = v;
    __syncthreads();
    for (int off = 1; off < 256; off <<= 1) {
        int u = (t >= off) ? sh[t - off] : 0;
        __syncthreads();
        sh[t] += u;
        __syncthreads();
    }
    if (t < m) part[t] = sh[t] - v;
}

__global__ void scan3_kernel(int* __restrict__ rp, const int* __restrict__ part, int n, int E) {
    int i = blockIdx.x * blockDim.x + threadIdx.x;
    if (i < n) rp[i] += part[i >> 10];
    if (i == 0) rp[n] = E;
}

// ---- bf16 helpers ------------------------------------------------------

__device__ inline unsigned bf16rne(float f) {           // round-to-nearest-even
    unsigned u = __float_as_uint(f);
    return (u + 0x7fffu + ((u >> 16) & 1u)) >> 16;
}
__device__ inline float bfl(unsigned u) { return __uint_as_float(u << 16); }
__device__ inline float bfh(unsigned u) { return __uint_as_float(u & 0xffff0000u); }

// ---- conv: dense row transform -> bf16-packed hs -----------------------
// hsb[r] = bf16(((relu?(in_rows[r]) ++ in_stat[r]) @ W) * norm[r])
// relu applied to dyn part only; rlo for rows<NLK, rhi for rows>=NLK.
__global__ void mm_scale_kernel(const float* __restrict__ in_rows, const float* __restrict__ in_stat,
                                const float* __restrict__ W, const float* __restrict__ norm,
                                unsigned* __restrict__ hsb, int nrows, int rlo, int rhi) {
    constexpr int FIN = DYNF + STATF;
    __shared__ float Ws[FIN * DYNF];
    for (int i = threadIdx.x; i < FIN * DYNF; i += blockDim.x) Ws[i] = W[i];
    __syncthreads();
    int r = blockIdx.x * blockDim.x + threadIdx.x;
    if (r >= nrows) return;
    float in[FIN];
    const float4* ip = (const float4*)(in_rows + (size_t)r * DYNF);
#pragma unroll
    for (int q = 0; q < DYNF / 4; q++) {
        float4 v = ip[q];
        in[q * 4 + 0] = v.x; in[q * 4 + 1] = v.y; in[q * 4 + 2] = v.z; in[q * 4 + 3] = v.w;
    }
    if (r < NLK ? rlo : rhi) {
#pragma unroll
        for (int j = 0; j < DYNF; j++) in[j] = fmaxf(in[j], 0.f);
    }
    const float4* sp = (const float4*)(in_stat + (size_t)r * STATF);
#pragma unroll
    for (int q = 0; q < STATF / 4; q++) {
        float4 v = sp[q];
        in[DYNF + q * 4 + 0] = v.x; in[DYNF + q * 4 + 1] = v.y;
        in[DYNF + q * 4 + 2] = v.z; in[DYNF + q * 4 + 3] = v.w;
    }
    float o[DYNF];
#pragma unroll
    for (int j = 0; j < DYNF; j++) o[j] = 0.f;
#pragma unroll
    for (int k = 0; k < FIN; k++) {
        float a = in[k];
#pragma unroll
        for (int j = 0; j < DYNF; j++) o[j] = fmaf(a, Ws[k * DYNF + j], o[j]);
    }
    float nm = norm[r];
    unsigned* hp = hsb + (size_t)r * (DYNF / 2);
#pragma unroll
    for (int k = 0; k < DYNF / 2; k++)
        hp[k] = bf16rne(o[2 * k] * nm) | (bf16rne(o[2 * k + 1] * nm) << 16);
}

// CSR pull over bf16 rows (8 thr/row): out[r] = norm[r]*(hsb[r] + sum hsb[col[e]]) + b
__global__ void pull_kernel(const int* __restrict__ rp, const int* __restrict__ col,
                            const unsigned* __restrict__ hsb, const float* __restrict__ nrm,
                            const float* __restrict__ b, float* __restrict__ out,
                            int row_lo, int n_rows) {
    int tid = blockIdx.x * blockDim.x + threadIdx.x;
    int rr = tid >> 3;
    if (rr >= n_rows) return;
    int r = row_lo + rr;
    int hw = (tid & 7) * 2;                 // uint pair index within 16-uint row
    int e0 = rp[r], e1 = rp[r + 1];
    uint2 sv = *(const uint2*)(hsb + (size_t)r * 16 + hw);
    float a0 = bfl(sv.x), a1 = bfh(sv.x), a2 = bfl(sv.y), a3 = bfh(sv.y);
    for (int e = e0; e < e1; e++) {
        int s = col[e];
        uint2 v = *(const uint2*)(hsb + (size_t)s * 16 + hw);
        a0 += bfl(v.x); a1 += bfh(v.x); a2 += bfl(v.y); a3 += bfh(v.y);
    }
    float nm = nrm[r];
    int q = hw * 2;
    float4 bv = *(const float4*)(b + q);
    *(float4*)(out + (size_t)r * DYNF + q) =
        make_float4(fmaf(a0, nm, bv.x), fmaf(a1, nm, bv.y),
                    fmaf(a2, nm, bv.z), fmaf(a3, nm, bv.w));
}

// ---- up conv in 4-dim space (f32 CSR pull) -----------------------------

__global__ void xs_kernel(const float* __restrict__ x, const float* __restrict__ nrm,
                          float* __restrict__ xs, int n) {
    int r = blockIdx.x * blockDim.x + threadIdx.x;
    if (r >= n) return;
    float nm = nrm[r];
    float4 v = *(const float4*)(x + (size_t)r * 4);
    *(float4*)(xs + (size_t)r * 4) = make_float4(v.x * nm, v.y * nm, v.z * nm, v.w * nm);
}

__global__ void pull4_kernel(const int* __restrict__ rp, const int* __restrict__ col,
                             const float* __restrict__ xs, float* __restrict__ y, int n) {
    int r = blockIdx.x * blockDim.x + threadIdx.x;
    if (r >= n) return;
    int e0 = rp[r], e1 = rp[r + 1];
    float4 acc = *(const float4*)(xs + (size_t)r * 4);
    for (int e = e0; e < e1; e++) {
        int s = col[e];
        float4 v = *(const float4*)(xs + (size_t)s * 4);
        acc.x += v.x; acc.y += v.y; acc.z += v.z; acc.w += v.w;
    }
    *(float4*)(y + (size_t)r * 4) = acc;
}

// h[r] = norm[r]*(y[r] @ W_up) + b
__global__ void up_mm_kernel(const float* __restrict__ y, const float* __restrict__ W,
                             const float* __restrict__ nrm, const float* __restrict__ b,
                             float* __restrict__ h, int n) {
    __shared__ float Ws[4 * DYNF];
    __shared__ float bs[DYNF];
    for (int i = threadIdx.x; i < 4 * DYNF; i += blockDim.x) Ws[i] = W[i];
    for (int i = threadIdx.x; i < DYNF; i += blockDim.x) bs[i] = b[i];
    __syncthreads();
    int r = blockIdx.x * blockDim.x + threadIdx.x;
    if (r >= n) return;
    float4 v = *(const float4*)(y + (size_t)r * 4);
    float nm = nrm[r];
    float4* hp = (float4*)(h + (size_t)r * DYNF);
#pragma unroll
    for (int q = 0; q < DYNF / 4; q++) {
        float4 o;
        o.x = v.x * Ws[0 * DYNF + q * 4 + 0] + v.y * Ws[1 * DYNF + q * 4 + 0] +
              v.z * Ws[2 * DYNF + q * 4 + 0] + v.w * Ws[3 * DYNF + q * 4 + 0];
        o.y = v.x * Ws[0 * DYNF + q * 4 + 1] + v.y * Ws[1 * DYNF + q * 4 + 1] +
              v.z * Ws[2 * DYNF + q * 4 + 1] + v.w * Ws[3 * DYNF + q * 4 + 1];
        o.z = v.x * Ws[0 * DYNF + q * 4 + 2] + v.y * Ws[1 * DYNF + q * 4 + 2] +
              v.z * Ws[2 * DYNF + q * 4 + 2] + v.w * Ws[3 * DYNF + q * 4 + 2];
        o.w = v.x * Ws[0 * DYNF + q * 4 + 3] + v.y * Ws[1 * DYNF + q * 4 + 3] +
              v.z * Ws[2 * DYNF + q * 4 + 3] + v.w * Ws[3 * DYNF + q * 4 + 3];
        hp[q] = make_float4(fmaf(o.x, nm, bs[q * 4 + 0]), fmaf(o.y, nm, bs[q * 4 + 1]),
                            fmaf(o.z, nm, bs[q * 4 + 2]), fmaf(o.w, nm, bs[q * 4 + 3]));
    }
}

// ---- epilogue ----------------------------------------------------------

__global__ void init_out_kernel(float* out, const float* __restrict__ lin_b) {
    int i = threadIdx.x;
    if (i < GG) out[i] = lin_b[0];
}

// final relu fused here (every h row has >=1 pending relu; relu is idempotent)
__global__ void pool_kernel(const float* __restrict__ h, const int* __restrict__ gids,
                            const float* __restrict__ linW, float* out) {
    __shared__ float part[GG];
    int t = threadIdx.x;
    if (t < GG) part[t] = 0.f;
    __syncthreads();
    int r = blockIdx.x * blockDim.x + t;
    float dotv = 0.f;
    const float4* hp = (const float4*)(h + (size_t)r * DYNF);
#pragma unroll
    for (int q = 0; q < 8; q++) {
        float4 v = hp[q];
        dotv += fmaxf(v.x, 0.f) * linW[q * 4 + 0] + fmaxf(v.y, 0.f) * linW[q * 4 + 1] +
                fmaxf(v.z, 0.f) * linW[q * 4 + 2] + fmaxf(v.w, 0.f) * linW[q * 4 + 3];
    }
    atomicAdd(&part[gids[r]], dotv);
    __syncthreads();
    if (t < GG) unsafeAtomicAdd(&out[t], part[t]);
}

// ------------------------------------------------------------------------

extern "C" void kernel_launch(void* const* d_in, const int* in_sizes, int n_in,
                              void* d_out, int out_size, void* d_ws, size_t ws_size,
                              hipStream_t stream) {
    const float* x     = (const float*)d_in[0];
    const float* stat  = (const float*)d_in[1];
    const int*   e_up  = (const int*)d_in[2];
    const int*   e_in  = (const int*)d_in[3];
    const int*   e_f   = (const int*)d_in[4];
    const int*   e_b   = (const int*)d_in[5];
    const int*   gids  = (const int*)d_in[6];
    const float* W_up  = (const float*)d_in[7];
    const float* b_up  = (const float*)d_in[8];
    const float* W_in  = (const float*)d_in[9];
    const float* b_in  = (const float*)d_in[10];
    const float* W_f   = (const float*)d_in[11];
    const float* b_f   = (const float*)d_in[12];
    const float* W_b   = (const float*)d_in[13];
    const float* b_b   = (const float*)d_in[14];
    const float* lin_W = (const float*)d_in[15];
    const float* lin_b = (const float*)d_in[16];
    float* out = (float*)d_out;

    // workspace carve (~117 MB)
    float*    h    = (float*)d_ws;                       // NN*32 floats (33.5 MB)
    int*      nsrc = (int*)h;                            // ALIAS build phase: EUP ints
    int*      nnxt = nsrc + EUP;                         // EUP ints (nsrc+nnxt fill h exactly)
    unsigned* hsb  = (unsigned*)(h + (size_t)NN * DYNF); // 2*NLK*16 uints (8.4 MB)
    float*    xs   = (float*)hsb;                        // alias (up phase): NN*4 floats
    float*    y4   = xs + (size_t)NN * 4;                // alias (up phase): NN*4 floats
    int*      cnt  = (int*)(xs + (size_t)2 * NN * 4);    // NS_TOT (norms in place)
    float*    norms= (float*)cnt;
    int*      head = cnt + NS_TOT;                       // NS_TOT
    int*      rp   = head + NS_TOT;                      // RP_TOT
    int*      col  = rp + RP_TOT;                        // CO_TOT
    int*      part = col + CO_TOT;                       // 256

    // ---- the 11 distinct edge lists ----
    struct ListDesc { const int* src; const int* dst; int E; int n; int ns; int rpo; int co; };
    ListDesc LD[11];
    LD[0] = { e_up, e_up + EUP, EUP, NN, NS_UP, RP_UP, CO_UP };
    for (int l = 0; l < 4; l++)
        LD[1 + l] = { e_in + (size_t)(l * 2) * EIN, e_in + (size_t)(l * 2 + 1) * EIN,
                      EIN, NLK, NS_IN(l), RP_IN(l), CO_IN(l) };
    for (int l = 0; l < 3; l++)
        LD[5 + l] = { e_f + (size_t)(l * 2) * EFB, e_f + (size_t)(l * 2 + 1) * EFB,
                      EFB, 2 * NLK, NS_F(l), RP_F(l), CO_F(l) };
    for (int l = 0; l < 3; l++)
        LD[8 + l] = { e_b + (size_t)(l * 2) * EFB, e_b + (size_t)(l * 2 + 1) * EFB,
                      EFB, 2 * NLK, NS_B(l), RP_B(l), CO_B(l) };

    // ---- CSR build per list: chain (1 atomic/edge) -> count -> scan -> walk ----
    hipMemsetAsync(head, 0xFF, (size_t)NS_TOT * 4, stream);   // head = -1
    for (int i = 0; i < 11; i++) {
        build_kernel<<<cdiv(LD[i].E, 256), 256, 0, stream>>>(
            LD[i].src, LD[i].dst, LD[i].E, head + LD[i].ns, nsrc, nnxt);
        count_kernel<<<cdiv(LD[i].n, 256), 256, 0, stream>>>(
            head + LD[i].ns, nnxt, cnt + LD[i].ns, LD[i].n);
        int nb = cdiv(LD[i].n, 1024);
        scan1_kernel<<<nb, 1024, 0, stream>>>(cnt + LD[i].ns, rp + LD[i].rpo, part, LD[i].n);
        scan2_kernel<<<1, 256, 0, stream>>>(part, nb);
        scan3_kernel<<<cdiv(LD[i].n, 256), 256, 0, stream>>>(rp + LD[i].rpo, part, LD[i].n, LD[i].E);
        walk_kernel<<<cdiv(LD[i].n, 256), 256, 0, stream>>>(
            head + LD[i].ns, nsrc, nnxt, rp + LD[i].rpo, col + LD[i].co, LD[i].n);
    }
    norm_kernel<<<cdiv(NS_TOT, 256), 256, 0, stream>>>(cnt, NS_TOT);

    // ---- up conv in 4-dim space ----
    xs_kernel<<<cdiv(NN, 256), 256, 0, stream>>>(x, norms + NS_UP, xs, NN);
    pull4_kernel<<<cdiv(NN, 256), 256, 0, stream>>>(rp + RP_UP, col + CO_UP, xs, y4, NN);
    up_mm_kernel<<<cdiv(NN, 256), 256, 0, stream>>>(y4, W_up, norms + NS_UP, b_up, h, NN);

    // ---- window conv driver (bf16 payload, fused relu flags) ----
    auto conv = [&](const float* in_rows, const float* in_stat, const float* W,
                    const float* bias, int ns, int rpo, int co, int gbase, int nwin,
                    int row_lo, int n_pull, int rlo, int rhi) {
        mm_scale_kernel<<<cdiv(nwin, 256), 256, 0, stream>>>(
            in_rows, in_stat, W, norms + ns, hsb, nwin, rlo, rhi);
        pull_kernel<<<cdiv((long)n_pull * 8, 256), 256, 0, stream>>>(
            rp + rpo, col + co, hsb, norms + ns, bias,
            h + (size_t)gbase * DYNF, row_lo, n_pull);
    };

    auto inner = [&](int l, int rl) {
        int s = l * NLK;
        conv(h + (size_t)s * DYNF, stat + (size_t)s * STATF, W_in, b_in,
             NS_IN(l), RP_IN(l), CO_IN(l), s, NLK, 0, NLK, rl, rl);
    };
    auto fwd = [&](int l, int rhi) {
        int s = l * NLK;
        conv(h + (size_t)s * DYNF, stat + (size_t)s * STATF, W_f, b_f,
             NS_F(l), RP_F(l), CO_F(l), s, 2 * NLK, NLK, NLK, 0, rhi);
    };
    auto bwd = [&](int lm1, int rlo, int rhi) {
        int s = lm1 * NLK;
        conv(h + (size_t)s * DYNF, stat + (size_t)s * STATF, W_b, b_b,
             NS_B(lm1), RP_B(lm1), CO_B(lm1), s, 2 * NLK, 0, NLK, rlo, rhi);
    };

    for (int p = 0; p < 2; p++) {
        // A-loop: raw inputs except rows carrying the previous pass's final relu
        for (int l = 0; l < 4; l++) {
            inner(l, (l == 0 && p == 1) ? 1 : 0);
            if (l < 3) fwd(l, (p == 1) ? 1 : 0);
        }
        // B-loop (RELU1 fused into reads of A-written layers)
        bwd(2, 1, 1); inner(2, 0);
        bwd(1, 1, 0); inner(1, 0);
        bwd(0, 1, 0); inner(0, 0);
        // (RELU2 fused into next A-loop / pool)
    }

    init_out_kernel<<<1, 64, 0, stream>>>(out, lin_b);
    pool_kernel<<<NN / 256, 256, 0, stream>>>(h, gids, lin_W, out);
}

// Round 7
// 2224.455 us; speedup vs baseline: 4.2032x; 1.1093x over previous
//
#include <hip/hip_runtime.h>

#define NLK 65536
#define NN (NLK * 4)        // 262144 nodes
#define DYNF 32
#define STATF 8
#define GG 64
#define EUP 4194304
#define EIN 1048576
#define EFB 1048576

// cnt/norm/cur/rp space: [up: NN][inner: 4*NLK][fwd: 3*2NLK][bwd: 3*2NLK]
// col regions are allocated in the SAME order by the ONE global scan, so the
// global exclusive prefix of cnt IS the global CSR row pointer (list
// boundaries line up because the layouts match).
#define NS_UP    0
#define NS_IN(l) (NN + (l) * NLK)
#define NS_F(l)  (NN + 4 * NLK + (l) * 2 * NLK)
#define NS_B(l)  (NN + 10 * NLK + (l) * 2 * NLK)
#define NS_TOT   (NN + 16 * NLK)                    // 1,310,720
#define CO_TOT   (EUP + 4 * EIN + 6 * EFB)          // 14,680,064
#define NPART    1280                               // NS_TOT / 1024

// build grid: EUP gets 8 slices x 32 groups = 256 blocks; each of the 10
// small lists gets 8 slices x 8 groups = 64 blocks.
#define NB_UP 256
#define NB_SM 64
#define NB_TOT (NB_UP + 10 * NB_SM)                 // 896

static inline int cdiv(long a, int b) { return (int)((a + b - 1) / b); }

// ---- decode a build block's (list, slice, group) ----------------------
// slice s owns dst range [s*n/8,(s+1)*n/8); only blocks with (bb&7)==s touch
// that range -> with round-robin block->XCD dispatch, the cnt/cur/col lines
// for a slice stay in ONE XCD's L2 (no cross-XCD atomic line migration).
// If the mapping heuristic is wrong this is still correct, just slower.
struct BD { const int* srcp; const int* dstp; int E, ns, shift, s, g, nbs; };

__device__ inline BD decode(int b, const int* e_up, const int* e_in,
                            const int* e_f, const int* e_b) {
    BD o;
    int bb;
    if (b < NB_UP) {
        o.srcp = e_up; o.dstp = e_up + EUP; o.E = EUP; o.ns = NS_UP; o.shift = 15;
        bb = b; o.nbs = NB_UP / 8;
    } else {
        int t = b - NB_UP;
        int list = t / NB_SM;
        bb = t % NB_SM; o.nbs = NB_SM / 8;
        if (list < 4) {
            o.srcp = e_in + (size_t)(2 * list) * EIN; o.dstp = o.srcp + EIN;
            o.E = EIN; o.ns = NS_IN(list); o.shift = 13;
        } else if (list < 7) {
            int l = list - 4;
            o.srcp = e_f + (size_t)(2 * l) * EFB; o.dstp = o.srcp + EFB;
            o.E = EFB; o.ns = NS_F(l); o.shift = 14;
        } else {
            int l = list - 7;
            o.srcp = e_b + (size_t)(2 * l) * EFB; o.dstp = o.srcp + EFB;
            o.E = EFB; o.ns = NS_B(l); o.shift = 14;
        }
    }
    o.s = bb & 7;
    o.g = bb >> 3;
    return o;
}

// ---- fused histogram over all 11 lists (XCD-sliced atomics) -----------
__global__ void hist_all_kernel(const int* __restrict__ e_up, const int* __restrict__ e_in,
                                const int* __restrict__ e_f, const int* __restrict__ e_b,
                                int* __restrict__ cnt) {
    BD o = decode(blockIdx.x, e_up, e_in, e_f, e_b);
    int stride = o.nbs * 256;
    for (int e = o.g * 256 + threadIdx.x; e < o.E; e += stride) {
        int d = o.dstp[e];
        if ((d >> o.shift) == o.s) atomicAdd(&cnt[o.ns + d], 1);
    }
}

// ---- fused scatter over all 11 lists (XCD-sliced atomics + writes) ----
__global__ void scatter_all_kernel(const int* __restrict__ e_up, const int* __restrict__ e_in,
                                   const int* __restrict__ e_f, const int* __restrict__ e_b,
                                   const int* __restrict__ rp, int* __restrict__ cur,
                                   int* __restrict__ col) {
    BD o = decode(blockIdx.x, e_up, e_in, e_f, e_b);
    int stride = o.nbs * 256;
    for (int e = o.g * 256 + threadIdx.x; e < o.E; e += stride) {
        int d = o.dstp[e];
        if ((d >> o.shift) == o.s) {
            int pos = rp[o.ns + d] + atomicAdd(&cur[o.ns + d], 1);
            col[pos] = o.srcp[e];
        }
    }
}

// norm = rsqrt(cnt + 1), in place (int -> float)
__global__ void norm_kernel(int* __restrict__ cntnorm, int n) {
    int i = blockIdx.x * blockDim.x + threadIdx.x;
    if (i < n) {
        int c = cntnorm[i];
        ((float*)cntnorm)[i] = rsqrtf((float)(c + 1));
    }
}

// ---- ONE global scan over cnt[NS_TOT] -> rp ---------------------------

__global__ void scan1_kernel(const int* __restrict__ cnt, int* __restrict__ rp,
                             int* __restrict__ part, int n) {
    __shared__ int sh[1024];
    int t = threadIdx.x;
    int i = blockIdx.x * 1024 + t;
    int v = (i < n) ? cnt[i] : 0;
    sh[t] = v;
    __syncthreads();
    for (int off = 1; off < 1024; off <<= 1) {
        int u = (t >= off) ? sh[t - off] : 0;
        __syncthreads();
        sh[t] += u;
        __syncthreads();
    }
    if (i < n) rp[i] = sh[t] - v;
    if (t == 1023) part[blockIdx.x] = sh[1023];
}

// single block, loops over m partials with running carry
__global__ void scan2_kernel(int* part, int m) {
    __shared__ int sh[256];
    __shared__ int carry;
    int t = threadIdx.x;
    if (t == 0) carry = 0;
    __syncthreads();
    for (int base = 0; base < m; base += 256) {
        int i = base + t;
        int v = (i < m) ? part[i] : 0;
        sh[t] = v;
        __syncthreads();
        for (int off = 1; off < 256; off <<= 1) {
            int u = (t >= off) ? sh[t - off] : 0;
            __syncthreads();
            sh[t] += u;
            __syncthreads();
        }
        if (i < m) part[i] = sh[t] - v + carry;
        __syncthreads();
        if (t == 255) carry += sh[255];
        __syncthreads();
    }
}

__global__ void scan3_kernel(int* __restrict__ rp, const int* __restrict__ part, int n, int total) {
    int i = blockIdx.x * blockDim.x + threadIdx.x;
    if (i < n) rp[i] += part[i >> 10];
    if (i == 0) rp[n] = total;
}

// ---- bf16 helpers ------------------------------------------------------

__device__ inline unsigned bf16rne(float f) {           // round-to-nearest-even
    unsigned u = __float_as_uint(f);
    return (u + 0x7fffu + ((u >> 16) & 1u)) >> 16;
}
__device__ inline float bfl(unsigned u) { return __uint_as_float(u << 16); }
__device__ inline float bfh(unsigned u) { return __uint_as_float(u & 0xffff0000u); }

// ---- conv: dense row transform -> bf16-packed hs -----------------------
// hsb[r] = bf16(((relu?(in_rows[r]) ++ in_stat[r]) @ W) * norm[r])
// relu applied to dyn part only; rlo for rows<NLK, rhi for rows>=NLK.
__global__ void mm_scale_kernel(const float* __restrict__ in_rows, const float* __restrict__ in_stat,
                                const float* __restrict__ W, const float* __restrict__ norm,
                                unsigned* __restrict__ hsb, int nrows, int rlo, int rhi) {
    constexpr int FIN = DYNF + STATF;
    __shared__ float Ws[FIN * DYNF];
    for (int i = threadIdx.x; i < FIN * DYNF; i += blockDim.x) Ws[i] = W[i];
    __syncthreads();
    int r = blockIdx.x * blockDim.x + threadIdx.x;
    if (r >= nrows) return;
    float in[FIN];
    const float4* ip = (const float4*)(in_rows + (size_t)r * DYNF);
#pragma unroll
    for (int q = 0; q < DYNF / 4; q++) {
        float4 v = ip[q];
        in[q * 4 + 0] = v.x; in[q * 4 + 1] = v.y; in[q * 4 + 2] = v.z; in[q * 4 + 3] = v.w;
    }
    if (r < NLK ? rlo : rhi) {
#pragma unroll
        for (int j = 0; j < DYNF; j++) in[j] = fmaxf(in[j], 0.f);
    }
    const float4* sp = (const float4*)(in_stat + (size_t)r * STATF);
#pragma unroll
    for (int q = 0; q < STATF / 4; q++) {
        float4 v = sp[q];
        in[DYNF + q * 4 + 0] = v.x; in[DYNF + q * 4 + 1] = v.y;
        in[DYNF + q * 4 + 2] = v.z; in[DYNF + q * 4 + 3] = v.w;
    }
    float o[DYNF];
#pragma unroll
    for (int j = 0; j < DYNF; j++) o[j] = 0.f;
#pragma unroll
    for (int k = 0; k < FIN; k++) {
        float a = in[k];
#pragma unroll
        for (int j = 0; j < DYNF; j++) o[j] = fmaf(a, Ws[k * DYNF + j], o[j]);
    }
    float nm = norm[r];
    unsigned* hp = hsb + (size_t)r * (DYNF / 2);
#pragma unroll
    for (int k = 0; k < DYNF / 2; k++)
        hp[k] = bf16rne(o[2 * k] * nm) | (bf16rne(o[2 * k + 1] * nm) << 16);
}

// CSR pull over bf16 rows (8 thr/row): out[r] = norm[r]*(hsb[r] + sum hsb[col[e]]) + b
// rp here is pre-offset to the list's NS base; col is the GLOBAL col array
// (positions in rp are global).
__global__ void pull_kernel(const int* __restrict__ rp, const int* __restrict__ col,
                            const unsigned* __restrict__ hsb, const float* __restrict__ nrm,
                            const float* __restrict__ b, float* __restrict__ out,
                            int row_lo, int n_rows) {
    int tid = blockIdx.x * blockDim.x + threadIdx.x;
    int rr = tid >> 3;
    if (rr >= n_rows) return;
    int r = row_lo + rr;
    int hw = (tid & 7) * 2;                 // uint pair index within 16-uint row
    int e0 = rp[r], e1 = rp[r + 1];
    uint2 sv = *(const uint2*)(hsb + (size_t)r * 16 + hw);
    float a0 = bfl(sv.x), a1 = bfh(sv.x), a2 = bfl(sv.y), a3 = bfh(sv.y);
    for (int e = e0; e < e1; e++) {
        int s = col[e];
        uint2 v = *(const uint2*)(hsb + (size_t)s * 16 + hw);
        a0 += bfl(v.x); a1 += bfh(v.x); a2 += bfl(v.y); a3 += bfh(v.y);
    }
    float nm = nrm[r];
    int q = hw * 2;
    float4 bv = *(const float4*)(b + q);
    *(float4*)(out + (size_t)r * DYNF + q) =
        make_float4(fmaf(a0, nm, bv.x), fmaf(a1, nm, bv.y),
                    fmaf(a2, nm, bv.z), fmaf(a3, nm, bv.w));
}

// ---- up conv in 4-dim space: fused pull4 + 4x32 matmul -----------------

__global__ void xs_kernel(const float* __restrict__ x, const float* __restrict__ nrm,
                          float* __restrict__ xs, int n) {
    int r = blockIdx.x * blockDim.x + threadIdx.x;
    if (r >= n) return;
    float nm = nrm[r];
    float4 v = *(const float4*)(x + (size_t)r * 4);
    *(float4*)(xs + (size_t)r * 4) = make_float4(v.x * nm, v.y * nm, v.z * nm, v.w * nm);
}

// h[r] = norm[r] * ((xs[r] + sum xs[col[e]]) @ W_up) + b
__global__ void pull4mm_kernel(const int* __restrict__ rp, const int* __restrict__ col,
                               const float* __restrict__ xs, const float* __restrict__ W,
                               const float* __restrict__ nrm, const float* __restrict__ b,
                               float* __restrict__ h, int n) {
    __shared__ float Ws[4 * DYNF];
    __shared__ float bs[DYNF];
    for (int i = threadIdx.x; i < 4 * DYNF; i += blockDim.x) Ws[i] = W[i];
    for (int i = threadIdx.x; i < DYNF; i += blockDim.x) bs[i] = b[i];
    __syncthreads();
    int r = blockIdx.x * blockDim.x + threadIdx.x;
    if (r >= n) return;
    int e0 = rp[r], e1 = rp[r + 1];
    float4 acc = *(const float4*)(xs + (size_t)r * 4);
    for (int e = e0; e < e1; e++) {
        int s = col[e];
        float4 v = *(const float4*)(xs + (size_t)s * 4);
        acc.x += v.x; acc.y += v.y; acc.z += v.z; acc.w += v.w;
    }
    float nm = nrm[r];
    float4* hp = (float4*)(h + (size_t)r * DYNF);
#pragma unroll
    for (int q = 0; q < DYNF / 4; q++) {
        float4 o;
        o.x = acc.x * Ws[0 * DYNF + q * 4 + 0] + acc.y * Ws[1 * DYNF + q * 4 + 0] +
              acc.z * Ws[2 * DYNF + q * 4 + 0] + acc.w * Ws[3 * DYNF + q * 4 + 0];
        o.y = acc.x * Ws[0 * DYNF + q * 4 + 1] + acc.y * Ws[1 * DYNF + q * 4 + 1] +
              acc.z * Ws[2 * DYNF + q * 4 + 1] + acc.w * Ws[3 * DYNF + q * 4 + 1];
        o.z = acc.x * Ws[0 * DYNF + q * 4 + 2] + acc.y * Ws[1 * DYNF + q * 4 + 2] +
              acc.z * Ws[2 * DYNF + q * 4 + 2] + acc.w * Ws[3 * DYNF + q * 4 + 2];
        o.w = acc.x * Ws[0 * DYNF + q * 4 + 3] + acc.y * Ws[1 * DYNF + q * 4 + 3] +
              acc.z * Ws[2 * DYNF + q * 4 + 3] + acc.w * Ws[3 * DYNF + q * 4 + 3];
        hp[q] = make_float4(fmaf(o.x, nm, bs[q * 4 + 0]), fmaf(o.y, nm, bs[q * 4 + 1]),
                            fmaf(o.z, nm, bs[q * 4 + 2]), fmaf(o.w, nm, bs[q * 4 + 3]));
    }
}

// ---- epilogue ----------------------------------------------------------

__global__ void init_out_kernel(float* out, const float* __restrict__ lin_b) {
    int i = threadIdx.x;
    if (i < GG) out[i] = lin_b[0];
}

// final relu fused here (every h row has >=1 pending relu; relu is idempotent)
__global__ void pool_kernel(const float* __restrict__ h, const int* __restrict__ gids,
                            const float* __restrict__ linW, float* out) {
    __shared__ float part[GG];
    int t = threadIdx.x;
    if (t < GG) part[t] = 0.f;
    __syncthreads();
    int r = blockIdx.x * blockDim.x + t;
    float dotv = 0.f;
    const float4* hp = (const float4*)(h + (size_t)r * DYNF);
#pragma unroll
    for (int q = 0; q < 8; q++) {
        float4 v = hp[q];
        dotv += fmaxf(v.x, 0.f) * linW[q * 4 + 0] + fmaxf(v.y, 0.f) * linW[q * 4 + 1] +
                fmaxf(v.z, 0.f) * linW[q * 4 + 2] + fmaxf(v.w, 0.f) * linW[q * 4 + 3];
    }
    atomicAdd(&part[gids[r]], dotv);
    __syncthreads();
    if (t < GG) unsafeAtomicAdd(&out[t], part[t]);
}

// ------------------------------------------------------------------------

extern "C" void kernel_launch(void* const* d_in, const int* in_sizes, int n_in,
                              void* d_out, int out_size, void* d_ws, size_t ws_size,
                              hipStream_t stream) {
    const float* x     = (const float*)d_in[0];
    const float* stat  = (const float*)d_in[1];
    const int*   e_up  = (const int*)d_in[2];
    const int*   e_in  = (const int*)d_in[3];
    const int*   e_f   = (const int*)d_in[4];
    const int*   e_b   = (const int*)d_in[5];
    const int*   gids  = (const int*)d_in[6];
    const float* W_up  = (const float*)d_in[7];
    const float* b_up  = (const float*)d_in[8];
    const float* W_in  = (const float*)d_in[9];
    const float* b_in  = (const float*)d_in[10];
    const float* W_f   = (const float*)d_in[11];
    const float* b_f   = (const float*)d_in[12];
    const float* W_b   = (const float*)d_in[13];
    const float* b_b   = (const float*)d_in[14];
    const float* lin_W = (const float*)d_in[15];
    const float* lin_b = (const float*)d_in[16];
    float* out = (float*)d_out;

    // workspace carve (~117 MB)
    float*    h    = (float*)d_ws;                       // NN*32 floats (33.5 MB)
    unsigned* hsb  = (unsigned*)(h + (size_t)NN * DYNF); // 2*NLK*16 uints (8.4 MB)
    float*    xs   = (float*)hsb;                        // alias (up phase): NN*4 floats
    int*      cnt  = (int*)(hsb + (size_t)2 * NLK * 16); // NS_TOT (norms in place)
    float*    norms= (float*)cnt;
    int*      cur  = cnt + NS_TOT;                       // NS_TOT (adjacent to cnt for 1 memset)
    int*      rp   = cur + NS_TOT;                       // NS_TOT + 1
    int*      col  = rp + NS_TOT + 1;                    // CO_TOT
    int*      part = col + CO_TOT;                       // NPART

    // ---- build: ONE hist, ONE global scan, ONE scatter --------------------
    hipMemsetAsync(cnt, 0, (size_t)2 * NS_TOT * 4, stream);      // cnt + cur
    hist_all_kernel<<<NB_TOT, 256, 0, stream>>>(e_up, e_in, e_f, e_b, cnt);
    scan1_kernel<<<NPART, 1024, 0, stream>>>(cnt, rp, part, NS_TOT);
    scan2_kernel<<<1, 256, 0, stream>>>(part, NPART);
    scan3_kernel<<<cdiv(NS_TOT, 256), 256, 0, stream>>>(rp, part, NS_TOT, CO_TOT);
    norm_kernel<<<cdiv(NS_TOT, 256), 256, 0, stream>>>(cnt, NS_TOT);
    scatter_all_kernel<<<NB_TOT, 256, 0, stream>>>(e_up, e_in, e_f, e_b, rp, cur, col);

    // ---- up conv in 4-dim space ----
    xs_kernel<<<cdiv(NN, 256), 256, 0, stream>>>(x, norms + NS_UP, xs, NN);
    pull4mm_kernel<<<cdiv(NN, 256), 256, 0, stream>>>(rp + NS_UP, col, xs, W_up,
                                                      norms + NS_UP, b_up, h, NN);

    // ---- window conv driver (bf16 payload, fused relu flags) ----
    auto conv = [&](const float* in_rows, const float* in_stat, const float* W,
                    const float* bias, int ns, int gbase, int nwin,
                    int row_lo, int n_pull, int rlo, int rhi) {
        mm_scale_kernel<<<cdiv(nwin, 256), 256, 0, stream>>>(
            in_rows, in_stat, W, norms + ns, hsb, nwin, rlo, rhi);
        pull_kernel<<<cdiv((long)n_pull * 8, 256), 256, 0, stream>>>(
            rp + ns, col, hsb, norms + ns, bias,
            h + (size_t)gbase * DYNF, row_lo, n_pull);
    };

    auto inner = [&](int l, int rl) {
        int s = l * NLK;
        conv(h + (size_t)s * DYNF, stat + (size_t)s * STATF, W_in, b_in,
             NS_IN(l), s, NLK, 0, NLK, rl, rl);
    };
    auto fwd = [&](int l, int rhi) {
        int s = l * NLK;
        conv(h + (size_t)s * DYNF, stat + (size_t)s * STATF, W_f, b_f,
             NS_F(l), s, 2 * NLK, NLK, NLK, 0, rhi);
    };
    auto bwd = [&](int lm1, int rlo, int rhi) {
        int s = lm1 * NLK;
        conv(h + (size_t)s * DYNF, stat + (size_t)s * STATF, W_b, b_b,
             NS_B(lm1), s, 2 * NLK, 0, NLK, rlo, rhi);
    };

    for (int p = 0; p < 2; p++) {
        // A-loop: raw inputs except rows carrying the previous pass's final relu
        for (int l = 0; l < 4; l++) {
            inner(l, (l == 0 && p == 1) ? 1 : 0);
            if (l < 3) fwd(l, (p == 1) ? 1 : 0);
        }
        // B-loop (RELU1 fused into reads of A-written layers)
        bwd(2, 1, 1); inner(2, 0);
        bwd(1, 1, 0); inner(1, 0);
        bwd(0, 1, 0); inner(0, 0);
        // (RELU2 fused into next A-loop / pool)
    }

    init_out_kernel<<<1, 64, 0, stream>>>(out, lin_b);
    pool_kernel<<<NN / 256, 256, 0, stream>>>(h, gids, lin_W, out);
}

// Round 8
// 2037.150 us; speedup vs baseline: 4.5897x; 1.0919x over previous
//
#include <hip/hip_runtime.h>

#define NLK 65536
#define NN (NLK * 4)        // 262144 nodes
#define DYNF 32
#define STATF 8
#define GG 64
#define EUP 4194304
#define EIN 1048576
#define EFB 1048576

// row space (norm/head): [up: NN][inner: 4*NLK][fwd: 3*2NLK][bwd: 3*2NLK]
#define NS_UP    0
#define NS_IN(l) (NN + (l) * NLK)
#define NS_F(l)  (NN + 4 * NLK + (l) * 2 * NLK)
#define NS_B(l)  (NN + 10 * NLK + (l) * 2 * NLK)
#define NS_TOT   (NN + 16 * NLK)                    // 1,310,720

#define TE (EUP + 4 * EIN + 6 * EFB)                // 14,680,064 total edges
#define NSM (4 * EIN + 6 * EFB)                     // 10,485,760 small-list edges

static inline int cdiv(long a, int b) { return (int)((a + b - 1) / b); }

// ---- actual XCD id of the executing wave (HW-verified on gfx950, m09) ---
__device__ inline int xcc_id() {
    unsigned v;
    asm volatile("s_getreg_b32 %0, hwreg(HW_REG_XCC_ID)" : "=s"(v));
    return (int)(v & 7);
}

// ---- build: per-XCD chain replicas, one LOCAL atomic per edge ----------
// head8[xcd*NS_TOT + ns + d] is only ever touched by blocks running on that
// XCD -> its cache line lives in exactly one L2, no cross-XCD migration.
// Correct regardless of dispatch (worst case all-one-XCD = R6 behavior).
__global__ void build_all_kernel(const int* __restrict__ e_up, const int* __restrict__ e_in,
                                 const int* __restrict__ e_f, const int* __restrict__ e_b,
                                 int* __restrict__ head8, int2* __restrict__ nodeU,
                                 int2* __restrict__ nodeS) {
    int t = blockIdx.x * 256 + threadIdx.x;       // TE divisible by 256
    int xcd = xcc_id();
    const int* srcp; const int* dstp; int el, ns; int2* node;
    if (t < EUP) {
        el = t; srcp = e_up; dstp = e_up + EUP; ns = NS_UP; node = nodeU;
    } else if (t < EUP + 4 * EIN) {
        int o = t - EUP; int l = o >> 20; el = o & (EIN - 1);
        srcp = e_in + (size_t)(2 * l) * EIN; dstp = srcp + EIN;
        ns = NS_IN(l); node = nodeS + (size_t)l * EIN;
    } else if (t < EUP + 4 * EIN + 3 * EFB) {
        int o = t - EUP - 4 * EIN; int l = o >> 20; el = o & (EFB - 1);
        srcp = e_f + (size_t)(2 * l) * EFB; dstp = srcp + EFB;
        ns = NS_F(l); node = nodeS + 4 * EIN + (size_t)l * EFB;
    } else {
        int o = t - EUP - 4 * EIN - 3 * EFB; int l = o >> 20; el = o & (EFB - 1);
        srcp = e_b + (size_t)(2 * l) * EFB; dstp = srcp + EFB;
        ns = NS_B(l); node = nodeS + 4 * EIN + 3 * EFB + (size_t)l * EFB;
    }
    int d = dstp[el];
    int s = srcp[el];
    int old = atomicExch(&head8[(size_t)xcd * NS_TOT + ns + d], el);
    node[el] = make_int2(s, old);
}

// ---- count degrees by walking the 8 chains; write norm in place --------
__global__ void count_norm_kernel(const int* __restrict__ head8, const int2* __restrict__ nodeU,
                                  const int2* __restrict__ nodeS, float* __restrict__ norms) {
    int i = blockIdx.x * 256 + threadIdx.x;       // NS_TOT divisible by 256
    const int2* node;
    if (i < NN) node = nodeU;
    else {
        int o = i - NN;
        if (o < 4 * NLK)       node = nodeS + ((size_t)(o >> 16)) * EIN;
        else if (o < 10 * NLK) node = nodeS + 4 * EIN + ((size_t)((o - 4 * NLK) >> 17)) * EFB;
        else                   node = nodeS + 4 * EIN + 3 * EFB + ((size_t)((o - 10 * NLK) >> 17)) * EFB;
    }
    int c = 0;
#pragma unroll
    for (int k = 0; k < 8; k++) {
        int e = head8[(size_t)k * NS_TOT + i];
        while (e >= 0) { c++; e = node[e].y; }
    }
    norms[i] = rsqrtf((float)(c + 1));            // +1 self-loop
}

// ---- bf16 helpers ------------------------------------------------------

__device__ inline unsigned bf16rne(float f) {
    unsigned u = __float_as_uint(f);
    return (u + 0x7fffu + ((u >> 16) & 1u)) >> 16;
}
__device__ inline float bfl(unsigned u) { return __uint_as_float(u << 16); }
__device__ inline float bfh(unsigned u) { return __uint_as_float(u & 0xffff0000u); }

// ---- conv: dense row transform -> bf16-packed hs -----------------------
// relu applied to dyn part only; rlo for rows<NLK, rhi for rows>=NLK.
__global__ void mm_scale_kernel(const float* __restrict__ in_rows, const float* __restrict__ in_stat,
                                const float* __restrict__ W, const float* __restrict__ norm,
                                unsigned* __restrict__ hsb, int nrows, int rlo, int rhi) {
    constexpr int FIN = DYNF + STATF;
    __shared__ float Ws[FIN * DYNF];
    for (int i = threadIdx.x; i < FIN * DYNF; i += blockDim.x) Ws[i] = W[i];
    __syncthreads();
    int r = blockIdx.x * blockDim.x + threadIdx.x;
    if (r >= nrows) return;
    float in[FIN];
    const float4* ip = (const float4*)(in_rows + (size_t)r * DYNF);
#pragma unroll
    for (int q = 0; q < DYNF / 4; q++) {
        float4 v = ip[q];
        in[q * 4 + 0] = v.x; in[q * 4 + 1] = v.y; in[q * 4 + 2] = v.z; in[q * 4 + 3] = v.w;
    }
    if (r < NLK ? rlo : rhi) {
#pragma unroll
        for (int j = 0; j < DYNF; j++) in[j] = fmaxf(in[j], 0.f);
    }
    const float4* sp = (const float4*)(in_stat + (size_t)r * STATF);
#pragma unroll
    for (int q = 0; q < STATF / 4; q++) {
        float4 v = sp[q];
        in[DYNF + q * 4 + 0] = v.x; in[DYNF + q * 4 + 1] = v.y;
        in[DYNF + q * 4 + 2] = v.z; in[DYNF + q * 4 + 3] = v.w;
    }
    float o[DYNF];
#pragma unroll
    for (int j = 0; j < DYNF; j++) o[j] = 0.f;
#pragma unroll
    for (int k = 0; k < FIN; k++) {
        float a = in[k];
#pragma unroll
        for (int j = 0; j < DYNF; j++) o[j] = fmaf(a, Ws[k * DYNF + j], o[j]);
    }
    float nm = norm[r];
    unsigned* hp = hsb + (size_t)r * (DYNF / 2);
#pragma unroll
    for (int k = 0; k < DYNF / 2; k++)
        hp[k] = bf16rne(o[2 * k] * nm) | (bf16rne(o[2 * k + 1] * nm) << 16);
}

// ---- pull over 8 chains (8 thr/row, bf16 payload) ----------------------
// out[r] = norm[r]*(hsb[r] + sum over 8 chains hsb[src]) + b
__global__ void pull8_kernel(const int* __restrict__ head,    // head8 + ns
                             const int2* __restrict__ node,   // list's node base
                             const unsigned* __restrict__ hsb, const float* __restrict__ nrm,
                             const float* __restrict__ b, float* __restrict__ out,
                             int row_lo, int n_rows) {
    int tid = blockIdx.x * blockDim.x + threadIdx.x;
    int rr = tid >> 3;
    if (rr >= n_rows) return;
    int r = row_lo + rr;
    int hw = (tid & 7) * 2;
    uint2 sv = *(const uint2*)(hsb + (size_t)r * 16 + hw);
    float a0 = bfl(sv.x), a1 = bfh(sv.x), a2 = bfl(sv.y), a3 = bfh(sv.y);
#pragma unroll
    for (int k = 0; k < 8; k++) {
        int e = head[(size_t)k * NS_TOT + r];
        int2 nd = make_int2(0, -1);
        if (e >= 0) nd = node[e];
        while (e >= 0) {
            int en = nd.y;
            int2 ndn = make_int2(0, -1);
            if (en >= 0) ndn = node[en];          // prefetch next hop
            uint2 v = *(const uint2*)(hsb + (size_t)nd.x * 16 + hw);
            a0 += bfl(v.x); a1 += bfh(v.x); a2 += bfl(v.y); a3 += bfh(v.y);
            e = en; nd = ndn;
        }
    }
    float nm = nrm[r];
    int q = hw * 2;
    float4 bv = *(const float4*)(b + q);
    *(float4*)(out + (size_t)r * DYNF + q) =
        make_float4(fmaf(a0, nm, bv.x), fmaf(a1, nm, bv.y),
                    fmaf(a2, nm, bv.z), fmaf(a3, nm, bv.w));
}

// ---- up conv in 4-dim space over chains --------------------------------

__global__ void xs_kernel(const float* __restrict__ x, const float* __restrict__ nrm,
                          float* __restrict__ xs, int n) {
    int r = blockIdx.x * blockDim.x + threadIdx.x;
    if (r >= n) return;
    float nm = nrm[r];
    float4 v = *(const float4*)(x + (size_t)r * 4);
    *(float4*)(xs + (size_t)r * 4) = make_float4(v.x * nm, v.y * nm, v.z * nm, v.w * nm);
}

__global__ void pull4_kernel(const int* __restrict__ head8, const int2* __restrict__ nodeU,
                             const float* __restrict__ xs, float* __restrict__ y4, int n) {
    int r = blockIdx.x * blockDim.x + threadIdx.x;
    if (r >= n) return;
    float4 acc = *(const float4*)(xs + (size_t)r * 4);
#pragma unroll
    for (int k = 0; k < 8; k++) {
        int e = head8[(size_t)k * NS_TOT + r];
        int2 nd = make_int2(0, -1);
        if (e >= 0) nd = nodeU[e];
        while (e >= 0) {
            int en = nd.y;
            int2 ndn = make_int2(0, -1);
            if (en >= 0) ndn = nodeU[en];
            float4 v = *(const float4*)(xs + (size_t)nd.x * 4);
            acc.x += v.x; acc.y += v.y; acc.z += v.z; acc.w += v.w;
            e = en; nd = ndn;
        }
    }
    *(float4*)(y4 + (size_t)r * 4) = acc;
}

// h[r] = norm[r]*(y[r] @ W_up) + b
__global__ void up_mm_kernel(const float* __restrict__ y, const float* __restrict__ W,
                             const float* __restrict__ nrm, const float* __restrict__ b,
                             float* __restrict__ h, int n) {
    __shared__ float Ws[4 * DYNF];
    __shared__ float bs[DYNF];
    for (int i = threadIdx.x; i < 4 * DYNF; i += blockDim.x) Ws[i] = W[i];
    for (int i = threadIdx.x; i < DYNF; i += blockDim.x) bs[i] = b[i];
    __syncthreads();
    int r = blockIdx.x * blockDim.x + threadIdx.x;
    if (r >= n) return;
    float4 v = *(const float4*)(y + (size_t)r * 4);
    float nm = nrm[r];
    float4* hp = (float4*)(h + (size_t)r * DYNF);
#pragma unroll
    for (int q = 0; q < DYNF / 4; q++) {
        float4 o;
        o.x = v.x * Ws[0 * DYNF + q * 4 + 0] + v.y * Ws[1 * DYNF + q * 4 + 0] +
              v.z * Ws[2 * DYNF + q * 4 + 0] + v.w * Ws[3 * DYNF + q * 4 + 0];
        o.y = v.x * Ws[0 * DYNF + q * 4 + 1] + v.y * Ws[1 * DYNF + q * 4 + 1] +
              v.z * Ws[2 * DYNF + q * 4 + 1] + v.w * Ws[3 * DYNF + q * 4 + 1];
        o.z = v.x * Ws[0 * DYNF + q * 4 + 2] + v.y * Ws[1 * DYNF + q * 4 + 2] +
              v.z * Ws[2 * DYNF + q * 4 + 2] + v.w * Ws[3 * DYNF + q * 4 + 2];
        o.w = v.x * Ws[0 * DYNF + q * 4 + 3] + v.y * Ws[1 * DYNF + q * 4 + 3] +
              v.z * Ws[2 * DYNF + q * 4 + 3] + v.w * Ws[3 * DYNF + q * 4 + 3];
        hp[q] = make_float4(fmaf(o.x, nm, bs[q * 4 + 0]), fmaf(o.y, nm, bs[q * 4 + 1]),
                            fmaf(o.z, nm, bs[q * 4 + 2]), fmaf(o.w, nm, bs[q * 4 + 3]));
    }
}

// ---- epilogue ----------------------------------------------------------

__global__ void init_out_kernel(float* out, const float* __restrict__ lin_b) {
    int i = threadIdx.x;
    if (i < GG) out[i] = lin_b[0];
}

// final relu fused here
__global__ void pool_kernel(const float* __restrict__ h, const int* __restrict__ gids,
                            const float* __restrict__ linW, float* out) {
    __shared__ float part[GG];
    int t = threadIdx.x;
    if (t < GG) part[t] = 0.f;
    __syncthreads();
    int r = blockIdx.x * blockDim.x + t;
    float dotv = 0.f;
    const float4* hp = (const float4*)(h + (size_t)r * DYNF);
#pragma unroll
    for (int q = 0; q < 8; q++) {
        float4 v = hp[q];
        dotv += fmaxf(v.x, 0.f) * linW[q * 4 + 0] + fmaxf(v.y, 0.f) * linW[q * 4 + 1] +
                fmaxf(v.z, 0.f) * linW[q * 4 + 2] + fmaxf(v.w, 0.f) * linW[q * 4 + 3];
    }
    atomicAdd(&part[gids[r]], dotv);
    __syncthreads();
    if (t < GG) unsafeAtomicAdd(&out[t], part[t]);
}

// ------------------------------------------------------------------------

extern "C" void kernel_launch(void* const* d_in, const int* in_sizes, int n_in,
                              void* d_out, int out_size, void* d_ws, size_t ws_size,
                              hipStream_t stream) {
    const float* x     = (const float*)d_in[0];
    const float* stat  = (const float*)d_in[1];
    const int*   e_up  = (const int*)d_in[2];
    const int*   e_in  = (const int*)d_in[3];
    const int*   e_f   = (const int*)d_in[4];
    const int*   e_b   = (const int*)d_in[5];
    const int*   gids  = (const int*)d_in[6];
    const float* W_up  = (const float*)d_in[7];
    const float* b_up  = (const float*)d_in[8];
    const float* W_in  = (const float*)d_in[9];
    const float* b_in  = (const float*)d_in[10];
    const float* W_f   = (const float*)d_in[11];
    const float* b_f   = (const float*)d_in[12];
    const float* W_b   = (const float*)d_in[13];
    const float* b_b   = (const float*)d_in[14];
    const float* lin_W = (const float*)d_in[15];
    const float* lin_b = (const float*)d_in[16];
    float* out = (float*)d_out;

    // workspace carve (~173 MB)
    float*    h     = (float*)d_ws;                        // NN*32 f32 (33.5 MB)
    int2*     nodeU = (int2*)h;                            // ALIAS: EUP int2 = exactly h size;
                                                           // h first written (up_mm) after pull4 done
    unsigned* hsb   = (unsigned*)(h + (size_t)NN * DYNF);  // 2*NLK*16 u32 (8.4 MB)
    float*    xs    = (float*)hsb;                         // alias (up phase): NN*4
    float*    y4    = xs + (size_t)NN * 4;                 // alias (up phase): NN*4 (8.4 MB total, exact)
    float*    norms = (float*)(hsb + (size_t)2 * NLK * 16);// NS_TOT f32 (5.25 MB)
    int*      head8 = (int*)(norms + NS_TOT);              // 8*NS_TOT (41.9 MB)
    int2*     nodeS = (int2*)(head8 + (size_t)8 * NS_TOT); // NSM int2 (83.9 MB)

    // ---- build: memset heads + ONE fused chain pass + count/norm ----
    hipMemsetAsync(head8, 0xFF, (size_t)8 * NS_TOT * 4, stream);
    build_all_kernel<<<TE / 256, 256, 0, stream>>>(e_up, e_in, e_f, e_b, head8, nodeU, nodeS);
    count_norm_kernel<<<NS_TOT / 256, 256, 0, stream>>>(head8, nodeU, nodeS, norms);

    // ---- up conv in 4-dim space (chains in nodeU, then h overwritten) ----
    xs_kernel<<<cdiv(NN, 256), 256, 0, stream>>>(x, norms + NS_UP, xs, NN);
    pull4_kernel<<<cdiv(NN, 256), 256, 0, stream>>>(head8 + NS_UP, nodeU, xs, y4, NN);
    up_mm_kernel<<<cdiv(NN, 256), 256, 0, stream>>>(y4, W_up, norms + NS_UP, b_up, h, NN);

    // ---- window conv driver (bf16 payload, fused relu flags) ----
    auto conv = [&](const float* in_rows, const float* in_stat, const float* W,
                    const float* bias, int ns, const int2* node, int gbase, int nwin,
                    int row_lo, int n_pull, int rlo, int rhi) {
        mm_scale_kernel<<<cdiv(nwin, 256), 256, 0, stream>>>(
            in_rows, in_stat, W, norms + ns, hsb, nwin, rlo, rhi);
        pull8_kernel<<<cdiv((long)n_pull * 8, 256), 256, 0, stream>>>(
            head8 + ns, node, hsb, norms + ns, bias,
            h + (size_t)gbase * DYNF, row_lo, n_pull);
    };

    auto inner = [&](int l, int rl) {
        int s = l * NLK;
        conv(h + (size_t)s * DYNF, stat + (size_t)s * STATF, W_in, b_in,
             NS_IN(l), nodeS + (size_t)l * EIN, s, NLK, 0, NLK, rl, rl);
    };
    auto fwd = [&](int l, int rhi) {
        int s = l * NLK;
        conv(h + (size_t)s * DYNF, stat + (size_t)s * STATF, W_f, b_f,
             NS_F(l), nodeS + 4 * EIN + (size_t)l * EFB, s, 2 * NLK, NLK, NLK, 0, rhi);
    };
    auto bwd = [&](int lm1, int rlo, int rhi) {
        int s = lm1 * NLK;
        conv(h + (size_t)s * DYNF, stat + (size_t)s * STATF, W_b, b_b,
             NS_B(lm1), nodeS + 4 * EIN + 3 * EFB + (size_t)lm1 * EFB, s, 2 * NLK, 0, NLK, rlo, rhi);
    };

    for (int p = 0; p < 2; p++) {
        for (int l = 0; l < 4; l++) {
            inner(l, (l == 0 && p == 1) ? 1 : 0);
            if (l < 3) fwd(l, (p == 1) ? 1 : 0);
        }
        bwd(2, 1, 1); inner(2, 0);
        bwd(1, 1, 0); inner(1, 0);
        bwd(0, 1, 0); inner(0, 0);
    }

    init_out_kernel<<<1, 64, 0, stream>>>(out, lin_b);
    pool_kernel<<<NN / 256, 256, 0, stream>>>(h, gids, lin_W, out);
}

// Round 9
// 1470.729 us; speedup vs baseline: 6.3573x; 1.3851x over previous
//
#include <hip/hip_runtime.h>

#define NLK 65536
#define NN (NLK * 4)        // 262144 nodes
#define DYNF 32
#define STATF 8
#define GG 64
#define EUP 4194304
#define EIN 1048576
#define EFB 1048576

// unified row space: [up: NN][inner: 4*NLK][fwd: 3*2NLK][bwd: 3*2NLK]
// col is laid out in the same global row order, so rp is global.
#define NS_UP    0
#define NS_IN(l) (NN + (l) * NLK)
#define NS_F(l)  (NN + 4 * NLK + (l) * 2 * NLK)
#define NS_B(l)  (NN + 10 * NLK + (l) * 2 * NLK)
#define NS_TOT   (NN + 16 * NLK)                    // 1,310,720
#define CO_TOT   (EUP + 4 * EIN + 6 * EFB)          // 14,680,064

#define CHUNK 16384                                 // edges per partition block
#define NB    (CO_TOT / CHUNK)                      // 896 partition blocks
#define NBUCK (NS_TOT / 512)                        // 2560 buckets (512 rows each)
#define HM    (NBUCK * NB)                          // 2,293,760 histogram entries

static inline int cdiv(long a, int b) { return (int)((a + b - 1) / b); }

// ---- which list does partition block b cover? --------------------------
// (CHUNK divides every list length, so each block is inside one list)
__device__ inline void cdecode(int b, const int* e_up, const int* e_in,
                               const int* e_f, const int* e_b,
                               const int*& srcp, const int*& dstp, int& ns, int& e0) {
    if (b < 256) { srcp = e_up; dstp = e_up + EUP; ns = NS_UP; e0 = b * CHUNK; return; }
    int t = b - 256;
    int list = t >> 6;
    e0 = (t & 63) * CHUNK;
    if (list < 4) {
        srcp = e_in + (size_t)(2 * list) * EIN; dstp = srcp + EIN; ns = NS_IN(list);
    } else if (list < 7) {
        int l = list - 4;
        srcp = e_f + (size_t)(2 * l) * EFB; dstp = srcp + EFB; ns = NS_F(l);
    } else {
        int l = list - 7;
        srcp = e_b + (size_t)(2 * l) * EFB; dstp = srcp + EFB; ns = NS_B(l);
    }
}

// ---- pass 1: per-block LDS bucket histogram ---------------------------
__global__ void hist_part_kernel(const int* __restrict__ e_up, const int* __restrict__ e_in,
                                 const int* __restrict__ e_f, const int* __restrict__ e_b,
                                 int* __restrict__ hmat) {
    __shared__ int lh[NBUCK];
    for (int k = threadIdx.x; k < NBUCK; k += 256) lh[k] = 0;
    __syncthreads();
    const int *srcp, *dstp; int ns, e0;
    cdecode(blockIdx.x, e_up, e_in, e_f, e_b, srcp, dstp, ns, e0);
#pragma unroll
    for (int j = 0; j < CHUNK / 256; j++) {
        int g = ns + dstp[e0 + j * 256 + threadIdx.x];
        atomicAdd(&lh[g >> 9], 1);
    }
    __syncthreads();
    for (int k = threadIdx.x; k < NBUCK; k += 256)
        if (lh[k]) hmat[(size_t)k * NB + blockIdx.x] = lh[k];   // hmat pre-zeroed
}

// ---- pass 2: scatter into per-(bucket,block) reserved slices ----------
__global__ void scatter_part_kernel(const int* __restrict__ e_up, const int* __restrict__ e_in,
                                    const int* __restrict__ e_f, const int* __restrict__ e_b,
                                    const int* __restrict__ smat, unsigned* __restrict__ pairs) {
    __shared__ int cur[NBUCK];
    const int *srcp, *dstp; int ns, e0;
    cdecode(blockIdx.x, e_up, e_in, e_f, e_b, srcp, dstp, ns, e0);
    for (int k = threadIdx.x; k < NBUCK; k += 256)
        cur[k] = smat[(size_t)k * NB + blockIdx.x];
    __syncthreads();
#pragma unroll
    for (int j = 0; j < CHUNK / 256; j++) {
        int el = e0 + j * 256 + threadIdx.x;
        int g = ns + dstp[el];
        int s = srcp[el];
        int pos = atomicAdd(&cur[g >> 9], 1);      // LDS cursor (block-local)
        pairs[pos] = ((unsigned)s << 9) | (unsigned)(g & 511);
    }
}

// ---- pass 3: per-bucket group by exact dst; emit col, rp, norms -------
__global__ void group_kernel(const unsigned* __restrict__ pairs, const int* __restrict__ smat,
                             int* __restrict__ col, int* __restrict__ rp,
                             float* __restrict__ norms) {
    __shared__ int lcnt[512];
    __shared__ int roff[512];
    __shared__ int lcur[512];
    __shared__ int ssum[256];
    int k = blockIdx.x;
    int t = threadIdx.x;
    int base = smat[(size_t)k * NB];
    int end  = (k + 1 < NBUCK) ? smat[(size_t)(k + 1) * NB] : CO_TOT;
    lcnt[t] = 0; lcnt[t + 256] = 0;
    lcur[t] = 0; lcur[t + 256] = 0;
    __syncthreads();
    for (int i = base + t; i < end; i += 256)
        atomicAdd(&lcnt[pairs[i] & 511], 1);
    __syncthreads();
    // exclusive scan over 512 counts (each thread owns rows 2t, 2t+1)
    int a0 = lcnt[2 * t], a1 = lcnt[2 * t + 1];
    int gsum = a0 + a1;
    ssum[t] = gsum;
    __syncthreads();
    for (int off = 1; off < 256; off <<= 1) {
        int u = (t >= off) ? ssum[t - off] : 0;
        __syncthreads();
        ssum[t] += u;
        __syncthreads();
    }
    int gex = ssum[t] - gsum;
    roff[2 * t] = gex;
    roff[2 * t + 1] = gex + a0;
    int row = (k << 9) + 2 * t;
    rp[row]     = base + gex;
    rp[row + 1] = base + gex + a0;
    norms[row]     = rsqrtf((float)(a0 + 1));      // +1 self-loop
    norms[row + 1] = rsqrtf((float)(a1 + 1));
    if (k == 0 && t == 0) rp[NS_TOT] = CO_TOT;     // sentinel
    __syncthreads();
    for (int i = base + t; i < end; i += 256) {
        unsigned p = pairs[i];
        int rl = p & 511;
        int pos = base + roff[rl] + atomicAdd(&lcur[rl], 1);
        col[pos] = (int)(p >> 9);
    }
}

// ---- global scan (scan1/scan2-carry/scan3) ----------------------------

__global__ void scan1_kernel(const int* __restrict__ cnt, int* __restrict__ rp,
                             int* __restrict__ part, int n) {
    __shared__ int sh[1024];
    int t = threadIdx.x;
    int i = blockIdx.x * 1024 + t;
    int v = (i < n) ? cnt[i] : 0;
    sh[t] = v;
    __syncthreads();
    for (int off = 1; off < 1024; off <<= 1) {
        int u = (t >= off) ? sh[t - off] : 0;
        __syncthreads();
        sh[t] += u;
        __syncthreads();
    }
    if (i < n) rp[i] = sh[t] - v;
    if (t == 1023) part[blockIdx.x] = sh[1023];
}

__global__ void scan2_kernel(int* part, int m) {
    __shared__ int sh[256];
    __shared__ int carry;
    int t = threadIdx.x;
    if (t == 0) carry = 0;
    __syncthreads();
    for (int base = 0; base < m; base += 256) {
        int i = base + t;
        int v = (i < m) ? part[i] : 0;
        sh[t] = v;
        __syncthreads();
        for (int off = 1; off < 256; off <<= 1) {
            int u = (t >= off) ? sh[t - off] : 0;
            __syncthreads();
            sh[t] += u;
            __syncthreads();
        }
        if (i < m) part[i] = sh[t] - v + carry;
        __syncthreads();
        if (t == 255) carry += sh[255];
        __syncthreads();
    }
}

__global__ void scan3_kernel(int* __restrict__ rp, const int* __restrict__ part, int n) {
    int i = blockIdx.x * blockDim.x + threadIdx.x;
    if (i < n) rp[i] += part[i >> 10];
}

// ---- bf16 helpers ------------------------------------------------------

__device__ inline unsigned bf16rne(float f) {
    unsigned u = __float_as_uint(f);
    return (u + 0x7fffu + ((u >> 16) & 1u)) >> 16;
}
__device__ inline float bfl(unsigned u) { return __uint_as_float(u << 16); }
__device__ inline float bfh(unsigned u) { return __uint_as_float(u & 0xffff0000u); }

// ---- conv: dense row transform -> bf16-packed hs -----------------------
__global__ void mm_scale_kernel(const float* __restrict__ in_rows, const float* __restrict__ in_stat,
                                const float* __restrict__ W, const float* __restrict__ norm,
                                unsigned* __restrict__ hsb, int nrows, int rlo, int rhi) {
    constexpr int FIN = DYNF + STATF;
    __shared__ float Ws[FIN * DYNF];
    for (int i = threadIdx.x; i < FIN * DYNF; i += blockDim.x) Ws[i] = W[i];
    __syncthreads();
    int r = blockIdx.x * blockDim.x + threadIdx.x;
    if (r >= nrows) return;
    float in[FIN];
    const float4* ip = (const float4*)(in_rows + (size_t)r * DYNF);
#pragma unroll
    for (int q = 0; q < DYNF / 4; q++) {
        float4 v = ip[q];
        in[q * 4 + 0] = v.x; in[q * 4 + 1] = v.y; in[q * 4 + 2] = v.z; in[q * 4 + 3] = v.w;
    }
    if (r < NLK ? rlo : rhi) {
#pragma unroll
        for (int j = 0; j < DYNF; j++) in[j] = fmaxf(in[j], 0.f);
    }
    const float4* sp = (const float4*)(in_stat + (size_t)r * STATF);
#pragma unroll
    for (int q = 0; q < STATF / 4; q++) {
        float4 v = sp[q];
        in[DYNF + q * 4 + 0] = v.x; in[DYNF + q * 4 + 1] = v.y;
        in[DYNF + q * 4 + 2] = v.z; in[DYNF + q * 4 + 3] = v.w;
    }
    float o[DYNF];
#pragma unroll
    for (int j = 0; j < DYNF; j++) o[j] = 0.f;
#pragma unroll
    for (int k = 0; k < FIN; k++) {
        float a = in[k];
#pragma unroll
        for (int j = 0; j < DYNF; j++) o[j] = fmaf(a, Ws[k * DYNF + j], o[j]);
    }
    float nm = norm[r];
    unsigned* hp = hsb + (size_t)r * (DYNF / 2);
#pragma unroll
    for (int k = 0; k < DYNF / 2; k++)
        hp[k] = bf16rne(o[2 * k] * nm) | (bf16rne(o[2 * k + 1] * nm) << 16);
}

// CSR pull over bf16 rows (8 thr/row): out[r] = norm[r]*(hsb[r] + sum hsb[col[e]]) + b
__global__ void pull_kernel(const int* __restrict__ rp, const int* __restrict__ col,
                            const unsigned* __restrict__ hsb, const float* __restrict__ nrm,
                            const float* __restrict__ b, float* __restrict__ out,
                            int row_lo, int n_rows) {
    int tid = blockIdx.x * blockDim.x + threadIdx.x;
    int rr = tid >> 3;
    if (rr >= n_rows) return;
    int r = row_lo + rr;
    int hw = (tid & 7) * 2;
    int e0 = rp[r], e1 = rp[r + 1];
    uint2 sv = *(const uint2*)(hsb + (size_t)r * 16 + hw);
    float a0 = bfl(sv.x), a1 = bfh(sv.x), a2 = bfl(sv.y), a3 = bfh(sv.y);
    for (int e = e0; e < e1; e++) {
        int s = col[e];
        uint2 v = *(const uint2*)(hsb + (size_t)s * 16 + hw);
        a0 += bfl(v.x); a1 += bfh(v.x); a2 += bfl(v.y); a3 += bfh(v.y);
    }
    float nm = nrm[r];
    int q = hw * 2;
    float4 bv = *(const float4*)(b + q);
    *(float4*)(out + (size_t)r * DYNF + q) =
        make_float4(fmaf(a0, nm, bv.x), fmaf(a1, nm, bv.y),
                    fmaf(a2, nm, bv.z), fmaf(a3, nm, bv.w));
}

// ---- up conv in 4-dim space: fused pull4 + 4x32 matmul -----------------

__global__ void xs_kernel(const float* __restrict__ x, const float* __restrict__ nrm,
                          float* __restrict__ xs, int n) {
    int r = blockIdx.x * blockDim.x + threadIdx.x;
    if (r >= n) return;
    float nm = nrm[r];
    float4 v = *(const float4*)(x + (size_t)r * 4);
    *(float4*)(xs + (size_t)r * 4) = make_float4(v.x * nm, v.y * nm, v.z * nm, v.w * nm);
}

__global__ void pull4mm_kernel(const int* __restrict__ rp, const int* __restrict__ col,
                               const float* __restrict__ xs, const float* __restrict__ W,
                               const float* __restrict__ nrm, const float* __restrict__ b,
                               float* __restrict__ h, int n) {
    __shared__ float Ws[4 * DYNF];
    __shared__ float bs[DYNF];
    for (int i = threadIdx.x; i < 4 * DYNF; i += blockDim.x) Ws[i] = W[i];
    for (int i = threadIdx.x; i < DYNF; i += blockDim.x) bs[i] = b[i];
    __syncthreads();
    int r = blockIdx.x * blockDim.x + threadIdx.x;
    if (r >= n) return;
    int e0 = rp[r], e1 = rp[r + 1];
    float4 acc = *(const float4*)(xs + (size_t)r * 4);
    for (int e = e0; e < e1; e++) {
        int s = col[e];
        float4 v = *(const float4*)(xs + (size_t)s * 4);
        acc.x += v.x; acc.y += v.y; acc.z += v.z; acc.w += v.w;
    }
    float nm = nrm[r];
    float4* hp = (float4*)(h + (size_t)r * DYNF);
#pragma unroll
    for (int q = 0; q < DYNF / 4; q++) {
        float4 o;
        o.x = acc.x * Ws[0 * DYNF + q * 4 + 0] + acc.y * Ws[1 * DYNF + q * 4 + 0] +
              acc.z * Ws[2 * DYNF + q * 4 + 0] + acc.w * Ws[3 * DYNF + q * 4 + 0];
        o.y = acc.x * Ws[0 * DYNF + q * 4 + 1] + acc.y * Ws[1 * DYNF + q * 4 + 1] +
              acc.z * Ws[2 * DYNF + q * 4 + 1] + acc.w * Ws[3 * DYNF + q * 4 + 1];
        o.z = acc.x * Ws[0 * DYNF + q * 4 + 2] + acc.y * Ws[1 * DYNF + q * 4 + 2] +
              acc.z * Ws[2 * DYNF + q * 4 + 2] + acc.w * Ws[3 * DYNF + q * 4 + 2];
        o.w = acc.x * Ws[0 * DYNF + q * 4 + 3] + acc.y * Ws[1 * DYNF + q * 4 + 3] +
              acc.z * Ws[2 * DYNF + q * 4 + 3] + acc.w * Ws[3 * DYNF + q * 4 + 3];
        hp[q] = make_float4(fmaf(o.x, nm, bs[q * 4 + 0]), fmaf(o.y, nm, bs[q * 4 + 1]),
                            fmaf(o.z, nm, bs[q * 4 + 2]), fmaf(o.w, nm, bs[q * 4 + 3]));
    }
}

// ---- epilogue ----------------------------------------------------------

__global__ void init_out_kernel(float* out, const float* __restrict__ lin_b) {
    int i = threadIdx.x;
    if (i < GG) out[i] = lin_b[0];
}

__global__ void pool_kernel(const float* __restrict__ h, const int* __restrict__ gids,
                            const float* __restrict__ linW, float* out) {
    __shared__ float part[GG];
    int t = threadIdx.x;
    if (t < GG) part[t] = 0.f;
    __syncthreads();
    int r = blockIdx.x * blockDim.x + t;
    float dotv = 0.f;
    const float4* hp = (const float4*)(h + (size_t)r * DYNF);
#pragma unroll
    for (int q = 0; q < 8; q++) {
        float4 v = hp[q];
        dotv += fmaxf(v.x, 0.f) * linW[q * 4 + 0] + fmaxf(v.y, 0.f) * linW[q * 4 + 1] +
                fmaxf(v.z, 0.f) * linW[q * 4 + 2] + fmaxf(v.w, 0.f) * linW[q * 4 + 3];
    }
    atomicAdd(&part[gids[r]], dotv);
    __syncthreads();
    if (t < GG) unsafeAtomicAdd(&out[t], part[t]);
}

// ------------------------------------------------------------------------

extern "C" void kernel_launch(void* const* d_in, const int* in_sizes, int n_in,
                              void* d_out, int out_size, void* d_ws, size_t ws_size,
                              hipStream_t stream) {
    const float* x     = (const float*)d_in[0];
    const float* stat  = (const float*)d_in[1];
    const int*   e_up  = (const int*)d_in[2];
    const int*   e_in  = (const int*)d_in[3];
    const int*   e_f   = (const int*)d_in[4];
    const int*   e_b   = (const int*)d_in[5];
    const int*   gids  = (const int*)d_in[6];
    const float* W_up  = (const float*)d_in[7];
    const float* b_up  = (const float*)d_in[8];
    const float* W_in  = (const float*)d_in[9];
    const float* b_in  = (const float*)d_in[10];
    const float* W_f   = (const float*)d_in[11];
    const float* b_f   = (const float*)d_in[12];
    const float* W_b   = (const float*)d_in[13];
    const float* b_b   = (const float*)d_in[14];
    const float* lin_W = (const float*)d_in[15];
    const float* lin_b = (const float*)d_in[16];
    float* out = (float*)d_out;

    // workspace carve (~146 MB peak)
    // [0, 58.7MB): build phase = pairs; conv phase = h (33.6) + hsb (8.4)
    unsigned* pairs = (unsigned*)d_ws;                       // CO_TOT u32
    float*    h     = (float*)d_ws;                          // NN*32 f32 (alias)
    unsigned* hsb   = (unsigned*)(h + (size_t)NN * DYNF);    // 2*NLK*16 u32 (alias)
    float*    xs    = (float*)hsb;                           // up phase (4.2 MB of hsb's 8.4)
    float*    norms = (float*)((char*)d_ws + (size_t)CO_TOT * 4);  // NS_TOT
    int*      rp    = (int*)(norms + NS_TOT);                // NS_TOT + 1
    int*      col   = rp + NS_TOT + 1;                       // CO_TOT
    int*      hmat  = col + CO_TOT;                          // HM
    int*      smat  = hmat + HM;                             // HM + 1
    int*      part  = smat + HM + 1;                         // 2240

    // ---- build: zero-global-atomic radix partition + per-bucket grouping ----
    hipMemsetAsync(hmat, 0, (size_t)HM * 4, stream);
    hist_part_kernel<<<NB, 256, 0, stream>>>(e_up, e_in, e_f, e_b, hmat);
    scan1_kernel<<<HM / 1024, 1024, 0, stream>>>(hmat, smat, part, HM);
    scan2_kernel<<<1, 256, 0, stream>>>(part, HM / 1024);
    scan3_kernel<<<cdiv(HM, 256), 256, 0, stream>>>(smat, part, HM);
    scatter_part_kernel<<<NB, 256, 0, stream>>>(e_up, e_in, e_f, e_b, smat, pairs);
    group_kernel<<<NBUCK, 256, 0, stream>>>(pairs, smat, col, rp, norms);

    // ---- up conv in 4-dim space (pairs region now dead; h/hsb live) ----
    xs_kernel<<<cdiv(NN, 256), 256, 0, stream>>>(x, norms + NS_UP, xs, NN);
    pull4mm_kernel<<<cdiv(NN, 256), 256, 0, stream>>>(rp + NS_UP, col, xs, W_up,
                                                      norms + NS_UP, b_up, h, NN);

    // ---- window conv driver (bf16 payload, fused relu flags) ----
    auto conv = [&](const float* in_rows, const float* in_stat, const float* W,
                    const float* bias, int ns, int gbase, int nwin,
                    int row_lo, int n_pull, int rlo, int rhi) {
        mm_scale_kernel<<<cdiv(nwin, 256), 256, 0, stream>>>(
            in_rows, in_stat, W, norms + ns, hsb, nwin, rlo, rhi);
        pull_kernel<<<cdiv((long)n_pull * 8, 256), 256, 0, stream>>>(
            rp + ns, col, hsb, norms + ns, bias,
            h + (size_t)gbase * DYNF, row_lo, n_pull);
    };

    auto inner = [&](int l, int rl) {
        int s = l * NLK;
        conv(h + (size_t)s * DYNF, stat + (size_t)s * STATF, W_in, b_in,
             NS_IN(l), s, NLK, 0, NLK, rl, rl);
    };
    auto fwd = [&](int l, int rhi) {
        int s = l * NLK;
        conv(h + (size_t)s * DYNF, stat + (size_t)s * STATF, W_f, b_f,
             NS_F(l), s, 2 * NLK, NLK, NLK, 0, rhi);
    };
    auto bwd = [&](int lm1, int rlo, int rhi) {
        int s = lm1 * NLK;
        conv(h + (size_t)s * DYNF, stat + (size_t)s * STATF, W_b, b_b,
             NS_B(lm1), s, 2 * NLK, 0, NLK, rlo, rhi);
    };

    for (int p = 0; p < 2; p++) {
        for (int l = 0; l < 4; l++) {
            inner(l, (l == 0 && p == 1) ? 1 : 0);
            if (l < 3) fwd(l, (p == 1) ? 1 : 0);
        }
        bwd(2, 1, 1); inner(2, 0);
        bwd(1, 1, 0); inner(1, 0);
        bwd(0, 1, 0); inner(0, 0);
    }

    init_out_kernel<<<1, 64, 0, stream>>>(out, lin_b);
    pool_kernel<<<NN / 256, 256, 0, stream>>>(h, gids, lin_W, out);
}

// Round 10
// 1343.629 us; speedup vs baseline: 6.9587x; 1.0946x over previous
//
#include <hip/hip_runtime.h>

#define NLK 65536
#define NN (NLK * 4)        // 262144 nodes
#define DYNF 32
#define STATF 8
#define GG 64
#define EUP 4194304
#define EIN 1048576
#define EFB 1048576

// unified row space: [up: NN][inner: 4*NLK][fwd: 3*2NLK][bwd: 3*2NLK]
// col is laid out in the same global row order, so rp is global.
#define NS_UP    0
#define NS_IN(l) (NN + (l) * NLK)
#define NS_F(l)  (NN + 4 * NLK + (l) * 2 * NLK)
#define NS_B(l)  (NN + 10 * NLK + (l) * 2 * NLK)
#define NS_TOT   (NN + 16 * NLK)                    // 1,310,720
#define CO_TOT   (EUP + 4 * EIN + 6 * EFB)          // 14,680,064

#define CHUNK 32768                                 // edges per partition block
#define NB    (CO_TOT / CHUNK)                      // 448 partition blocks
#define BROWS 2048                                  // rows per bucket
#define NBUCK (NS_TOT / BROWS)                      // 640 buckets
#define HM    (NBUCK * NB)                          // 286,720 histogram entries

static inline int cdiv(long a, int b) { return (int)((a + b - 1) / b); }

// ---- which list does partition block b cover? --------------------------
// (CHUNK divides every list length, so each block is inside one list)
__device__ inline void cdecode(int b, const int* e_up, const int* e_in,
                               const int* e_f, const int* e_b,
                               const int*& srcp, const int*& dstp, int& ns, int& e0) {
    if (b < EUP / CHUNK) { srcp = e_up; dstp = e_up + EUP; ns = NS_UP; e0 = b * CHUNK; return; }
    int t = b - EUP / CHUNK;
    int list = t >> 5;                               // 32 blocks per small list
    e0 = (t & 31) * CHUNK;
    if (list < 4) {
        srcp = e_in + (size_t)(2 * list) * EIN; dstp = srcp + EIN; ns = NS_IN(list);
    } else if (list < 7) {
        int l = list - 4;
        srcp = e_f + (size_t)(2 * l) * EFB; dstp = srcp + EFB; ns = NS_F(l);
    } else {
        int l = list - 7;
        srcp = e_b + (size_t)(2 * l) * EFB; dstp = srcp + EFB; ns = NS_B(l);
    }
}

// ---- pass 1: per-block LDS bucket histogram ---------------------------
__global__ void hist_part_kernel(const int* __restrict__ e_up, const int* __restrict__ e_in,
                                 const int* __restrict__ e_f, const int* __restrict__ e_b,
                                 int* __restrict__ hmat) {
    __shared__ int lh[NBUCK];
    for (int k = threadIdx.x; k < NBUCK; k += 256) lh[k] = 0;
    __syncthreads();
    const int *srcp, *dstp; int ns, e0;
    cdecode(blockIdx.x, e_up, e_in, e_f, e_b, srcp, dstp, ns, e0);
    for (int j = 0; j < CHUNK / 256; j++) {
        int g = ns + dstp[e0 + j * 256 + threadIdx.x];
        atomicAdd(&lh[g >> 11], 1);
    }
    __syncthreads();
    for (int k = threadIdx.x; k < NBUCK; k += 256)
        hmat[(size_t)k * NB + blockIdx.x] = lh[k];
}

// ---- pass 2: scatter into per-(bucket,block) reserved slices ----------
__global__ void scatter_part_kernel(const int* __restrict__ e_up, const int* __restrict__ e_in,
                                    const int* __restrict__ e_f, const int* __restrict__ e_b,
                                    const int* __restrict__ smat, unsigned* __restrict__ pairs) {
    __shared__ int cur[NBUCK];
    const int *srcp, *dstp; int ns, e0;
    cdecode(blockIdx.x, e_up, e_in, e_f, e_b, srcp, dstp, ns, e0);
    for (int k = threadIdx.x; k < NBUCK; k += 256)
        cur[k] = smat[(size_t)k * NB + blockIdx.x];
    __syncthreads();
    for (int j = 0; j < CHUNK / 256; j++) {
        int el = e0 + j * 256 + threadIdx.x;
        int g = ns + dstp[el];
        int s = srcp[el];
        int pos = atomicAdd(&cur[g >> 11], 1);      // LDS cursor (block-local)
        pairs[pos] = ((unsigned)s << 11) | (unsigned)(g & (BROWS - 1));
    }
}

// ---- pass 3: per-bucket group by exact dst; emit col, rp, norms -------
__global__ void group_kernel(const unsigned* __restrict__ pairs, const int* __restrict__ smat,
                             int* __restrict__ col, int* __restrict__ rp,
                             float* __restrict__ norms) {
    __shared__ int lcnt[BROWS];
    __shared__ int roff[BROWS];
    __shared__ int lcur[BROWS];
    __shared__ int ssum[256];
    int k = blockIdx.x;
    int t = threadIdx.x;
    int base = smat[(size_t)k * NB];
    int end  = (k + 1 < NBUCK) ? smat[(size_t)(k + 1) * NB] : CO_TOT;
    for (int j = t; j < BROWS; j += 256) { lcnt[j] = 0; lcur[j] = 0; }
    __syncthreads();
    for (int i = base + t; i < end; i += 256)
        atomicAdd(&lcnt[pairs[i] & (BROWS - 1)], 1);
    __syncthreads();
    // exclusive scan over BROWS counts; thread t owns rows 8t..8t+7
    constexpr int RPT = BROWS / 256;                 // 8
    int a[RPT];
    int gsum = 0;
#pragma unroll
    for (int j = 0; j < RPT; j++) { a[j] = lcnt[RPT * t + j]; gsum += a[j]; }
    ssum[t] = gsum;
    __syncthreads();
    for (int off = 1; off < 256; off <<= 1) {
        int u = (t >= off) ? ssum[t - off] : 0;
        __syncthreads();
        ssum[t] += u;
        __syncthreads();
    }
    int run = ssum[t] - gsum;
    int row0 = k * BROWS + RPT * t;
#pragma unroll
    for (int j = 0; j < RPT; j++) {
        roff[RPT * t + j] = run;
        rp[row0 + j] = base + run;
        norms[row0 + j] = rsqrtf((float)(a[j] + 1));  // +1 self-loop
        run += a[j];
    }
    if (k == 0 && t == 0) rp[NS_TOT] = CO_TOT;        // sentinel
    __syncthreads();
    for (int i = base + t; i < end; i += 256) {
        unsigned p = pairs[i];
        int rl = p & (BROWS - 1);
        int pos = base + roff[rl] + atomicAdd(&lcur[rl], 1);
        col[pos] = (int)(p >> 11);
    }
}

// ---- global scan (scan1/scan2-carry/scan3) ----------------------------

__global__ void scan1_kernel(const int* __restrict__ cnt, int* __restrict__ rp,
                             int* __restrict__ part, int n) {
    __shared__ int sh[1024];
    int t = threadIdx.x;
    int i = blockIdx.x * 1024 + t;
    int v = (i < n) ? cnt[i] : 0;
    sh[t] = v;
    __syncthreads();
    for (int off = 1; off < 1024; off <<= 1) {
        int u = (t >= off) ? sh[t - off] : 0;
        __syncthreads();
        sh[t] += u;
        __syncthreads();
    }
    if (i < n) rp[i] = sh[t] - v;
    if (t == 1023) part[blockIdx.x] = sh[1023];
}

__global__ void scan2_kernel(int* part, int m) {
    __shared__ int sh[256];
    __shared__ int carry;
    int t = threadIdx.x;
    if (t == 0) carry = 0;
    __syncthreads();
    for (int base = 0; base < m; base += 256) {
        int i = base + t;
        int v = (i < m) ? part[i] : 0;
        sh[t] = v;
        __syncthreads();
        for (int off = 1; off < 256; off <<= 1) {
            int u = (t >= off) ? sh[t - off] : 0;
            __syncthreads();
            sh[t] += u;
            __syncthreads();
        }
        if (i < m) part[i] = sh[t] - v + carry;
        __syncthreads();
        if (t == 255) carry += sh[255];
        __syncthreads();
    }
}

__global__ void scan3_kernel(int* __restrict__ rp, const int* __restrict__ part, int n) {
    int i = blockIdx.x * blockDim.x + threadIdx.x;
    if (i < n) rp[i] += part[i >> 10];
}

// ---- bf16 helpers ------------------------------------------------------

__device__ inline unsigned bf16rne(float f) {
    unsigned u = __float_as_uint(f);
    return (u + 0x7fffu + ((u >> 16) & 1u)) >> 16;
}
__device__ inline float bfl(unsigned u) { return __uint_as_float(u << 16); }
__device__ inline float bfh(unsigned u) { return __uint_as_float(u & 0xffff0000u); }

// ---- conv: dense row transform -> bf16-packed hs -----------------------
__global__ void mm_scale_kernel(const float* __restrict__ in_rows, const float* __restrict__ in_stat,
                                const float* __restrict__ W, const float* __restrict__ norm,
                                unsigned* __restrict__ hsb, int nrows, int rlo, int rhi) {
    constexpr int FIN = DYNF + STATF;
    __shared__ float Ws[FIN * DYNF];
    for (int i = threadIdx.x; i < FIN * DYNF; i += blockDim.x) Ws[i] = W[i];
    __syncthreads();
    int r = blockIdx.x * blockDim.x + threadIdx.x;
    if (r >= nrows) return;
    float in[FIN];
    const float4* ip = (const float4*)(in_rows + (size_t)r * DYNF);
#pragma unroll
    for (int q = 0; q < DYNF / 4; q++) {
        float4 v = ip[q];
        in[q * 4 + 0] = v.x; in[q * 4 + 1] = v.y; in[q * 4 + 2] = v.z; in[q * 4 + 3] = v.w;
    }
    if (r < NLK ? rlo : rhi) {
#pragma unroll
        for (int j = 0; j < DYNF; j++) in[j] = fmaxf(in[j], 0.f);
    }
    const float4* sp = (const float4*)(in_stat + (size_t)r * STATF);
#pragma unroll
    for (int q = 0; q < STATF / 4; q++) {
        float4 v = sp[q];
        in[DYNF + q * 4 + 0] = v.x; in[DYNF + q * 4 + 1] = v.y;
        in[DYNF + q * 4 + 2] = v.z; in[DYNF + q * 4 + 3] = v.w;
    }
    float o[DYNF];
#pragma unroll
    for (int j = 0; j < DYNF; j++) o[j] = 0.f;
#pragma unroll
    for (int k = 0; k < FIN; k++) {
        float a = in[k];
#pragma unroll
        for (int j = 0; j < DYNF; j++) o[j] = fmaf(a, Ws[k * DYNF + j], o[j]);
    }
    float nm = norm[r];
    unsigned* hp = hsb + (size_t)r * (DYNF / 2);
#pragma unroll
    for (int k = 0; k < DYNF / 2; k++)
        hp[k] = bf16rne(o[2 * k] * nm) | (bf16rne(o[2 * k + 1] * nm) << 16);
}

// CSR pull over bf16 rows (8 thr/row): out[r] = norm[r]*(hsb[r] + sum hsb[col[e]]) + b
__global__ void pull_kernel(const int* __restrict__ rp, const int* __restrict__ col,
                            const unsigned* __restrict__ hsb, const float* __restrict__ nrm,
                            const float* __restrict__ b, float* __restrict__ out,
                            int row_lo, int n_rows) {
    int tid = blockIdx.x * blockDim.x + threadIdx.x;
    int rr = tid >> 3;
    if (rr >= n_rows) return;
    int r = row_lo + rr;
    int hw = (tid & 7) * 2;
    int e0 = rp[r], e1 = rp[r + 1];
    uint2 sv = *(const uint2*)(hsb + (size_t)r * 16 + hw);
    float a0 = bfl(sv.x), a1 = bfh(sv.x), a2 = bfl(sv.y), a3 = bfh(sv.y);
    for (int e = e0; e < e1; e++) {
        int s = col[e];
        uint2 v = *(const uint2*)(hsb + (size_t)s * 16 + hw);
        a0 += bfl(v.x); a1 += bfh(v.x); a2 += bfl(v.y); a3 += bfh(v.y);
    }
    float nm = nrm[r];
    int q = hw * 2;
    float4 bv = *(const float4*)(b + q);
    *(float4*)(out + (size_t)r * DYNF + q) =
        make_float4(fmaf(a0, nm, bv.x), fmaf(a1, nm, bv.y),
                    fmaf(a2, nm, bv.z), fmaf(a3, nm, bv.w));
}

// ---- up conv in 4-dim space: fused pull4 + 4x32 matmul -----------------

__global__ void xs_kernel(const float* __restrict__ x, const float* __restrict__ nrm,
                          float* __restrict__ xs, int n) {
    int r = blockIdx.x * blockDim.x + threadIdx.x;
    if (r >= n) return;
    float nm = nrm[r];
    float4 v = *(const float4*)(x + (size_t)r * 4);
    *(float4*)(xs + (size_t)r * 4) = make_float4(v.x * nm, v.y * nm, v.z * nm, v.w * nm);
}

__global__ void pull4mm_kernel(const int* __restrict__ rp, const int* __restrict__ col,
                               const float* __restrict__ xs, const float* __restrict__ W,
                               const float* __restrict__ nrm, const float* __restrict__ b,
                               float* __restrict__ h, int n) {
    __shared__ float Ws[4 * DYNF];
    __shared__ float bs[DYNF];
    for (int i = threadIdx.x; i < 4 * DYNF; i += blockDim.x) Ws[i] = W[i];
    for (int i = threadIdx.x; i < DYNF; i += blockDim.x) bs[i] = b[i];
    __syncthreads();
    int r = blockIdx.x * blockDim.x + threadIdx.x;
    if (r >= n) return;
    int e0 = rp[r], e1 = rp[r + 1];
    float4 acc = *(const float4*)(xs + (size_t)r * 4);
    for (int e = e0; e < e1; e++) {
        int s = col[e];
        float4 v = *(const float4*)(xs + (size_t)s * 4);
        acc.x += v.x; acc.y += v.y; acc.z += v.z; acc.w += v.w;
    }
    float nm = nrm[r];
    float4* hp = (float4*)(h + (size_t)r * DYNF);
#pragma unroll
    for (int q = 0; q < DYNF / 4; q++) {
        float4 o;
        o.x = acc.x * Ws[0 * DYNF + q * 4 + 0] + acc.y * Ws[1 * DYNF + q * 4 + 0] +
              acc.z * Ws[2 * DYNF + q * 4 + 0] + acc.w * Ws[3 * DYNF + q * 4 + 0];
        o.y = acc.x * Ws[0 * DYNF + q * 4 + 1] + acc.y * Ws[1 * DYNF + q * 4 + 1] +
              acc.z * Ws[2 * DYNF + q * 4 + 1] + acc.w * Ws[3 * DYNF + q * 4 + 1];
        o.z = acc.x * Ws[0 * DYNF + q * 4 + 2] + acc.y * Ws[1 * DYNF + q * 4 + 2] +
              acc.z * Ws[2 * DYNF + q * 4 + 2] + acc.w * Ws[3 * DYNF + q * 4 + 2];
        o.w = acc.x * Ws[0 * DYNF + q * 4 + 3] + acc.y * Ws[1 * DYNF + q * 4 + 3] +
              acc.z * Ws[2 * DYNF + q * 4 + 3] + acc.w * Ws[3 * DYNF + q * 4 + 3];
        hp[q] = make_float4(fmaf(o.x, nm, bs[q * 4 + 0]), fmaf(o.y, nm, bs[q * 4 + 1]),
                            fmaf(o.z, nm, bs[q * 4 + 2]), fmaf(o.w, nm, bs[q * 4 + 3]));
    }
}

// ---- epilogue ----------------------------------------------------------

__global__ void init_out_kernel(float* out, const float* __restrict__ lin_b) {
    int i = threadIdx.x;
    if (i < GG) out[i] = lin_b[0];
}

__global__ void pool_kernel(const float* __restrict__ h, const int* __restrict__ gids,
                            const float* __restrict__ linW, float* out) {
    __shared__ float part[GG];
    int t = threadIdx.x;
    if (t < GG) part[t] = 0.f;
    __syncthreads();
    int r = blockIdx.x * blockDim.x + t;
    float dotv = 0.f;
    const float4* hp = (const float4*)(h + (size_t)r * DYNF);
#pragma unroll
    for (int q = 0; q < 8; q++) {
        float4 v = hp[q];
        dotv += fmaxf(v.x, 0.f) * linW[q * 4 + 0] + fmaxf(v.y, 0.f) * linW[q * 4 + 1] +
                fmaxf(v.z, 0.f) * linW[q * 4 + 2] + fmaxf(v.w, 0.f) * linW[q * 4 + 3];
    }
    atomicAdd(&part[gids[r]], dotv);
    __syncthreads();
    if (t < GG) unsafeAtomicAdd(&out[t], part[t]);
}

// ------------------------------------------------------------------------

extern "C" void kernel_launch(void* const* d_in, const int* in_sizes, int n_in,
                              void* d_out, int out_size, void* d_ws, size_t ws_size,
                              hipStream_t stream) {
    const float* x     = (const float*)d_in[0];
    const float* stat  = (const float*)d_in[1];
    const int*   e_up  = (const int*)d_in[2];
    const int*   e_in  = (const int*)d_in[3];
    const int*   e_f   = (const int*)d_in[4];
    const int*   e_b   = (const int*)d_in[5];
    const int*   gids  = (const int*)d_in[6];
    const float* W_up  = (const float*)d_in[7];
    const float* b_up  = (const float*)d_in[8];
    const float* W_in  = (const float*)d_in[9];
    const float* b_in  = (const float*)d_in[10];
    const float* W_f   = (const float*)d_in[11];
    const float* b_f   = (const float*)d_in[12];
    const float* W_b   = (const float*)d_in[13];
    const float* b_b   = (const float*)d_in[14];
    const float* lin_W = (const float*)d_in[15];
    const float* lin_b = (const float*)d_in[16];
    float* out = (float*)d_out;

    // workspace carve (~128 MB peak)
    // [0, 58.7MB): build phase = pairs; conv phase = h (33.6) + hsb (8.4)
    unsigned* pairs = (unsigned*)d_ws;                       // CO_TOT u32
    float*    h     = (float*)d_ws;                          // NN*32 f32 (alias)
    unsigned* hsb   = (unsigned*)(h + (size_t)NN * DYNF);    // 2*NLK*16 u32 (alias)
    float*    xs    = (float*)hsb;                           // up phase (4.2 MB of hsb's 8.4)
    float*    norms = (float*)((char*)d_ws + (size_t)CO_TOT * 4);  // NS_TOT
    int*      rp    = (int*)(norms + NS_TOT);                // NS_TOT + 1
    int*      col   = rp + NS_TOT + 1;                       // CO_TOT
    int*      hmat  = col + CO_TOT;                          // HM
    int*      smat  = hmat + HM;                             // HM + 1
    int*      part  = smat + HM + 1;                         // >= HM/1024 = 280

    // ---- build: zero-global-atomic radix partition + per-bucket grouping ----
    hist_part_kernel<<<NB, 256, 0, stream>>>(e_up, e_in, e_f, e_b, hmat);
    scan1_kernel<<<HM / 1024, 1024, 0, stream>>>(hmat, smat, part, HM);
    scan2_kernel<<<1, 256, 0, stream>>>(part, HM / 1024);
    scan3_kernel<<<cdiv(HM, 256), 256, 0, stream>>>(smat, part, HM);
    scatter_part_kernel<<<NB, 256, 0, stream>>>(e_up, e_in, e_f, e_b, smat, pairs);
    group_kernel<<<NBUCK, 256, 0, stream>>>(pairs, smat, col, rp, norms);

    // ---- up conv in 4-dim space (pairs region now dead; h/hsb live) ----
    xs_kernel<<<cdiv(NN, 256), 256, 0, stream>>>(x, norms + NS_UP, xs, NN);
    pull4mm_kernel<<<cdiv(NN, 256), 256, 0, stream>>>(rp + NS_UP, col, xs, W_up,
                                                      norms + NS_UP, b_up, h, NN);

    // ---- window conv driver (bf16 payload, fused relu flags) ----
    auto conv = [&](const float* in_rows, const float* in_stat, const float* W,
                    const float* bias, int ns, int gbase, int nwin,
                    int row_lo, int n_pull, int rlo, int rhi) {
        mm_scale_kernel<<<cdiv(nwin, 256), 256, 0, stream>>>(
            in_rows, in_stat, W, norms + ns, hsb, nwin, rlo, rhi);
        pull_kernel<<<cdiv((long)n_pull * 8, 256), 256, 0, stream>>>(
            rp + ns, col, hsb, norms + ns, bias,
            h + (size_t)gbase * DYNF, row_lo, n_pull);
    };

    auto inner = [&](int l, int rl) {
        int s = l * NLK;
        conv(h + (size_t)s * DYNF, stat + (size_t)s * STATF, W_in, b_in,
             NS_IN(l), s, NLK, 0, NLK, rl, rl);
    };
    auto fwd = [&](int l, int rhi) {
        int s = l * NLK;
        conv(h + (size_t)s * DYNF, stat + (size_t)s * STATF, W_f, b_f,
             NS_F(l), s, 2 * NLK, NLK, NLK, 0, rhi);
    };
    auto bwd = [&](int lm1, int rlo, int rhi) {
        int s = lm1 * NLK;
        conv(h + (size_t)s * DYNF, stat + (size_t)s * STATF, W_b, b_b,
             NS_B(lm1), s, 2 * NLK, 0, NLK, rlo, rhi);
    };

    for (int p = 0; p < 2; p++) {
        for (int l = 0; l < 4; l++) {
            inner(l, (l == 0 && p == 1) ? 1 : 0);
            if (l < 3) fwd(l, (p == 1) ? 1 : 0);
        }
        bwd(2, 1, 1); inner(2, 0);
        bwd(1, 1, 0); inner(1, 0);
        bwd(0, 1, 0); inner(0, 0);
    }

    init_out_kernel<<<1, 64, 0, stream>>>(out, lin_b);
    pool_kernel<<<NN / 256, 256, 0, stream>>>(h, gids, lin_W, out);
}

// Round 11
// 1334.215 us; speedup vs baseline: 7.0078x; 1.0071x over previous
//
#include <hip/hip_runtime.h>

#define NLK 65536
#define NN (NLK * 4)        // 262144 nodes
#define DYNF 32
#define STATF 8
#define GG 64
#define EUP 4194304
#define EIN 1048576
#define EFB 1048576

// unified row space: [up: NN][inner: 4*NLK][fwd: 3*2NLK][bwd: 3*2NLK]
// col is laid out in the same global row order, so rp is global.
#define NS_UP    0
#define NS_IN(l) (NN + (l) * NLK)
#define NS_F(l)  (NN + 4 * NLK + (l) * 2 * NLK)
#define NS_B(l)  (NN + 10 * NLK + (l) * 2 * NLK)
#define NS_TOT   (NN + 16 * NLK)                    // 1,310,720
#define CO_TOT   (EUP + 4 * EIN + 6 * EFB)          // 14,680,064

#define CHUNK 32768                                 // edges per partition block
#define NB    (CO_TOT / CHUNK)                      // 448 partition blocks
#define BROWS 1024                                  // rows per bucket
#define NBUCK (NS_TOT / BROWS)                      // 1280 buckets
#define HM    (NBUCK * NB)                          // 573,440 histogram entries
#define SCAP  20480                                 // LDS sort capacity (heavy mean 16384, +32 sigma)

static inline int cdiv(long a, int b) { return (int)((a + b - 1) / b); }

// ---- which list does partition block b cover? --------------------------
__device__ inline void cdecode(int b, const int* e_up, const int* e_in,
                               const int* e_f, const int* e_b,
                               const int*& srcp, const int*& dstp, int& ns, int& e0) {
    if (b < EUP / CHUNK) { srcp = e_up; dstp = e_up + EUP; ns = NS_UP; e0 = b * CHUNK; return; }
    int t = b - EUP / CHUNK;
    int list = t >> 5;                               // 32 blocks per small list
    e0 = (t & 31) * CHUNK;
    if (list < 4) {
        srcp = e_in + (size_t)(2 * list) * EIN; dstp = srcp + EIN; ns = NS_IN(list);
    } else if (list < 7) {
        int l = list - 4;
        srcp = e_f + (size_t)(2 * l) * EFB; dstp = srcp + EFB; ns = NS_F(l);
    } else {
        int l = list - 7;
        srcp = e_b + (size_t)(2 * l) * EFB; dstp = srcp + EFB; ns = NS_B(l);
    }
}

// ---- pass 1: per-block LDS bucket histogram ---------------------------
__global__ void hist_part_kernel(const int* __restrict__ e_up, const int* __restrict__ e_in,
                                 const int* __restrict__ e_f, const int* __restrict__ e_b,
                                 int* __restrict__ hmat) {
    __shared__ int lh[NBUCK];
    for (int k = threadIdx.x; k < NBUCK; k += 256) lh[k] = 0;
    __syncthreads();
    const int *srcp, *dstp; int ns, e0;
    cdecode(blockIdx.x, e_up, e_in, e_f, e_b, srcp, dstp, ns, e0);
    for (int j = 0; j < CHUNK / 256; j++) {
        int g = ns + dstp[e0 + j * 256 + threadIdx.x];
        atomicAdd(&lh[g >> 10], 1);
    }
    __syncthreads();
    for (int k = threadIdx.x; k < NBUCK; k += 256)
        hmat[(size_t)k * NB + blockIdx.x] = lh[k];
}

// ---- pass 2: scatter into per-(bucket,block) reserved slices ----------
__global__ void scatter_part_kernel(const int* __restrict__ e_up, const int* __restrict__ e_in,
                                    const int* __restrict__ e_f, const int* __restrict__ e_b,
                                    const int* __restrict__ smat, unsigned* __restrict__ pairs) {
    __shared__ int cur[NBUCK];
    const int *srcp, *dstp; int ns, e0;
    cdecode(blockIdx.x, e_up, e_in, e_f, e_b, srcp, dstp, ns, e0);
    for (int k = threadIdx.x; k < NBUCK; k += 256)
        cur[k] = smat[(size_t)k * NB + blockIdx.x];
    __syncthreads();
    for (int j = 0; j < CHUNK / 256; j++) {
        int el = e0 + j * 256 + threadIdx.x;
        int g = ns + dstp[el];
        int s = srcp[el];
        int pos = atomicAdd(&cur[g >> 10], 1);      // LDS cursor (block-local)
        pairs[pos] = ((unsigned)s << 10) | (unsigned)(g & (BROWS - 1));
    }
}

// ---- pass 3: per-bucket group; LDS-staged sort -> SEQUENTIAL col writes
__global__ void group_kernel(const unsigned* __restrict__ pairs, const int* __restrict__ smat,
                             int* __restrict__ col, int* __restrict__ rp,
                             float* __restrict__ norms) {
    __shared__ int srt[SCAP];
    __shared__ int lcnt[BROWS];
    __shared__ int roff[BROWS];
    __shared__ int lcur[BROWS];
    __shared__ int ssum[256];
    int k = blockIdx.x;
    int t = threadIdx.x;
    int base = smat[(size_t)k * NB];
    int end  = (k + 1 < NBUCK) ? smat[(size_t)(k + 1) * NB] : CO_TOT;
    int nb = end - base;
    for (int j = t; j < BROWS; j += 256) { lcnt[j] = 0; lcur[j] = 0; }
    __syncthreads();
    for (int i = base + t; i < end; i += 256)
        atomicAdd(&lcnt[pairs[i] & (BROWS - 1)], 1);
    __syncthreads();
    // exclusive scan over BROWS counts; thread t owns rows 4t..4t+3
    constexpr int RPT = BROWS / 256;                 // 4
    int a[RPT];
    int gsum = 0;
#pragma unroll
    for (int j = 0; j < RPT; j++) { a[j] = lcnt[RPT * t + j]; gsum += a[j]; }
    ssum[t] = gsum;
    __syncthreads();
    for (int off = 1; off < 256; off <<= 1) {
        int u = (t >= off) ? ssum[t - off] : 0;
        __syncthreads();
        ssum[t] += u;
        __syncthreads();
    }
    int run = ssum[t] - gsum;
    int row0 = k * BROWS + RPT * t;
#pragma unroll
    for (int j = 0; j < RPT; j++) {
        roff[RPT * t + j] = run;
        rp[row0 + j] = base + run;
        norms[row0 + j] = rsqrtf((float)(a[j] + 1));  // +1 self-loop
        run += a[j];
    }
    if (k == 0 && t == 0) rp[NS_TOT] = CO_TOT;        // sentinel
    __syncthreads();
    if (nb <= SCAP) {
        // staged: sort into LDS (re-read of pairs is L2-hot), then stream out
        for (int i = base + t; i < end; i += 256) {
            unsigned p = pairs[i];
            int rl = p & (BROWS - 1);
            int pos = roff[rl] + atomicAdd(&lcur[rl], 1);
            srt[pos] = (int)(p >> 10);
        }
        __syncthreads();
        for (int j = t; j < nb; j += 256)
            col[base + j] = srt[j];                   // fully coalesced
    } else {
        // overflow fallback (statistically unreachable): direct scatter
        for (int i = base + t; i < end; i += 256) {
            unsigned p = pairs[i];
            int rl = p & (BROWS - 1);
            int pos = base + roff[rl] + atomicAdd(&lcur[rl], 1);
            col[pos] = (int)(p >> 10);
        }
    }
}

// ---- global scan (scan1/scan2-carry/scan3) ----------------------------

__global__ void scan1_kernel(const int* __restrict__ cnt, int* __restrict__ rp,
                             int* __restrict__ part, int n) {
    __shared__ int sh[1024];
    int t = threadIdx.x;
    int i = blockIdx.x * 1024 + t;
    int v = (i < n) ? cnt[i] : 0;
    sh[t] = v;
    __syncthreads();
    for (int off = 1; off < 1024; off <<= 1) {
        int u = (t >= off) ? sh[t - off] : 0;
        __syncthreads();
        sh[t] += u;
        __syncthreads();
    }
    if (i < n) rp[i] = sh[t] - v;
    if (t == 1023) part[blockIdx.x] = sh[1023];
}

__global__ void scan2_kernel(int* part, int m) {
    __shared__ int sh[256];
    __shared__ int carry;
    int t = threadIdx.x;
    if (t == 0) carry = 0;
    __syncthreads();
    for (int base = 0; base < m; base += 256) {
        int i = base + t;
        int v = (i < m) ? part[i] : 0;
        sh[t] = v;
        __syncthreads();
        for (int off = 1; off < 256; off <<= 1) {
            int u = (t >= off) ? sh[t - off] : 0;
            __syncthreads();
            sh[t] += u;
            __syncthreads();
        }
        if (i < m) part[i] = sh[t] - v + carry;
        __syncthreads();
        if (t == 255) carry += sh[255];
        __syncthreads();
    }
}

__global__ void scan3_kernel(int* __restrict__ rp, const int* __restrict__ part, int n) {
    int i = blockIdx.x * blockDim.x + threadIdx.x;
    if (i < n) rp[i] += part[i >> 10];
}

// ---- bf16 helpers ------------------------------------------------------

__device__ inline unsigned bf16rne(float f) {
    unsigned u = __float_as_uint(f);
    return (u + 0x7fffu + ((u >> 16) & 1u)) >> 16;
}
__device__ inline float bfl(unsigned u) { return __uint_as_float(u << 16); }
__device__ inline float bfh(unsigned u) { return __uint_as_float(u & 0xffff0000u); }

// ---- conv: dense row transform -> bf16-packed hs -----------------------
__global__ void mm_scale_kernel(const float* __restrict__ in_rows, const float* __restrict__ in_stat,
                                const float* __restrict__ W, const float* __restrict__ norm,
                                unsigned* __restrict__ hsb, int nrows, int rlo, int rhi) {
    constexpr int FIN = DYNF + STATF;
    __shared__ float Ws[FIN * DYNF];
    for (int i = threadIdx.x; i < FIN * DYNF; i += blockDim.x) Ws[i] = W[i];
    __syncthreads();
    int r = blockIdx.x * blockDim.x + threadIdx.x;
    if (r >= nrows) return;
    float in[FIN];
    const float4* ip = (const float4*)(in_rows + (size_t)r * DYNF);
#pragma unroll
    for (int q = 0; q < DYNF / 4; q++) {
        float4 v = ip[q];
        in[q * 4 + 0] = v.x; in[q * 4 + 1] = v.y; in[q * 4 + 2] = v.z; in[q * 4 + 3] = v.w;
    }
    if (r < NLK ? rlo : rhi) {
#pragma unroll
        for (int j = 0; j < DYNF; j++) in[j] = fmaxf(in[j], 0.f);
    }
    const float4* sp = (const float4*)(in_stat + (size_t)r * STATF);
#pragma unroll
    for (int q = 0; q < STATF / 4; q++) {
        float4 v = sp[q];
        in[DYNF + q * 4 + 0] = v.x; in[DYNF + q * 4 + 1] = v.y;
        in[DYNF + q * 4 + 2] = v.z; in[DYNF + q * 4 + 3] = v.w;
    }
    float o[DYNF];
#pragma unroll
    for (int j = 0; j < DYNF; j++) o[j] = 0.f;
#pragma unroll
    for (int k = 0; k < FIN; k++) {
        float a = in[k];
#pragma unroll
        for (int j = 0; j < DYNF; j++) o[j] = fmaf(a, Ws[k * DYNF + j], o[j]);
    }
    float nm = norm[r];
    unsigned* hp = hsb + (size_t)r * (DYNF / 2);
#pragma unroll
    for (int k = 0; k < DYNF / 2; k++)
        hp[k] = bf16rne(o[2 * k] * nm) | (bf16rne(o[2 * k + 1] * nm) << 16);
}

// CSR pull over bf16 rows (8 thr/row): out[r] = norm[r]*(hsb[r] + sum hsb[col[e]]) + b
__global__ void pull_kernel(const int* __restrict__ rp, const int* __restrict__ col,
                            const unsigned* __restrict__ hsb, const float* __restrict__ nrm,
                            const float* __restrict__ b, float* __restrict__ out,
                            int row_lo, int n_rows) {
    int tid = blockIdx.x * blockDim.x + threadIdx.x;
    int rr = tid >> 3;
    if (rr >= n_rows) return;
    int r = row_lo + rr;
    int hw = (tid & 7) * 2;
    int e0 = rp[r], e1 = rp[r + 1];
    uint2 sv = *(const uint2*)(hsb + (size_t)r * 16 + hw);
    float a0 = bfl(sv.x), a1 = bfh(sv.x), a2 = bfl(sv.y), a3 = bfh(sv.y);
    for (int e = e0; e < e1; e++) {
        int s = col[e];
        uint2 v = *(const uint2*)(hsb + (size_t)s * 16 + hw);
        a0 += bfl(v.x); a1 += bfh(v.x); a2 += bfl(v.y); a3 += bfh(v.y);
    }
    float nm = nrm[r];
    int q = hw * 2;
    float4 bv = *(const float4*)(b + q);
    *(float4*)(out + (size_t)r * DYNF + q) =
        make_float4(fmaf(a0, nm, bv.x), fmaf(a1, nm, bv.y),
                    fmaf(a2, nm, bv.z), fmaf(a3, nm, bv.w));
}

// ---- up conv in 4-dim space: fused pull4 + 4x32 matmul -----------------

__global__ void xs_kernel(const float* __restrict__ x, const float* __restrict__ nrm,
                          float* __restrict__ xs, int n) {
    int r = blockIdx.x * blockDim.x + threadIdx.x;
    if (r >= n) return;
    float nm = nrm[r];
    float4 v = *(const float4*)(x + (size_t)r * 4);
    *(float4*)(xs + (size_t)r * 4) = make_float4(v.x * nm, v.y * nm, v.z * nm, v.w * nm);
}

__global__ void pull4mm_kernel(const int* __restrict__ rp, const int* __restrict__ col,
                               const float* __restrict__ xs, const float* __restrict__ W,
                               const float* __restrict__ nrm, const float* __restrict__ b,
                               float* __restrict__ h, int n) {
    __shared__ float Ws[4 * DYNF];
    __shared__ float bs[DYNF];
    for (int i = threadIdx.x; i < 4 * DYNF; i += blockDim.x) Ws[i] = W[i];
    for (int i = threadIdx.x; i < DYNF; i += blockDim.x) bs[i] = b[i];
    __syncthreads();
    int r = blockIdx.x * blockDim.x + threadIdx.x;
    if (r >= n) return;
    int e0 = rp[r], e1 = rp[r + 1];
    float4 acc = *(const float4*)(xs + (size_t)r * 4);
    for (int e = e0; e < e1; e++) {
        int s = col[e];
        float4 v = *(const float4*)(xs + (size_t)s * 4);
        acc.x += v.x; acc.y += v.y; acc.z += v.z; acc.w += v.w;
    }
    float nm = nrm[r];
    float4* hp = (float4*)(h + (size_t)r * DYNF);
#pragma unroll
    for (int q = 0; q < DYNF / 4; q++) {
        float4 o;
        o.x = acc.x * Ws[0 * DYNF + q * 4 + 0] + acc.y * Ws[1 * DYNF + q * 4 + 0] +
              acc.z * Ws[2 * DYNF + q * 4 + 0] + acc.w * Ws[3 * DYNF + q * 4 + 0];
        o.y = acc.x * Ws[0 * DYNF + q * 4 + 1] + acc.y * Ws[1 * DYNF + q * 4 + 1] +
              acc.z * Ws[2 * DYNF + q * 4 + 1] + acc.w * Ws[3 * DYNF + q * 4 + 1];
        o.z = acc.x * Ws[0 * DYNF + q * 4 + 2] + acc.y * Ws[1 * DYNF + q * 4 + 2] +
              acc.z * Ws[2 * DYNF + q * 4 + 2] + acc.w * Ws[3 * DYNF + q * 4 + 2];
        o.w = acc.x * Ws[0 * DYNF + q * 4 + 3] + acc.y * Ws[1 * DYNF + q * 4 + 3] +
              acc.z * Ws[2 * DYNF + q * 4 + 3] + acc.w * Ws[3 * DYNF + q * 4 + 3];
        hp[q] = make_float4(fmaf(o.x, nm, bs[q * 4 + 0]), fmaf(o.y, nm, bs[q * 4 + 1]),
                            fmaf(o.z, nm, bs[q * 4 + 2]), fmaf(o.w, nm, bs[q * 4 + 3]));
    }
}

// ---- epilogue ----------------------------------------------------------

__global__ void init_out_kernel(float* out, const float* __restrict__ lin_b) {
    int i = threadIdx.x;
    if (i < GG) out[i] = lin_b[0];
}

__global__ void pool_kernel(const float* __restrict__ h, const int* __restrict__ gids,
                            const float* __restrict__ linW, float* out) {
    __shared__ float part[GG];
    int t = threadIdx.x;
    if (t < GG) part[t] = 0.f;
    __syncthreads();
    int r = blockIdx.x * blockDim.x + t;
    float dotv = 0.f;
    const float4* hp = (const float4*)(h + (size_t)r * DYNF);
#pragma unroll
    for (int q = 0; q < 8; q++) {
        float4 v = hp[q];
        dotv += fmaxf(v.x, 0.f) * linW[q * 4 + 0] + fmaxf(v.y, 0.f) * linW[q * 4 + 1] +
                fmaxf(v.z, 0.f) * linW[q * 4 + 2] + fmaxf(v.w, 0.f) * linW[q * 4 + 3];
    }
    atomicAdd(&part[gids[r]], dotv);
    __syncthreads();
    if (t < GG) unsafeAtomicAdd(&out[t], part[t]);
}

// ------------------------------------------------------------------------

extern "C" void kernel_launch(void* const* d_in, const int* in_sizes, int n_in,
                              void* d_out, int out_size, void* d_ws, size_t ws_size,
                              hipStream_t stream) {
    const float* x     = (const float*)d_in[0];
    const float* stat  = (const float*)d_in[1];
    const int*   e_up  = (const int*)d_in[2];
    const int*   e_in  = (const int*)d_in[3];
    const int*   e_f   = (const int*)d_in[4];
    const int*   e_b   = (const int*)d_in[5];
    const int*   gids  = (const int*)d_in[6];
    const float* W_up  = (const float*)d_in[7];
    const float* b_up  = (const float*)d_in[8];
    const float* W_in  = (const float*)d_in[9];
    const float* b_in  = (const float*)d_in[10];
    const float* W_f   = (const float*)d_in[11];
    const float* b_f   = (const float*)d_in[12];
    const float* W_b   = (const float*)d_in[13];
    const float* b_b   = (const float*)d_in[14];
    const float* lin_W = (const float*)d_in[15];
    const float* lin_b = (const float*)d_in[16];
    float* out = (float*)d_out;

    // workspace carve (~130 MB peak)
    // [0, 58.7MB): build phase = pairs; conv phase = h (33.6) + hsb (8.4)
    unsigned* pairs = (unsigned*)d_ws;                       // CO_TOT u32
    float*    h     = (float*)d_ws;                          // NN*32 f32 (alias)
    unsigned* hsb   = (unsigned*)(h + (size_t)NN * DYNF);    // 2*NLK*16 u32 (alias)
    float*    xs    = (float*)hsb;                           // up phase (4.2 MB of hsb's 8.4)
    float*    norms = (float*)((char*)d_ws + (size_t)CO_TOT * 4);  // NS_TOT
    int*      rp    = (int*)(norms + NS_TOT);                // NS_TOT + 1
    int*      col   = rp + NS_TOT + 1;                       // CO_TOT
    int*      hmat  = col + CO_TOT;                          // HM
    int*      smat  = hmat + HM;                             // HM + 1
    int*      part  = smat + HM + 1;                         // 1024

    // ---- build: zero-global-atomic radix partition + LDS-staged grouping ----
    hist_part_kernel<<<NB, 256, 0, stream>>>(e_up, e_in, e_f, e_b, hmat);
    scan1_kernel<<<HM / 1024, 1024, 0, stream>>>(hmat, smat, part, HM);
    scan2_kernel<<<1, 256, 0, stream>>>(part, HM / 1024);
    scan3_kernel<<<cdiv(HM, 256), 256, 0, stream>>>(smat, part, HM);
    scatter_part_kernel<<<NB, 256, 0, stream>>>(e_up, e_in, e_f, e_b, smat, pairs);
    group_kernel<<<NBUCK, 256, 0, stream>>>(pairs, smat, col, rp, norms);

    // ---- up conv in 4-dim space (pairs region now dead; h/hsb live) ----
    xs_kernel<<<cdiv(NN, 256), 256, 0, stream>>>(x, norms + NS_UP, xs, NN);
    pull4mm_kernel<<<cdiv(NN, 256), 256, 0, stream>>>(rp + NS_UP, col, xs, W_up,
                                                      norms + NS_UP, b_up, h, NN);

    // ---- window conv driver (bf16 payload, fused relu flags) ----
    auto conv = [&](const float* in_rows, const float* in_stat, const float* W,
                    const float* bias, int ns, int gbase, int nwin,
                    int row_lo, int n_pull, int rlo, int rhi) {
        mm_scale_kernel<<<cdiv(nwin, 256), 256, 0, stream>>>(
            in_rows, in_stat, W, norms + ns, hsb, nwin, rlo, rhi);
        pull_kernel<<<cdiv((long)n_pull * 8, 256), 256, 0, stream>>>(
            rp + ns, col, hsb, norms + ns, bias,
            h + (size_t)gbase * DYNF, row_lo, n_pull);
    };

    auto inner = [&](int l, int rl) {
        int s = l * NLK;
        conv(h + (size_t)s * DYNF, stat + (size_t)s * STATF, W_in, b_in,
             NS_IN(l), s, NLK, 0, NLK, rl, rl);
    };
    auto fwd = [&](int l, int rhi) {
        int s = l * NLK;
        conv(h + (size_t)s * DYNF, stat + (size_t)s * STATF, W_f, b_f,
             NS_F(l), s, 2 * NLK, NLK, NLK, 0, rhi);
    };
    auto bwd = [&](int lm1, int rlo, int rhi) {
        int s = lm1 * NLK;
        conv(h + (size_t)s * DYNF, stat + (size_t)s * STATF, W_b, b_b,
             NS_B(lm1), s, 2 * NLK, 0, NLK, rlo, rhi);
    };

    for (int p = 0; p < 2; p++) {
        for (int l = 0; l < 4; l++) {
            inner(l, (l == 0 && p == 1) ? 1 : 0);
            if (l < 3) fwd(l, (p == 1) ? 1 : 0);
        }
        bwd(2, 1, 1); inner(2, 0);
        bwd(1, 1, 0); inner(1, 0);
        bwd(0, 1, 0); inner(0, 0);
    }

    init_out_kernel<<<1, 64, 0, stream>>>(out, lin_b);
    pool_kernel<<<NN / 256, 256, 0, stream>>>(h, gids, lin_W, out);
}

// Round 12
// 1221.705 us; speedup vs baseline: 7.6532x; 1.0921x over previous
//
#include <hip/hip_runtime.h>

#define NLK 65536
#define NN (NLK * 4)        // 262144 nodes
#define DYNF 32
#define STATF 8
#define GG 64
#define EUP 4194304
#define EIN 1048576
#define EFB 1048576

// unified row space: [up: NN][inner: 4*NLK][fwd: 3*2NLK][bwd: 3*2NLK]
#define NS_UP    0
#define NS_IN(l) (NN + (l) * NLK)
#define NS_F(l)  (NN + 4 * NLK + (l) * 2 * NLK)
#define NS_B(l)  (NN + 10 * NLK + (l) * 2 * NLK)
#define NS_TOT   (NN + 16 * NLK)                    // 1,310,720
#define CO_TOT   (EUP + 4 * EIN + 6 * EFB)          // 14,680,064

#define CHUNK 16384                                 // edges per partition block
#define NB    (CO_TOT / CHUNK)                      // 896 partition blocks
#define BROWS 1024                                  // rows per bucket
#define NBUCK (NS_TOT / BROWS)                      // 1280 buckets
#define HM    (NBUCK * NB)                          // 1,146,880
#define SCAP  20480                                 // LDS sort capacity

static inline int cdiv(long a, int b) { return (int)((a + b - 1) / b); }

// ---- which list does partition block b cover? --------------------------
__device__ inline void cdecode(int b, const int* e_up, const int* e_in,
                               const int* e_f, const int* e_b,
                               const int*& srcp, const int*& dstp, int& ns, int& e0) {
    if (b < EUP / CHUNK) { srcp = e_up; dstp = e_up + EUP; ns = NS_UP; e0 = b * CHUNK; return; }
    int t = b - EUP / CHUNK;
    int list = t >> 6;                               // 64 blocks per small list
    e0 = (t & 63) * CHUNK;
    if (list < 4) {
        srcp = e_in + (size_t)(2 * list) * EIN; dstp = srcp + EIN; ns = NS_IN(list);
    } else if (list < 7) {
        int l = list - 4;
        srcp = e_f + (size_t)(2 * l) * EFB; dstp = srcp + EFB; ns = NS_F(l);
    } else {
        int l = list - 7;
        srcp = e_b + (size_t)(2 * l) * EFB; dstp = srcp + EFB; ns = NS_B(l);
    }
}

// ---- pass 1: per-block LDS bucket histogram ---------------------------
__global__ void hist_part_kernel(const int* __restrict__ e_up, const int* __restrict__ e_in,
                                 const int* __restrict__ e_f, const int* __restrict__ e_b,
                                 int* __restrict__ hmat) {
    __shared__ int lh[NBUCK];
    for (int k = threadIdx.x; k < NBUCK; k += 256) lh[k] = 0;
    __syncthreads();
    const int *srcp, *dstp; int ns, e0;
    cdecode(blockIdx.x, e_up, e_in, e_f, e_b, srcp, dstp, ns, e0);
    for (int j = 0; j < CHUNK / 256; j++) {
        int g = ns + dstp[e0 + j * 256 + threadIdx.x];
        atomicAdd(&lh[g >> 10], 1);
    }
    __syncthreads();
    for (int k = threadIdx.x; k < NBUCK; k += 256)
        hmat[(size_t)k * NB + blockIdx.x] = lh[k];
}

// ---- pass 2: scatter into per-(bucket,block) reserved slices ----------
__global__ void scatter_part_kernel(const int* __restrict__ e_up, const int* __restrict__ e_in,
                                    const int* __restrict__ e_f, const int* __restrict__ e_b,
                                    const int* __restrict__ smat, unsigned* __restrict__ pairs) {
    __shared__ int cur[NBUCK];
    const int *srcp, *dstp; int ns, e0;
    cdecode(blockIdx.x, e_up, e_in, e_f, e_b, srcp, dstp, ns, e0);
    for (int k = threadIdx.x; k < NBUCK; k += 256)
        cur[k] = smat[(size_t)k * NB + blockIdx.x];
    __syncthreads();
    for (int j = 0; j < CHUNK / 256; j++) {
        int el = e0 + j * 256 + threadIdx.x;
        int g = ns + dstp[el];
        int s = srcp[el];
        int pos = atomicAdd(&cur[g >> 10], 1);
        pairs[pos] = ((unsigned)s << 10) | (unsigned)(g & (BROWS - 1));
    }
}

// ---- pass 3: per-bucket group; LDS-staged sort -> sequential col ------
__global__ void group_kernel(const unsigned* __restrict__ pairs, const int* __restrict__ smat,
                             int* __restrict__ col, int* __restrict__ rp,
                             float* __restrict__ norms) {
    __shared__ int srt[SCAP];
    __shared__ int lcnt[BROWS];
    __shared__ int roff[BROWS];
    __shared__ int lcur[BROWS];
    __shared__ int ssum[256];
    int k = blockIdx.x;
    int t = threadIdx.x;
    int base = smat[(size_t)k * NB];
    int end  = (k + 1 < NBUCK) ? smat[(size_t)(k + 1) * NB] : CO_TOT;
    int nb = end - base;
    for (int j = t; j < BROWS; j += 256) { lcnt[j] = 0; lcur[j] = 0; }
    __syncthreads();
    for (int i = base + t; i < end; i += 256)
        atomicAdd(&lcnt[pairs[i] & (BROWS - 1)], 1);
    __syncthreads();
    constexpr int RPT = BROWS / 256;                 // 4
    int a[RPT];
    int gsum = 0;
#pragma unroll
    for (int j = 0; j < RPT; j++) { a[j] = lcnt[RPT * t + j]; gsum += a[j]; }
    ssum[t] = gsum;
    __syncthreads();
    for (int off = 1; off < 256; off <<= 1) {
        int u = (t >= off) ? ssum[t - off] : 0;
        __syncthreads();
        ssum[t] += u;
        __syncthreads();
    }
    int run = ssum[t] - gsum;
    int row0 = k * BROWS + RPT * t;
#pragma unroll
    for (int j = 0; j < RPT; j++) {
        roff[RPT * t + j] = run;
        rp[row0 + j] = base + run;
        norms[row0 + j] = rsqrtf((float)(a[j] + 1));
        run += a[j];
    }
    if (k == 0 && t == 0) rp[NS_TOT] = CO_TOT;
    __syncthreads();
    if (nb <= SCAP) {
        for (int i = base + t; i < end; i += 256) {
            unsigned p = pairs[i];
            int rl = p & (BROWS - 1);
            int pos = roff[rl] + atomicAdd(&lcur[rl], 1);
            srt[pos] = (int)(p >> 10);
        }
        __syncthreads();
        for (int j = t; j < nb; j += 256)
            col[base + j] = srt[j];
    } else {
        for (int i = base + t; i < end; i += 256) {
            unsigned p = pairs[i];
            int rl = p & (BROWS - 1);
            int pos = base + roff[rl] + atomicAdd(&lcur[rl], 1);
            col[pos] = (int)(p >> 10);
        }
    }
}

// ---- global scan ------------------------------------------------------

__global__ void scan1_kernel(const int* __restrict__ cnt, int* __restrict__ rp,
                             int* __restrict__ part, int n) {
    __shared__ int sh[1024];
    int t = threadIdx.x;
    int i = blockIdx.x * 1024 + t;
    int v = (i < n) ? cnt[i] : 0;
    sh[t] = v;
    __syncthreads();
    for (int off = 1; off < 1024; off <<= 1) {
        int u = (t >= off) ? sh[t - off] : 0;
        __syncthreads();
        sh[t] += u;
        __syncthreads();
    }
    if (i < n) rp[i] = sh[t] - v;
    if (t == 1023) part[blockIdx.x] = sh[1023];
}

__global__ void scan2_kernel(int* part, int m) {
    __shared__ int sh[256];
    __shared__ int carry;
    int t = threadIdx.x;
    if (t == 0) carry = 0;
    __syncthreads();
    for (int base = 0; base < m; base += 256) {
        int i = base + t;
        int v = (i < m) ? part[i] : 0;
        sh[t] = v;
        __syncthreads();
        for (int off = 1; off < 256; off <<= 1) {
            int u = (t >= off) ? sh[t - off] : 0;
            __syncthreads();
            sh[t] += u;
            __syncthreads();
        }
        if (i < m) part[i] = sh[t] - v + carry;
        __syncthreads();
        if (t == 255) carry += sh[255];
        __syncthreads();
    }
}

__global__ void scan3_kernel(int* __restrict__ rp, const int* __restrict__ part, int n) {
    int i = blockIdx.x * blockDim.x + threadIdx.x;
    if (i < n) rp[i] += part[i >> 10];
}

// ---- bf16 helpers ------------------------------------------------------

__device__ inline unsigned bf16rne(float f) {
    unsigned u = __float_as_uint(f);
    return (u + 0x7fffu + ((u >> 16) & 1u)) >> 16;
}
__device__ inline float bfl(unsigned u) { return __uint_as_float(u << 16); }
__device__ inline float bfh(unsigned u) { return __uint_as_float(u & 0xffff0000u); }

// ---- fused pull + pack-emission ----------------------------------------
// Phase 1 (8 thr/row): out[r] = nrm[r]*(hsb_in[r] + sum hsb_in[col[e]]) + b.
// Phase 2: for each emission, emit bf16( em.nrm[rr] * ([relu?(out_row), stat_row] @ em.W) )
// into em.hsb (the CONSUMER conv's packed input buffer).

struct EmitArg {
    const float* nrm;    // consumer norm, index [rr]
    unsigned*    hsb;    // consumer packed buffer, write at rr*16 + j*2
    const float* W;      // 40x32 weights (global)
    int relu;
    int on;
};

__global__ void pull_emit_kernel(const int* __restrict__ rp, const int* __restrict__ col,
                                 const unsigned* __restrict__ hsb_in, const float* __restrict__ nrm,
                                 const float* __restrict__ b, float* __restrict__ out,
                                 const float* __restrict__ stat_p, int row_lo, int write_h,
                                 EmitArg em0, EmitArg em1) {
    __shared__ float W0[1280];
    __shared__ float W1[1280];
    __shared__ float rowbuf[32][41];
    int t = threadIdx.x;
    if (em0.on) for (int i = t; i < 1280; i += 256) W0[i] = em0.W[i];
    if (em1.on) for (int i = t; i < 1280; i += 256) W1[i] = em1.W[i];
    int tid = blockIdx.x * 256 + t;
    int rr = tid >> 3;
    int r = row_lo + rr;
    int j = tid & 7;
    int hw = j * 2;
    int ea = rp[r], eb = rp[r + 1];
    uint2 sv = *(const uint2*)(hsb_in + (size_t)r * 16 + hw);
    float a0 = bfl(sv.x), a1 = bfh(sv.x), a2 = bfl(sv.y), a3 = bfh(sv.y);
    for (int e = ea; e < eb; e++) {
        int s = col[e];
        uint2 v = *(const uint2*)(hsb_in + (size_t)s * 16 + hw);
        a0 += bfl(v.x); a1 += bfh(v.x); a2 += bfl(v.y); a3 += bfh(v.y);
    }
    float nm = nrm[r];
    int q = j * 4;
    float4 bv = *(const float4*)(b + q);
    float o0 = fmaf(a0, nm, bv.x), o1 = fmaf(a1, nm, bv.y);
    float o2 = fmaf(a2, nm, bv.z), o3 = fmaf(a3, nm, bv.w);
    if (write_h)
        *(float4*)(out + (size_t)r * DYNF + q) = make_float4(o0, o1, o2, o3);
    if (!em0.on && !em1.on) return;
    int lrow = t >> 3;
    rowbuf[lrow][q] = o0; rowbuf[lrow][q + 1] = o1;
    rowbuf[lrow][q + 2] = o2; rowbuf[lrow][q + 3] = o3;
    rowbuf[lrow][32 + j] = stat_p[(size_t)rr * 8 + j];
    __syncthreads();
    if (em0.on) {
        float nmc = em0.nrm[rr];
        float r0 = 0, r1 = 0, r2 = 0, r3 = 0;
#pragma unroll
        for (int k = 0; k < 40; k++) {
            float v = rowbuf[lrow][k];
            if (k < 32 && em0.relu) v = fmaxf(v, 0.f);
            const float* Wp = &W0[k * 32 + q];
            r0 = fmaf(v, Wp[0], r0); r1 = fmaf(v, Wp[1], r1);
            r2 = fmaf(v, Wp[2], r2); r3 = fmaf(v, Wp[3], r3);
        }
        unsigned u0 = bf16rne(r0 * nmc) | (bf16rne(r1 * nmc) << 16);
        unsigned u1 = bf16rne(r2 * nmc) | (bf16rne(r3 * nmc) << 16);
        *(uint2*)(em0.hsb + (size_t)rr * 16 + hw) = make_uint2(u0, u1);
    }
    if (em1.on) {
        float nmc = em1.nrm[rr];
        float r0 = 0, r1 = 0, r2 = 0, r3 = 0;
#pragma unroll
        for (int k = 0; k < 40; k++) {
            float v = rowbuf[lrow][k];
            if (k < 32 && em1.relu) v = fmaxf(v, 0.f);
            const float* Wp = &W1[k * 32 + q];
            r0 = fmaf(v, Wp[0], r0); r1 = fmaf(v, Wp[1], r1);
            r2 = fmaf(v, Wp[2], r2); r3 = fmaf(v, Wp[3], r3);
        }
        unsigned u0 = bf16rne(r0 * nmc) | (bf16rne(r1 * nmc) << 16);
        unsigned u1 = bf16rne(r2 * nmc) | (bf16rne(r3 * nmc) << 16);
        *(uint2*)(em1.hsb + (size_t)rr * 16 + hw) = make_uint2(u0, u1);
    }
}

// ---- up conv: 4-dim pull + 4x32 matmul + per-layer pack emission -------

__global__ void xs_kernel(const float* __restrict__ x, const float* __restrict__ nrm,
                          float* __restrict__ xs, int n) {
    int r = blockIdx.x * blockDim.x + threadIdx.x;
    if (r >= n) return;
    float nm = nrm[r];
    float4 v = *(const float4*)(x + (size_t)r * 4);
    *(float4*)(xs + (size_t)r * 4) = make_float4(v.x * nm, v.y * nm, v.z * nm, v.w * nm);
}

struct UpEmit {
    const float* n0; const float* n1; const float* n2; const float* n3;
    unsigned* h0; unsigned* h1; unsigned* h2; unsigned* h3;
};

__global__ void pull4mm_emit_kernel(const int* __restrict__ rp0, const int* __restrict__ col,
                                    const float* __restrict__ xs, const float* __restrict__ Wup,
                                    const float* __restrict__ nrm, const float* __restrict__ bup,
                                    const float* __restrict__ Win, const float* __restrict__ Wf,
                                    const float* __restrict__ stat, UpEmit ue) {
    __shared__ float Ws[128];
    __shared__ float bs[32];
    __shared__ float Wa[1280];
    __shared__ float Wb[1280];
    int t = threadIdx.x;
    for (int i = t; i < 128; i += 256) Ws[i] = Wup[i];
    if (t < 32) bs[t] = bup[t];
    for (int i = t; i < 1280; i += 256) { Wa[i] = Win[i]; Wb[i] = Wf[i]; }
    __syncthreads();
    int g = blockIdx.x * 256 + t;                   // NN grid exact
    int ea = rp0[g], eb = rp0[g + 1];
    float4 acc = *(const float4*)(xs + (size_t)g * 4);
    for (int e = ea; e < eb; e++) {
        int s = col[e];
        float4 v = *(const float4*)(xs + (size_t)s * 4);
        acc.x += v.x; acc.y += v.y; acc.z += v.z; acc.w += v.w;
    }
    float nm = nrm[g];
    float o[32];
#pragma unroll
    for (int d = 0; d < 32; d++) {
        float s = acc.x * Ws[d] + acc.y * Ws[32 + d] + acc.z * Ws[64 + d] + acc.w * Ws[96 + d];
        o[d] = fmaf(s, nm, bs[d]);
    }
    int l = g >> 16;
    const float* W = (l == 0) ? Wa : Wb;
    const float* nc = (l == 0) ? ue.n0 : (l == 1) ? ue.n1 : (l == 2) ? ue.n2 : ue.n3;
    unsigned* hc = (((l == 0) ? ue.h0 : (l == 1) ? ue.h1 : (l == 2) ? ue.h2 : ue.h3)) + (size_t)g * 16;
    float nmc = nc[g];
    float st[8];
#pragma unroll
    for (int k = 0; k < 8; k++) st[k] = stat[(size_t)g * 8 + k];
    float res[32];
#pragma unroll
    for (int d = 0; d < 32; d++) res[d] = 0.f;
#pragma unroll
    for (int k = 0; k < 32; k++) {
        float v = o[k];
#pragma unroll
        for (int d = 0; d < 32; d++) res[d] = fmaf(v, W[k * 32 + d], res[d]);
    }
#pragma unroll
    for (int k = 0; k < 8; k++) {
        float v = st[k];
#pragma unroll
        for (int d = 0; d < 32; d++) res[d] = fmaf(v, W[(32 + k) * 32 + d], res[d]);
    }
#pragma unroll
    for (int kk = 0; kk < 16; kk++)
        hc[kk] = bf16rne(res[2 * kk] * nmc) | (bf16rne(res[2 * kk + 1] * nmc) << 16);
}

// ---- epilogue ----------------------------------------------------------

__global__ void init_out_kernel(float* out, const float* __restrict__ lin_b) {
    int i = threadIdx.x;
    if (i < GG) out[i] = lin_b[0];
}

__global__ void pool_kernel(const float* __restrict__ h, const int* __restrict__ gids,
                            const float* __restrict__ linW, float* out) {
    __shared__ float part[GG];
    int t = threadIdx.x;
    if (t < GG) part[t] = 0.f;
    __syncthreads();
    int r = blockIdx.x * blockDim.x + t;
    float dotv = 0.f;
    const float4* hp = (const float4*)(h + (size_t)r * DYNF);
#pragma unroll
    for (int q = 0; q < 8; q++) {
        float4 v = hp[q];
        dotv += fmaxf(v.x, 0.f) * linW[q * 4 + 0] + fmaxf(v.y, 0.f) * linW[q * 4 + 1] +
                fmaxf(v.z, 0.f) * linW[q * 4 + 2] + fmaxf(v.w, 0.f) * linW[q * 4 + 3];
    }
    atomicAdd(&part[gids[r]], dotv);
    __syncthreads();
    if (t < GG) unsafeAtomicAdd(&out[t], part[t]);
}

// ------------------------------------------------------------------------

extern "C" void kernel_launch(void* const* d_in, const int* in_sizes, int n_in,
                              void* d_out, int out_size, void* d_ws, size_t ws_size,
                              hipStream_t stream) {
    const float* x     = (const float*)d_in[0];
    const float* stat  = (const float*)d_in[1];
    const int*   e_up  = (const int*)d_in[2];
    const int*   e_in  = (const int*)d_in[3];
    const int*   e_f   = (const int*)d_in[4];
    const int*   e_b   = (const int*)d_in[5];
    const int*   gids  = (const int*)d_in[6];
    const float* W_up  = (const float*)d_in[7];
    const float* b_up  = (const float*)d_in[8];
    const float* W_in  = (const float*)d_in[9];
    const float* b_in  = (const float*)d_in[10];
    const float* W_f   = (const float*)d_in[11];
    const float* b_f   = (const float*)d_in[12];
    const float* W_b   = (const float*)d_in[13];
    const float* b_b   = (const float*)d_in[14];
    const float* lin_W = (const float*)d_in[15];
    const float* lin_b = (const float*)d_in[16];
    float* out = (float*)d_out;

    // ---- workspace carve (~170 MB peak) ----
    // shared (build+conv): norms, rp, col.  build-only: pairs,hmat,smat,part
    // (aliased into the conv-only h/hsbpool region; dead before those are written).
    float*    norms = (float*)d_ws;                              // NS_TOT
    int*      rp    = (int*)(norms + NS_TOT);                    // NS_TOT+1
    int*      col   = rp + NS_TOT + 1;                           // CO_TOT
    unsigned* H0    = (unsigned*)(col + CO_TOT);                 // conv region base
    float*    h     = (float*)H0;                                // NN*32 f32
    unsigned* hsbp  = H0 + (size_t)NN * DYNF;                    // pack pool: 16*NLK rows *16 u32
    float*    xs    = (float*)hsbp;                              // up phase alias (NN*4 f32 = 4.2MB)
    unsigned* pairs = H0;                                        // build alias (CO_TOT u32)
    int*      hmat  = (int*)(H0 + CO_TOT);                       // HM
    int*      smat  = hmat + HM;                                 // HM
    int*      part  = smat + HM;                                 // 1120

    // pack-buffer slots (rows of 16 u32); lifetimes verified disjoint:
    unsigned* SA  = hsbp + (size_t)0  * NLK * 16;   // {I0, I3}
    unsigned* SB  = hsbp + (size_t)1  * NLK * 16;   // {I1, i1}
    unsigned* SC  = hsbp + (size_t)2  * NLK * 16;   // {I2, i2}
    unsigned* SD  = hsbp + (size_t)3  * NLK * 16;   // {i0}
    unsigned* F0b = hsbp + (size_t)4  * NLK * 16;   // 2NLK
    unsigned* F1b = hsbp + (size_t)6  * NLK * 16;
    unsigned* F2b = hsbp + (size_t)8  * NLK * 16;
    unsigned* B0b = hsbp + (size_t)10 * NLK * 16;
    unsigned* B1b = hsbp + (size_t)12 * NLK * 16;
    unsigned* B2b = hsbp + (size_t)14 * NLK * 16;

    // ---- build: zero-global-atomic radix partition + LDS-staged grouping ----
    hist_part_kernel<<<NB, 256, 0, stream>>>(e_up, e_in, e_f, e_b, hmat);
    scan1_kernel<<<HM / 1024, 1024, 0, stream>>>(hmat, smat, part, HM);
    scan2_kernel<<<1, 256, 0, stream>>>(part, HM / 1024);
    scan3_kernel<<<cdiv(HM, 256), 256, 0, stream>>>(smat, part, HM);
    scatter_part_kernel<<<NB, 256, 0, stream>>>(e_up, e_in, e_f, e_b, smat, pairs);
    group_kernel<<<NBUCK, 256, 0, stream>>>(pairs, smat, col, rp, norms);

    // ---- up conv: xs = x*norm; fused pull4 + matmul + per-layer pack ----
    xs_kernel<<<cdiv(NN, 256), 256, 0, stream>>>(x, norms + NS_UP, xs, NN);
    UpEmit ue;
    ue.n0 = norms + NS_IN(0);
    ue.n1 = norms + NS_F(0);
    ue.n2 = norms + NS_F(1) - NLK;
    ue.n3 = norms + NS_F(2) - 2 * NLK;
    ue.h0 = SA;
    ue.h1 = F0b;
    ue.h2 = F1b - (size_t)NLK * 16;
    ue.h3 = F2b - (size_t)2 * NLK * 16;
    pull4mm_emit_kernel<<<NN / 256, 256, 0, stream>>>(rp + NS_UP, col, xs, W_up,
                                                      norms + NS_UP, b_up, W_in, W_f, stat, ue);

    // ---- fused conv chain: 13 pulls per pass, each emits its consumers' packs ----
    auto EM = [&](const float* n, unsigned* hb, const float* W, int rl) {
        EmitArg e; e.nrm = n; e.hsb = hb; e.W = W; e.relu = rl; e.on = 1; return e;
    };
    EmitArg OFF; OFF.nrm = nullptr; OFF.hsb = nullptr; OFF.W = nullptr; OFF.relu = 0; OFF.on = 0;

    auto P = [&](unsigned* buf, int ns, const float* bias, int gbase, int row_lo,
                 int wh, EmitArg a, EmitArg c) {
        pull_emit_kernel<<<(NLK * 8) / 256, 256, 0, stream>>>(
            rp + ns, col, buf, norms + ns, bias, h + (size_t)gbase * DYNF,
            stat + (size_t)(gbase + row_lo) * STATF, row_lo, wh, a, c);
    };

    for (int p = 0; p < 2; p++) {
        // A-loop
        P(SA, NS_IN(0), b_in, 0, 0, 0,
          EM(norms + NS_F(0), F0b, W_f, 0), EM(norms + NS_B(0), B0b, W_b, 1));        // I0
        P(F0b, NS_F(0), b_f, 0, NLK, 0,
          EM(norms + NS_IN(1), SB, W_in, 0), OFF);                                    // F0
        P(SB, NS_IN(1), b_in, NLK, 0, 0,
          EM(norms + NS_F(1), F1b, W_f, 0), EM(norms + NS_B(1), B1b, W_b, 1));        // I1
        P(F1b, NS_F(1), b_f, NLK, NLK, 0,
          EM(norms + NS_IN(2), SC, W_in, 0), OFF);                                    // F1
        P(SC, NS_IN(2), b_in, 2 * NLK, 0, 0,
          EM(norms + NS_F(2), F2b, W_f, 0), EM(norms + NS_B(2), B2b, W_b, 1));        // I2
        P(F2b, NS_F(2), b_f, 2 * NLK, NLK, 0,
          EM(norms + NS_IN(3), SA, W_in, 0), OFF);                                    // F2
        P(SA, NS_IN(3), b_in, 3 * NLK, 0, (p == 1),
          EM(norms + NS_B(2) + NLK, B2b + (size_t)NLK * 16, W_b, 1),
          p == 0 ? EM(norms + NS_F(2) + NLK, F2b + (size_t)NLK * 16, W_f, 1) : OFF);  // I3
        // B-loop
        P(B2b, NS_B(2), b_b, 2 * NLK, 0, 0,
          EM(norms + NS_IN(2), SC, W_in, 0), OFF);                                    // B2
        P(SC, NS_IN(2), b_in, 2 * NLK, 0, (p == 1),
          EM(norms + NS_B(1) + NLK, B1b + (size_t)NLK * 16, W_b, 0),
          p == 0 ? EM(norms + NS_F(1) + NLK, F1b + (size_t)NLK * 16, W_f, 1) : OFF);  // i2
        P(B1b, NS_B(1), b_b, NLK, 0, 0,
          EM(norms + NS_IN(1), SB, W_in, 0), OFF);                                    // B1
        P(SB, NS_IN(1), b_in, NLK, 0, (p == 1),
          EM(norms + NS_B(0) + NLK, B0b + (size_t)NLK * 16, W_b, 0),
          p == 0 ? EM(norms + NS_F(0) + NLK, F0b + (size_t)NLK * 16, W_f, 1) : OFF);  // i1
        P(B0b, NS_B(0), b_b, 0, 0, 0,
          EM(norms + NS_IN(0), SD, W_in, 0), OFF);                                    // B0
        P(SD, NS_IN(0), b_in, 0, 0, (p == 1),
          p == 0 ? EM(norms + NS_IN(0), SA, W_in, 1) : OFF, OFF);                     // i0
    }

    init_out_kernel<<<1, 64, 0, stream>>>(out, lin_b);
    pool_kernel<<<NN / 256, 256, 0, stream>>>(h, gids, lin_W, out);
}

// Round 13
// 1087.963 us; speedup vs baseline: 8.5940x; 1.1229x over previous
//
#include <hip/hip_runtime.h>

#define NLK 65536
#define NN (NLK * 4)        // 262144 nodes
#define DYNF 32
#define STATF 8
#define GG 64
#define EUP 4194304
#define EIN 1048576
#define EFB 1048576

// unified row space: [up: NN][inner: 4*NLK][fwd: 3*2NLK][bwd: 3*2NLK]
#define NS_UP    0
#define NS_IN(l) (NN + (l) * NLK)
#define NS_F(l)  (NN + 4 * NLK + (l) * 2 * NLK)
#define NS_B(l)  (NN + 10 * NLK + (l) * 2 * NLK)
#define NS_TOT   (NN + 16 * NLK)                    // 1,310,720
#define CO_TOT   (EUP + 4 * EIN + 6 * EFB)          // 14,680,064

#define CHUNK 16384                                 // edges per partition block
#define NB    (CO_TOT / CHUNK)                      // 896 partition blocks
#define BROWS 1024                                  // rows per bucket
#define NBUCK (NS_TOT / BROWS)                      // 1280 buckets
#define HM    (NBUCK * NB)                          // 1,146,880
#define SCAP  20480                                 // LDS sort capacity

static inline int cdiv(long a, int b) { return (int)((a + b - 1) / b); }

// ---- which list does partition block b cover? --------------------------
__device__ inline void cdecode(int b, const int* e_up, const int* e_in,
                               const int* e_f, const int* e_b,
                               const int*& srcp, const int*& dstp, int& ns, int& e0) {
    if (b < EUP / CHUNK) { srcp = e_up; dstp = e_up + EUP; ns = NS_UP; e0 = b * CHUNK; return; }
    int t = b - EUP / CHUNK;
    int list = t >> 6;                               // 64 blocks per small list
    e0 = (t & 63) * CHUNK;
    if (list < 4) {
        srcp = e_in + (size_t)(2 * list) * EIN; dstp = srcp + EIN; ns = NS_IN(list);
    } else if (list < 7) {
        int l = list - 4;
        srcp = e_f + (size_t)(2 * l) * EFB; dstp = srcp + EFB; ns = NS_F(l);
    } else {
        int l = list - 7;
        srcp = e_b + (size_t)(2 * l) * EFB; dstp = srcp + EFB; ns = NS_B(l);
    }
}

// ---- pass 1: per-block LDS bucket histogram ---------------------------
__global__ void hist_part_kernel(const int* __restrict__ e_up, const int* __restrict__ e_in,
                                 const int* __restrict__ e_f, const int* __restrict__ e_b,
                                 int* __restrict__ hmat) {
    __shared__ int lh[NBUCK];
    for (int k = threadIdx.x; k < NBUCK; k += 256) lh[k] = 0;
    __syncthreads();
    const int *srcp, *dstp; int ns, e0;
    cdecode(blockIdx.x, e_up, e_in, e_f, e_b, srcp, dstp, ns, e0);
    for (int j = 0; j < CHUNK / 256; j++) {
        int g = ns + dstp[e0 + j * 256 + threadIdx.x];
        atomicAdd(&lh[g >> 10], 1);
    }
    __syncthreads();
    for (int k = threadIdx.x; k < NBUCK; k += 256)
        hmat[(size_t)k * NB + blockIdx.x] = lh[k];
}

// ---- pass 2: scatter into per-(bucket,block) reserved slices ----------
__global__ void scatter_part_kernel(const int* __restrict__ e_up, const int* __restrict__ e_in,
                                    const int* __restrict__ e_f, const int* __restrict__ e_b,
                                    const int* __restrict__ smat, unsigned* __restrict__ pairs) {
    __shared__ int cur[NBUCK];
    const int *srcp, *dstp; int ns, e0;
    cdecode(blockIdx.x, e_up, e_in, e_f, e_b, srcp, dstp, ns, e0);
    for (int k = threadIdx.x; k < NBUCK; k += 256)
        cur[k] = smat[(size_t)k * NB + blockIdx.x];
    __syncthreads();
    for (int j = 0; j < CHUNK / 256; j++) {
        int el = e0 + j * 256 + threadIdx.x;
        int g = ns + dstp[el];
        int s = srcp[el];
        int pos = atomicAdd(&cur[g >> 10], 1);
        pairs[pos] = ((unsigned)s << 10) | (unsigned)(g & (BROWS - 1));
    }
}

// ---- pass 3: per-bucket group; LDS-staged sort -> sequential col ------
__global__ void group_kernel(const unsigned* __restrict__ pairs, const int* __restrict__ smat,
                             int* __restrict__ col, int* __restrict__ rp,
                             float* __restrict__ norms) {
    __shared__ int srt[SCAP];
    __shared__ int lcnt[BROWS];
    __shared__ int roff[BROWS];
    __shared__ int lcur[BROWS];
    __shared__ int ssum[256];
    int k = blockIdx.x;
    int t = threadIdx.x;
    int base = smat[(size_t)k * NB];
    int end  = (k + 1 < NBUCK) ? smat[(size_t)(k + 1) * NB] : CO_TOT;
    int nb = end - base;
    for (int j = t; j < BROWS; j += 256) { lcnt[j] = 0; lcur[j] = 0; }
    __syncthreads();
    for (int i = base + t; i < end; i += 256)
        atomicAdd(&lcnt[pairs[i] & (BROWS - 1)], 1);
    __syncthreads();
    constexpr int RPT = BROWS / 256;                 // 4
    int a[RPT];
    int gsum = 0;
#pragma unroll
    for (int j = 0; j < RPT; j++) { a[j] = lcnt[RPT * t + j]; gsum += a[j]; }
    ssum[t] = gsum;
    __syncthreads();
    for (int off = 1; off < 256; off <<= 1) {
        int u = (t >= off) ? ssum[t - off] : 0;
        __syncthreads();
        ssum[t] += u;
        __syncthreads();
    }
    int run = ssum[t] - gsum;
    int row0 = k * BROWS + RPT * t;
#pragma unroll
    for (int j = 0; j < RPT; j++) {
        roff[RPT * t + j] = run;
        rp[row0 + j] = base + run;
        norms[row0 + j] = rsqrtf((float)(a[j] + 1));
        run += a[j];
    }
    if (k == 0 && t == 0) rp[NS_TOT] = CO_TOT;
    __syncthreads();
    if (nb <= SCAP) {
        for (int i = base + t; i < end; i += 256) {
            unsigned p = pairs[i];
            int rl = p & (BROWS - 1);
            int pos = roff[rl] + atomicAdd(&lcur[rl], 1);
            srt[pos] = (int)(p >> 10);
        }
        __syncthreads();
        for (int j = t; j < nb; j += 256)
            col[base + j] = srt[j];
    } else {
        for (int i = base + t; i < end; i += 256) {
            unsigned p = pairs[i];
            int rl = p & (BROWS - 1);
            int pos = base + roff[rl] + atomicAdd(&lcur[rl], 1);
            col[pos] = (int)(p >> 10);
        }
    }
}

// ---- global scan ------------------------------------------------------

__global__ void scan1_kernel(const int* __restrict__ cnt, int* __restrict__ rp,
                             int* __restrict__ part, int n) {
    __shared__ int sh[1024];
    int t = threadIdx.x;
    int i = blockIdx.x * 1024 + t;
    int v = (i < n) ? cnt[i] : 0;
    sh[t] = v;
    __syncthreads();
    for (int off = 1; off < 1024; off <<= 1) {
        int u = (t >= off) ? sh[t - off] : 0;
        __syncthreads();
        sh[t] += u;
        __syncthreads();
    }
    if (i < n) rp[i] = sh[t] - v;
    if (t == 1023) part[blockIdx.x] = sh[1023];
}

__global__ void scan2_kernel(int* part, int m) {
    __shared__ int sh[256];
    __shared__ int carry;
    int t = threadIdx.x;
    if (t == 0) carry = 0;
    __syncthreads();
    for (int base = 0; base < m; base += 256) {
        int i = base + t;
        int v = (i < m) ? part[i] : 0;
        sh[t] = v;
        __syncthreads();
        for (int off = 1; off < 256; off <<= 1) {
            int u = (t >= off) ? sh[t - off] : 0;
            __syncthreads();
            sh[t] += u;
            __syncthreads();
        }
        if (i < m) part[i] = sh[t] - v + carry;
        __syncthreads();
        if (t == 255) carry += sh[255];
        __syncthreads();
    }
}

__global__ void scan3_kernel(int* __restrict__ rp, const int* __restrict__ part, int n) {
    int i = blockIdx.x * blockDim.x + threadIdx.x;
    if (i < n) rp[i] += part[i >> 10];
}

// ---- bf16 helpers ------------------------------------------------------

__device__ inline unsigned bf16rne(float f) {
    unsigned u = __float_as_uint(f);
    return (u + 0x7fffu + ((u >> 16) & 1u)) >> 16;
}
__device__ inline float bfl(unsigned u) { return __uint_as_float(u << 16); }
__device__ inline float bfh(unsigned u) { return __uint_as_float(u & 0xffff0000u); }

// ---- fused pull + pack-emission ----------------------------------------

struct EmitArg {
    const float* nrm;
    unsigned*    hsb;
    const float* W;
    int relu;
    int on;
};

__global__ void pull_emit_kernel(const int* __restrict__ rp, const int* __restrict__ col,
                                 const unsigned* __restrict__ hsb_in, const float* __restrict__ nrm,
                                 const float* __restrict__ b, float* __restrict__ out,
                                 const float* __restrict__ stat_p, int row_lo, int write_h,
                                 EmitArg em0, EmitArg em1) {
    __shared__ float W0[1280];
    __shared__ float W1[1280];
    __shared__ float rowbuf[32][41];
    int t = threadIdx.x;
    if (em0.on) for (int i = t; i < 1280; i += 256) W0[i] = em0.W[i];
    if (em1.on) for (int i = t; i < 1280; i += 256) W1[i] = em1.W[i];
    int tid = blockIdx.x * 256 + t;
    int rr = tid >> 3;
    int r = row_lo + rr;
    int j = tid & 7;
    int hw = j * 2;
    int ea = rp[r], eb = rp[r + 1];
    uint2 sv = *(const uint2*)(hsb_in + (size_t)r * 16 + hw);
    float a0 = bfl(sv.x), a1 = bfh(sv.x), a2 = bfl(sv.y), a3 = bfh(sv.y);
    for (int e = ea; e < eb; e++) {
        int s = col[e];
        uint2 v = *(const uint2*)(hsb_in + (size_t)s * 16 + hw);
        a0 += bfl(v.x); a1 += bfh(v.x); a2 += bfl(v.y); a3 += bfh(v.y);
    }
    float nm = nrm[r];
    int q = j * 4;
    float4 bv = *(const float4*)(b + q);
    float o0 = fmaf(a0, nm, bv.x), o1 = fmaf(a1, nm, bv.y);
    float o2 = fmaf(a2, nm, bv.z), o3 = fmaf(a3, nm, bv.w);
    if (write_h)
        *(float4*)(out + (size_t)r * DYNF + q) = make_float4(o0, o1, o2, o3);
    if (!em0.on && !em1.on) return;
    int lrow = t >> 3;
    rowbuf[lrow][q] = o0; rowbuf[lrow][q + 1] = o1;
    rowbuf[lrow][q + 2] = o2; rowbuf[lrow][q + 3] = o3;
    rowbuf[lrow][32 + j] = stat_p[(size_t)rr * 8 + j];
    __syncthreads();
    if (em0.on) {
        float nmc = em0.nrm[rr];
        float r0 = 0, r1 = 0, r2 = 0, r3 = 0;
#pragma unroll
        for (int k = 0; k < 40; k++) {
            float v = rowbuf[lrow][k];
            if (k < 32 && em0.relu) v = fmaxf(v, 0.f);
            const float* Wp = &W0[k * 32 + q];
            r0 = fmaf(v, Wp[0], r0); r1 = fmaf(v, Wp[1], r1);
            r2 = fmaf(v, Wp[2], r2); r3 = fmaf(v, Wp[3], r3);
        }
        unsigned u0 = bf16rne(r0 * nmc) | (bf16rne(r1 * nmc) << 16);
        unsigned u1 = bf16rne(r2 * nmc) | (bf16rne(r3 * nmc) << 16);
        *(uint2*)(em0.hsb + (size_t)rr * 16 + hw) = make_uint2(u0, u1);
    }
    if (em1.on) {
        float nmc = em1.nrm[rr];
        float r0 = 0, r1 = 0, r2 = 0, r3 = 0;
#pragma unroll
        for (int k = 0; k < 40; k++) {
            float v = rowbuf[lrow][k];
            if (k < 32 && em1.relu) v = fmaxf(v, 0.f);
            const float* Wp = &W1[k * 32 + q];
            r0 = fmaf(v, Wp[0], r0); r1 = fmaf(v, Wp[1], r1);
            r2 = fmaf(v, Wp[2], r2); r3 = fmaf(v, Wp[3], r3);
        }
        unsigned u0 = bf16rne(r0 * nmc) | (bf16rne(r1 * nmc) << 16);
        unsigned u1 = bf16rne(r2 * nmc) | (bf16rne(r3 * nmc) << 16);
        *(uint2*)(em1.hsb + (size_t)rr * 16 + hw) = make_uint2(u0, u1);
    }
}

// ---- up conv: bf16 xs, 8 thr/row edge-parallel pull + emission ---------

__global__ void xsb_kernel(const float* __restrict__ x, const float* __restrict__ nrm,
                           uint2* __restrict__ xsb, int n) {
    int r = blockIdx.x * blockDim.x + threadIdx.x;
    if (r >= n) return;
    float nm = nrm[r];
    float4 v = *(const float4*)(x + (size_t)r * 4);
    xsb[r] = make_uint2(bf16rne(v.x * nm) | (bf16rne(v.y * nm) << 16),
                        bf16rne(v.z * nm) | (bf16rne(v.w * nm) << 16));
}

struct UpEmit {
    const float* n0; const float* n1; const float* n2; const float* n3;
    unsigned* h0; unsigned* h1; unsigned* h2; unsigned* h3;
};

__global__ void pull4mm_emit_kernel(const int* __restrict__ rp0, const int* __restrict__ col,
                                    const uint2* __restrict__ xsb, const float* __restrict__ Wup,
                                    const float* __restrict__ nrm, const float* __restrict__ bup,
                                    const float* __restrict__ Win, const float* __restrict__ Wf,
                                    const float* __restrict__ stat, UpEmit ue) {
    __shared__ float Ws[128];
    __shared__ float bs[32];
    __shared__ float Wa[1280];
    __shared__ float Wb[1280];
    __shared__ float rowbuf[32][41];
    int t = threadIdx.x;
    for (int i = t; i < 128; i += 256) Ws[i] = Wup[i];
    if (t < 32) bs[t] = bup[t];
    for (int i = t; i < 1280; i += 256) { Wa[i] = Win[i]; Wb[i] = Wf[i]; }
    __syncthreads();
    int tid = blockIdx.x * 256 + t;
    int g = tid >> 3;                               // row (grid = NN*8 threads exact)
    int j = t & 7;
    int ea = rp0[g], eb = rp0[g + 1];
    float a0 = 0.f, a1 = 0.f, a2 = 0.f, a3 = 0.f;
    for (int e = ea + j; e < eb; e += 8) {
        uint2 v = xsb[col[e]];
        a0 += bfl(v.x); a1 += bfh(v.x); a2 += bfl(v.y); a3 += bfh(v.y);
    }
#pragma unroll
    for (int m = 1; m < 8; m <<= 1) {
        a0 += __shfl_xor(a0, m);
        a1 += __shfl_xor(a1, m);
        a2 += __shfl_xor(a2, m);
        a3 += __shfl_xor(a3, m);
    }
    uint2 sv = xsb[g];                              // self-loop
    a0 += bfl(sv.x); a1 += bfh(sv.x); a2 += bfl(sv.y); a3 += bfh(sv.y);
    float nm = nrm[g];
    int q = j * 4;
    int lrow = t >> 3;
#pragma unroll
    for (int d = 0; d < 4; d++) {
        float s = a0 * Ws[q + d] + a1 * Ws[32 + q + d] + a2 * Ws[64 + q + d] + a3 * Ws[96 + q + d];
        rowbuf[lrow][q + d] = fmaf(s, nm, bs[q + d]);
    }
    rowbuf[lrow][32 + j] = stat[(size_t)g * 8 + j];
    __syncthreads();
    int l = g >> 16;
    const float* W = (l == 0) ? Wa : Wb;
    const float* nc = (l == 0) ? ue.n0 : (l == 1) ? ue.n1 : (l == 2) ? ue.n2 : ue.n3;
    unsigned* hb = (l == 0) ? ue.h0 : (l == 1) ? ue.h1 : (l == 2) ? ue.h2 : ue.h3;
    float nmc = nc[g];
    float r0 = 0, r1 = 0, r2 = 0, r3 = 0;
#pragma unroll
    for (int k = 0; k < 40; k++) {
        float v = rowbuf[lrow][k];
        const float* Wp = &W[k * 32 + q];
        r0 = fmaf(v, Wp[0], r0); r1 = fmaf(v, Wp[1], r1);
        r2 = fmaf(v, Wp[2], r2); r3 = fmaf(v, Wp[3], r3);
    }
    unsigned u0 = bf16rne(r0 * nmc) | (bf16rne(r1 * nmc) << 16);
    unsigned u1 = bf16rne(r2 * nmc) | (bf16rne(r3 * nmc) << 16);
    *(uint2*)(hb + (size_t)g * 16 + j * 2) = make_uint2(u0, u1);
}

// ---- epilogue ----------------------------------------------------------

__global__ void init_out_kernel(float* out, const float* __restrict__ lin_b) {
    int i = threadIdx.x;
    if (i < GG) out[i] = lin_b[0];
}

__global__ void pool_kernel(const float* __restrict__ h, const int* __restrict__ gids,
                            const float* __restrict__ linW, float* out) {
    __shared__ float part[GG];
    int t = threadIdx.x;
    if (t < GG) part[t] = 0.f;
    __syncthreads();
    int r = blockIdx.x * blockDim.x + t;
    float dotv = 0.f;
    const float4* hp = (const float4*)(h + (size_t)r * DYNF);
#pragma unroll
    for (int q = 0; q < 8; q++) {
        float4 v = hp[q];
        dotv += fmaxf(v.x, 0.f) * linW[q * 4 + 0] + fmaxf(v.y, 0.f) * linW[q * 4 + 1] +
                fmaxf(v.z, 0.f) * linW[q * 4 + 2] + fmaxf(v.w, 0.f) * linW[q * 4 + 3];
    }
    atomicAdd(&part[gids[r]], dotv);
    __syncthreads();
    if (t < GG) unsafeAtomicAdd(&out[t], part[t]);
}

// ------------------------------------------------------------------------

extern "C" void kernel_launch(void* const* d_in, const int* in_sizes, int n_in,
                              void* d_out, int out_size, void* d_ws, size_t ws_size,
                              hipStream_t stream) {
    const float* x     = (const float*)d_in[0];
    const float* stat  = (const float*)d_in[1];
    const int*   e_up  = (const int*)d_in[2];
    const int*   e_in  = (const int*)d_in[3];
    const int*   e_f   = (const int*)d_in[4];
    const int*   e_b   = (const int*)d_in[5];
    const int*   gids  = (const int*)d_in[6];
    const float* W_up  = (const float*)d_in[7];
    const float* b_up  = (const float*)d_in[8];
    const float* W_in  = (const float*)d_in[9];
    const float* b_in  = (const float*)d_in[10];
    const float* W_f   = (const float*)d_in[11];
    const float* b_f   = (const float*)d_in[12];
    const float* W_b   = (const float*)d_in[13];
    const float* b_b   = (const float*)d_in[14];
    const float* lin_W = (const float*)d_in[15];
    const float* lin_b = (const float*)d_in[16];
    float* out = (float*)d_out;

    // ---- workspace carve (~172 MB peak) ----
    float*    norms = (float*)d_ws;                              // NS_TOT
    int*      rp    = (int*)(norms + NS_TOT);                    // NS_TOT+1
    int*      col   = rp + NS_TOT + 1;                           // CO_TOT
    unsigned* H0    = (unsigned*)(col + CO_TOT);                 // conv region base
    float*    h     = (float*)H0;                                // NN*32 f32
    unsigned* hsbp  = H0 + (size_t)NN * DYNF;                    // pack pool: 16*NLK rows *16 u32
    uint2*    xsb   = (uint2*)(hsbp + (size_t)16 * NLK * 16);    // NN uint2 (DEDICATED, no alias)
    unsigned* pairs = H0;                                        // build alias (CO_TOT u32)
    int*      hmat  = (int*)(H0 + CO_TOT);                       // HM
    int*      smat  = hmat + HM;                                 // HM
    int*      part  = smat + HM;                                 // 1120

    // pack-buffer slots (rows of 16 u32); lifetimes verified disjoint:
    unsigned* SA  = hsbp + (size_t)0  * NLK * 16;   // {I0, I3}
    unsigned* SB  = hsbp + (size_t)1  * NLK * 16;   // {I1, i1}
    unsigned* SC  = hsbp + (size_t)2  * NLK * 16;   // {I2, i2}
    unsigned* SD  = hsbp + (size_t)3  * NLK * 16;   // {i0}
    unsigned* F0b = hsbp + (size_t)4  * NLK * 16;   // 2NLK
    unsigned* F1b = hsbp + (size_t)6  * NLK * 16;
    unsigned* F2b = hsbp + (size_t)8  * NLK * 16;
    unsigned* B0b = hsbp + (size_t)10 * NLK * 16;
    unsigned* B1b = hsbp + (size_t)12 * NLK * 16;
    unsigned* B2b = hsbp + (size_t)14 * NLK * 16;

    // ---- build: zero-global-atomic radix partition + LDS-staged grouping ----
    hist_part_kernel<<<NB, 256, 0, stream>>>(e_up, e_in, e_f, e_b, hmat);
    scan1_kernel<<<HM / 1024, 1024, 0, stream>>>(hmat, smat, part, HM);
    scan2_kernel<<<1, 256, 0, stream>>>(part, HM / 1024);
    scan3_kernel<<<cdiv(HM, 256), 256, 0, stream>>>(smat, part, HM);
    scatter_part_kernel<<<NB, 256, 0, stream>>>(e_up, e_in, e_f, e_b, smat, pairs);
    group_kernel<<<NBUCK, 256, 0, stream>>>(pairs, smat, col, rp, norms);

    // ---- up conv: bf16 xs; fused 8-thr/row pull4 + matmul + per-layer pack ----
    xsb_kernel<<<cdiv(NN, 256), 256, 0, stream>>>(x, norms + NS_UP, xsb, NN);
    UpEmit ue;
    ue.n0 = norms + NS_IN(0);
    ue.n1 = norms + NS_F(0);
    ue.n2 = norms + NS_F(1) - NLK;
    ue.n3 = norms + NS_F(2) - 2 * NLK;
    ue.h0 = SA;
    ue.h1 = F0b;
    ue.h2 = F1b - (size_t)NLK * 16;
    ue.h3 = F2b - (size_t)2 * NLK * 16;
    pull4mm_emit_kernel<<<(NN * 8) / 256, 256, 0, stream>>>(rp + NS_UP, col, xsb, W_up,
                                                            norms + NS_UP, b_up, W_in, W_f, stat, ue);

    // ---- fused conv chain: 13 pulls per pass, each emits its consumers' packs ----
    auto EM = [&](const float* n, unsigned* hb, const float* W, int rl) {
        EmitArg e; e.nrm = n; e.hsb = hb; e.W = W; e.relu = rl; e.on = 1; return e;
    };
    EmitArg OFF; OFF.nrm = nullptr; OFF.hsb = nullptr; OFF.W = nullptr; OFF.relu = 0; OFF.on = 0;

    auto P = [&](unsigned* buf, int ns, const float* bias, int gbase, int row_lo,
                 int wh, EmitArg a, EmitArg c) {
        pull_emit_kernel<<<(NLK * 8) / 256, 256, 0, stream>>>(
            rp + ns, col, buf, norms + ns, bias, h + (size_t)gbase * DYNF,
            stat + (size_t)(gbase + row_lo) * STATF, row_lo, wh, a, c);
    };

    for (int p = 0; p < 2; p++) {
        // A-loop
        P(SA, NS_IN(0), b_in, 0, 0, 0,
          EM(norms + NS_F(0), F0b, W_f, 0), EM(norms + NS_B(0), B0b, W_b, 1));        // I0
        P(F0b, NS_F(0), b_f, 0, NLK, 0,
          EM(norms + NS_IN(1), SB, W_in, 0), OFF);                                    // F0
        P(SB, NS_IN(1), b_in, NLK, 0, 0,
          EM(norms + NS_F(1), F1b, W_f, 0), EM(norms + NS_B(1), B1b, W_b, 1));        // I1
        P(F1b, NS_F(1), b_f, NLK, NLK, 0,
          EM(norms + NS_IN(2), SC, W_in, 0), OFF);                                    // F1
        P(SC, NS_IN(2), b_in, 2 * NLK, 0, 0,
          EM(norms + NS_F(2), F2b, W_f, 0), EM(norms + NS_B(2), B2b, W_b, 1));        // I2
        P(F2b, NS_F(2), b_f, 2 * NLK, NLK, 0,
          EM(norms + NS_IN(3), SA, W_in, 0), OFF);                                    // F2
        P(SA, NS_IN(3), b_in, 3 * NLK, 0, (p == 1),
          EM(norms + NS_B(2) + NLK, B2b + (size_t)NLK * 16, W_b, 1),
          p == 0 ? EM(norms + NS_F(2) + NLK, F2b + (size_t)NLK * 16, W_f, 1) : OFF);  // I3
        // B-loop
        P(B2b, NS_B(2), b_b, 2 * NLK, 0, 0,
          EM(norms + NS_IN(2), SC, W_in, 0), OFF);                                    // B2
        P(SC, NS_IN(2), b_in, 2 * NLK, 0, (p == 1),
          EM(norms + NS_B(1) + NLK, B1b + (size_t)NLK * 16, W_b, 0),
          p == 0 ? EM(norms + NS_F(1) + NLK, F1b + (size_t)NLK * 16, W_f, 1) : OFF);  // i2
        P(B1b, NS_B(1), b_b, NLK, 0, 0,
          EM(norms + NS_IN(1), SB, W_in, 0), OFF);                                    // B1
        P(SB, NS_IN(1), b_in, NLK, 0, (p == 1),
          EM(norms + NS_B(0) + NLK, B0b + (size_t)NLK * 16, W_b, 0),
          p == 0 ? EM(norms + NS_F(0) + NLK, F0b + (size_t)NLK * 16, W_f, 1) : OFF);  // i1
        P(B0b, NS_B(0), b_b, 0, 0, 0,
          EM(norms + NS_IN(0), SD, W_in, 0), OFF);                                    // B0
        P(SD, NS_IN(0), b_in, 0, 0, (p == 1),
          p == 0 ? EM(norms + NS_IN(0), SA, W_in, 1) : OFF, OFF);                     // i0
    }

    init_out_kernel<<<1, 64, 0, stream>>>(out, lin_b);
    pool_kernel<<<NN / 256, 256, 0, stream>>>(h, gids, lin_W, out);
}

// Round 14
// 963.482 us; speedup vs baseline: 9.7043x; 1.1292x over previous
//
#include <hip/hip_runtime.h>

#define NLK 65536
#define NN (NLK * 4)        // 262144 nodes
#define DYNF 32
#define STATF 8
#define GG 64
#define EUP 4194304
#define EIN 1048576
#define EFB 1048576

// unified row space: [up: NN][inner: 4*NLK][fwd: 3*2NLK][bwd: 3*2NLK]
#define NS_UP    0
#define NS_IN(l) (NN + (l) * NLK)
#define NS_F(l)  (NN + 4 * NLK + (l) * 2 * NLK)
#define NS_B(l)  (NN + 10 * NLK + (l) * 2 * NLK)
#define NS_TOT   (NN + 16 * NLK)                    // 1,310,720
#define CO_TOT   (EUP + 4 * EIN + 6 * EFB)          // 14,680,064

#define CHUNK 32768                                 // edges per partition block (fat slices)
#define NB    (CO_TOT / CHUNK)                      // 448 partition blocks
#define BROWS 1024                                  // rows per bucket
#define NBUCK (NS_TOT / BROWS)                      // 1280 buckets
#define HM    (NBUCK * NB)                          // 573,440
#define SCAP  20480                                 // LDS sort capacity

static inline int cdiv(long a, int b) { return (int)((a + b - 1) / b); }

// ---- which list does partition block b cover? --------------------------
__device__ inline void cdecode(int b, const int* e_up, const int* e_in,
                               const int* e_f, const int* e_b,
                               const int*& srcp, const int*& dstp, int& ns, int& e0) {
    if (b < EUP / CHUNK) { srcp = e_up; dstp = e_up + EUP; ns = NS_UP; e0 = b * CHUNK; return; }
    int t = b - EUP / CHUNK;
    int list = t >> 5;                               // 32 blocks per small list
    e0 = (t & 31) * CHUNK;
    if (list < 4) {
        srcp = e_in + (size_t)(2 * list) * EIN; dstp = srcp + EIN; ns = NS_IN(list);
    } else if (list < 7) {
        int l = list - 4;
        srcp = e_f + (size_t)(2 * l) * EFB; dstp = srcp + EFB; ns = NS_F(l);
    } else {
        int l = list - 7;
        srcp = e_b + (size_t)(2 * l) * EFB; dstp = srcp + EFB; ns = NS_B(l);
    }
}

// ---- pass 1: per-block LDS bucket histogram (1024 threads) -------------
__global__ void hist_part_kernel(const int* __restrict__ e_up, const int* __restrict__ e_in,
                                 const int* __restrict__ e_f, const int* __restrict__ e_b,
                                 int* __restrict__ hmat) {
    __shared__ int lh[NBUCK];
    for (int k = threadIdx.x; k < NBUCK; k += 1024) lh[k] = 0;
    __syncthreads();
    const int *srcp, *dstp; int ns, e0;
    cdecode(blockIdx.x, e_up, e_in, e_f, e_b, srcp, dstp, ns, e0);
    for (int j = 0; j < CHUNK / 1024; j++) {
        int g = ns + dstp[e0 + j * 1024 + threadIdx.x];
        atomicAdd(&lh[g >> 10], 1);
    }
    __syncthreads();
    for (int k = threadIdx.x; k < NBUCK; k += 1024)
        hmat[(size_t)k * NB + blockIdx.x] = lh[k];
}

// ---- pass 2: scatter into per-(bucket,block) slices (1024 threads) -----
__global__ void scatter_part_kernel(const int* __restrict__ e_up, const int* __restrict__ e_in,
                                    const int* __restrict__ e_f, const int* __restrict__ e_b,
                                    const int* __restrict__ smat, unsigned* __restrict__ pairs) {
    __shared__ int cur[NBUCK];
    const int *srcp, *dstp; int ns, e0;
    cdecode(blockIdx.x, e_up, e_in, e_f, e_b, srcp, dstp, ns, e0);
    for (int k = threadIdx.x; k < NBUCK; k += 1024)
        cur[k] = smat[(size_t)k * NB + blockIdx.x];
    __syncthreads();
    for (int j = 0; j < CHUNK / 1024; j++) {
        int el = e0 + j * 1024 + threadIdx.x;
        int g = ns + dstp[el];
        int s = srcp[el];
        int pos = atomicAdd(&cur[g >> 10], 1);
        pairs[pos] = ((unsigned)s << 10) | (unsigned)(g & (BROWS - 1));
    }
}

// ---- pass 3: per-bucket group; LDS-staged sort -> sequential col (512 thr)
__global__ void group_kernel(const unsigned* __restrict__ pairs, const int* __restrict__ smat,
                             int* __restrict__ col, int* __restrict__ rp,
                             float* __restrict__ norms) {
    __shared__ int srt[SCAP];
    __shared__ int lcnt[BROWS];
    __shared__ int roff[BROWS];
    __shared__ int lcur[BROWS];
    __shared__ int ssum[512];
    int k = blockIdx.x;
    int t = threadIdx.x;
    int base = smat[(size_t)k * NB];
    int end  = (k + 1 < NBUCK) ? smat[(size_t)(k + 1) * NB] : CO_TOT;
    int nb = end - base;
    for (int j = t; j < BROWS; j += 512) { lcnt[j] = 0; lcur[j] = 0; }
    __syncthreads();
    for (int i = base + t; i < end; i += 512)
        atomicAdd(&lcnt[pairs[i] & (BROWS - 1)], 1);
    __syncthreads();
    constexpr int RPT = BROWS / 512;                 // 2
    int a[RPT];
    int gsum = 0;
#pragma unroll
    for (int j = 0; j < RPT; j++) { a[j] = lcnt[RPT * t + j]; gsum += a[j]; }
    ssum[t] = gsum;
    __syncthreads();
    for (int off = 1; off < 512; off <<= 1) {
        int u = (t >= off) ? ssum[t - off] : 0;
        __syncthreads();
        ssum[t] += u;
        __syncthreads();
    }
    int run = ssum[t] - gsum;
    int row0 = k * BROWS + RPT * t;
#pragma unroll
    for (int j = 0; j < RPT; j++) {
        roff[RPT * t + j] = run;
        rp[row0 + j] = base + run;
        norms[row0 + j] = rsqrtf((float)(a[j] + 1));
        run += a[j];
    }
    if (k == 0 && t == 0) rp[NS_TOT] = CO_TOT;
    __syncthreads();
    if (nb <= SCAP) {
        for (int i = base + t; i < end; i += 512) {
            unsigned p = pairs[i];
            int rl = p & (BROWS - 1);
            int pos = roff[rl] + atomicAdd(&lcur[rl], 1);
            srt[pos] = (int)(p >> 10);
        }
        __syncthreads();
        for (int j = t; j < nb; j += 512)
            col[base + j] = srt[j];
    } else {
        for (int i = base + t; i < end; i += 512) {
            unsigned p = pairs[i];
            int rl = p & (BROWS - 1);
            int pos = base + roff[rl] + atomicAdd(&lcur[rl], 1);
            col[pos] = (int)(p >> 10);
        }
    }
}

// ---- global scan ------------------------------------------------------

__global__ void scan1_kernel(const int* __restrict__ cnt, int* __restrict__ rp,
                             int* __restrict__ part, int n) {
    __shared__ int sh[1024];
    int t = threadIdx.x;
    int i = blockIdx.x * 1024 + t;
    int v = (i < n) ? cnt[i] : 0;
    sh[t] = v;
    __syncthreads();
    for (int off = 1; off < 1024; off <<= 1) {
        int u = (t >= off) ? sh[t - off] : 0;
        __syncthreads();
        sh[t] += u;
        __syncthreads();
    }
    if (i < n) rp[i] = sh[t] - v;
    if (t == 1023) part[blockIdx.x] = sh[1023];
}

__global__ void scan2_kernel(int* part, int m) {
    __shared__ int sh[256];
    __shared__ int carry;
    int t = threadIdx.x;
    if (t == 0) carry = 0;
    __syncthreads();
    for (int base = 0; base < m; base += 256) {
        int i = base + t;
        int v = (i < m) ? part[i] : 0;
        sh[t] = v;
        __syncthreads();
        for (int off = 1; off < 256; off <<= 1) {
            int u = (t >= off) ? sh[t - off] : 0;
            __syncthreads();
            sh[t] += u;
            __syncthreads();
        }
        if (i < m) part[i] = sh[t] - v + carry;
        __syncthreads();
        if (t == 255) carry += sh[255];
        __syncthreads();
    }
}

__global__ void scan3_kernel(int* __restrict__ rp, const int* __restrict__ part, int n) {
    int i = blockIdx.x * blockDim.x + threadIdx.x;
    if (i < n) rp[i] += part[i >> 10];
}

// ---- bf16 helpers ------------------------------------------------------

__device__ inline unsigned bf16rne(float f) {
    unsigned u = __float_as_uint(f);
    return (u + 0x7fffu + ((u >> 16) & 1u)) >> 16;
}
__device__ inline float bfl(unsigned u) { return __uint_as_float(u << 16); }
__device__ inline float bfh(unsigned u) { return __uint_as_float(u & 0xffff0000u); }

// ---- fused pull + pack-emission ----------------------------------------

struct EmitArg {
    const float* nrm;
    unsigned*    hsb;
    const float* W;
    int relu;
    int on;
};

__global__ void pull_emit_kernel(const int* __restrict__ rp, const int* __restrict__ col,
                                 const unsigned* __restrict__ hsb_in, const float* __restrict__ nrm,
                                 const float* __restrict__ b, float* __restrict__ out,
                                 const float* __restrict__ stat_p, int row_lo, int write_h,
                                 EmitArg em0, EmitArg em1) {
    __shared__ float W0[1280];
    __shared__ float W1[1280];
    __shared__ float rowbuf[32][41];
    int t = threadIdx.x;
    if (em0.on) for (int i = t; i < 1280; i += 256) W0[i] = em0.W[i];
    if (em1.on) for (int i = t; i < 1280; i += 256) W1[i] = em1.W[i];
    int tid = blockIdx.x * 256 + t;
    int rr = tid >> 3;
    int r = row_lo + rr;
    int j = tid & 7;
    int hw = j * 2;
    int ea = rp[r], eb = rp[r + 1];
    uint2 sv = *(const uint2*)(hsb_in + (size_t)r * 16 + hw);
    float a0 = bfl(sv.x), a1 = bfh(sv.x), a2 = bfl(sv.y), a3 = bfh(sv.y);
    for (int e = ea; e < eb; e++) {
        int s = col[e];
        uint2 v = *(const uint2*)(hsb_in + (size_t)s * 16 + hw);
        a0 += bfl(v.x); a1 += bfh(v.x); a2 += bfl(v.y); a3 += bfh(v.y);
    }
    float nm = nrm[r];
    int q = j * 4;
    float4 bv = *(const float4*)(b + q);
    float o0 = fmaf(a0, nm, bv.x), o1 = fmaf(a1, nm, bv.y);
    float o2 = fmaf(a2, nm, bv.z), o3 = fmaf(a3, nm, bv.w);
    if (write_h)
        *(float4*)(out + (size_t)r * DYNF + q) = make_float4(o0, o1, o2, o3);
    if (!em0.on && !em1.on) return;
    int lrow = t >> 3;
    rowbuf[lrow][q] = o0; rowbuf[lrow][q + 1] = o1;
    rowbuf[lrow][q + 2] = o2; rowbuf[lrow][q + 3] = o3;
    rowbuf[lrow][32 + j] = stat_p[(size_t)rr * 8 + j];
    __syncthreads();
    if (em0.on) {
        float nmc = em0.nrm[rr];
        float r0 = 0, r1 = 0, r2 = 0, r3 = 0;
#pragma unroll
        for (int k = 0; k < 40; k++) {
            float v = rowbuf[lrow][k];
            if (k < 32 && em0.relu) v = fmaxf(v, 0.f);
            const float* Wp = &W0[k * 32 + q];
            r0 = fmaf(v, Wp[0], r0); r1 = fmaf(v, Wp[1], r1);
            r2 = fmaf(v, Wp[2], r2); r3 = fmaf(v, Wp[3], r3);
        }
        unsigned u0 = bf16rne(r0 * nmc) | (bf16rne(r1 * nmc) << 16);
        unsigned u1 = bf16rne(r2 * nmc) | (bf16rne(r3 * nmc) << 16);
        *(uint2*)(em0.hsb + (size_t)rr * 16 + hw) = make_uint2(u0, u1);
    }
    if (em1.on) {
        float nmc = em1.nrm[rr];
        float r0 = 0, r1 = 0, r2 = 0, r3 = 0;
#pragma unroll
        for (int k = 0; k < 40; k++) {
            float v = rowbuf[lrow][k];
            if (k < 32 && em1.relu) v = fmaxf(v, 0.f);
            const float* Wp = &W1[k * 32 + q];
            r0 = fmaf(v, Wp[0], r0); r1 = fmaf(v, Wp[1], r1);
            r2 = fmaf(v, Wp[2], r2); r3 = fmaf(v, Wp[3], r3);
        }
        unsigned u0 = bf16rne(r0 * nmc) | (bf16rne(r1 * nmc) << 16);
        unsigned u1 = bf16rne(r2 * nmc) | (bf16rne(r3 * nmc) << 16);
        *(uint2*)(em1.hsb + (size_t)rr * 16 + hw) = make_uint2(u0, u1);
    }
}

// ---- up conv: bf16 xs, 8 thr/row edge-parallel pull + emission ---------

__global__ void xsb_kernel(const float* __restrict__ x, const float* __restrict__ nrm,
                           uint2* __restrict__ xsb, int n) {
    int r = blockIdx.x * blockDim.x + threadIdx.x;
    if (r >= n) return;
    float nm = nrm[r];
    float4 v = *(const float4*)(x + (size_t)r * 4);
    xsb[r] = make_uint2(bf16rne(v.x * nm) | (bf16rne(v.y * nm) << 16),
                        bf16rne(v.z * nm) | (bf16rne(v.w * nm) << 16));
}

struct UpEmit {
    const float* n0; const float* n1; const float* n2; const float* n3;
    unsigned* h0; unsigned* h1; unsigned* h2; unsigned* h3;
};

__global__ void pull4mm_emit_kernel(const int* __restrict__ rp0, const int* __restrict__ col,
                                    const uint2* __restrict__ xsb, const float* __restrict__ Wup,
                                    const float* __restrict__ nrm, const float* __restrict__ bup,
                                    const float* __restrict__ Win, const float* __restrict__ Wf,
                                    const float* __restrict__ stat, UpEmit ue) {
    __shared__ float Ws[128];
    __shared__ float bs[32];
    __shared__ float Wa[1280];
    __shared__ float Wb[1280];
    __shared__ float rowbuf[32][41];
    int t = threadIdx.x;
    for (int i = t; i < 128; i += 256) Ws[i] = Wup[i];
    if (t < 32) bs[t] = bup[t];
    for (int i = t; i < 1280; i += 256) { Wa[i] = Win[i]; Wb[i] = Wf[i]; }
    __syncthreads();
    int tid = blockIdx.x * 256 + t;
    int g = tid >> 3;
    int j = t & 7;
    int ea = rp0[g], eb = rp0[g + 1];
    float a0 = 0.f, a1 = 0.f, a2 = 0.f, a3 = 0.f;
    for (int e = ea + j; e < eb; e += 8) {
        uint2 v = xsb[col[e]];
        a0 += bfl(v.x); a1 += bfh(v.x); a2 += bfl(v.y); a3 += bfh(v.y);
    }
#pragma unroll
    for (int m = 1; m < 8; m <<= 1) {
        a0 += __shfl_xor(a0, m);
        a1 += __shfl_xor(a1, m);
        a2 += __shfl_xor(a2, m);
        a3 += __shfl_xor(a3, m);
    }
    uint2 sv = xsb[g];
    a0 += bfl(sv.x); a1 += bfh(sv.x); a2 += bfl(sv.y); a3 += bfh(sv.y);
    float nm = nrm[g];
    int q = j * 4;
    int lrow = t >> 3;
#pragma unroll
    for (int d = 0; d < 4; d++) {
        float s = a0 * Ws[q + d] + a1 * Ws[32 + q + d] + a2 * Ws[64 + q + d] + a3 * Ws[96 + q + d];
        rowbuf[lrow][q + d] = fmaf(s, nm, bs[q + d]);
    }
    rowbuf[lrow][32 + j] = stat[(size_t)g * 8 + j];
    __syncthreads();
    int l = g >> 16;
    const float* W = (l == 0) ? Wa : Wb;
    const float* nc = (l == 0) ? ue.n0 : (l == 1) ? ue.n1 : (l == 2) ? ue.n2 : ue.n3;
    unsigned* hb = (l == 0) ? ue.h0 : (l == 1) ? ue.h1 : (l == 2) ? ue.h2 : ue.h3;
    float nmc = nc[g];
    float r0 = 0, r1 = 0, r2 = 0, r3 = 0;
#pragma unroll
    for (int k = 0; k < 40; k++) {
        float v = rowbuf[lrow][k];
        const float* Wp = &W[k * 32 + q];
        r0 = fmaf(v, Wp[0], r0); r1 = fmaf(v, Wp[1], r1);
        r2 = fmaf(v, Wp[2], r2); r3 = fmaf(v, Wp[3], r3);
    }
    unsigned u0 = bf16rne(r0 * nmc) | (bf16rne(r1 * nmc) << 16);
    unsigned u1 = bf16rne(r2 * nmc) | (bf16rne(r3 * nmc) << 16);
    *(uint2*)(hb + (size_t)g * 16 + j * 2) = make_uint2(u0, u1);
}

// ---- epilogue ----------------------------------------------------------

__global__ void init_out_kernel(float* out, const float* __restrict__ lin_b) {
    int i = threadIdx.x;
    if (i < GG) out[i] = lin_b[0];
}

__global__ void pool_kernel(const float* __restrict__ h, const int* __restrict__ gids,
                            const float* __restrict__ linW, float* out) {
    __shared__ float part[GG];
    int t = threadIdx.x;
    if (t < GG) part[t] = 0.f;
    __syncthreads();
    int r = blockIdx.x * blockDim.x + t;
    float dotv = 0.f;
    const float4* hp = (const float4*)(h + (size_t)r * DYNF);
#pragma unroll
    for (int q = 0; q < 8; q++) {
        float4 v = hp[q];
        dotv += fmaxf(v.x, 0.f) * linW[q * 4 + 0] + fmaxf(v.y, 0.f) * linW[q * 4 + 1] +
                fmaxf(v.z, 0.f) * linW[q * 4 + 2] + fmaxf(v.w, 0.f) * linW[q * 4 + 3];
    }
    atomicAdd(&part[gids[r]], dotv);
    __syncthreads();
    if (t < GG) unsafeAtomicAdd(&out[t], part[t]);
}

// ------------------------------------------------------------------------

extern "C" void kernel_launch(void* const* d_in, const int* in_sizes, int n_in,
                              void* d_out, int out_size, void* d_ws, size_t ws_size,
                              hipStream_t stream) {
    const float* x     = (const float*)d_in[0];
    const float* stat  = (const float*)d_in[1];
    const int*   e_up  = (const int*)d_in[2];
    const int*   e_in  = (const int*)d_in[3];
    const int*   e_f   = (const int*)d_in[4];
    const int*   e_b   = (const int*)d_in[5];
    const int*   gids  = (const int*)d_in[6];
    const float* W_up  = (const float*)d_in[7];
    const float* b_up  = (const float*)d_in[8];
    const float* W_in  = (const float*)d_in[9];
    const float* b_in  = (const float*)d_in[10];
    const float* W_f   = (const float*)d_in[11];
    const float* b_f   = (const float*)d_in[12];
    const float* W_b   = (const float*)d_in[13];
    const float* b_b   = (const float*)d_in[14];
    const float* lin_W = (const float*)d_in[15];
    const float* lin_b = (const float*)d_in[16];
    float* out = (float*)d_out;

    // ---- workspace carve (~172 MB peak) ----
    float*    norms = (float*)d_ws;                              // NS_TOT
    int*      rp    = (int*)(norms + NS_TOT);                    // NS_TOT+1
    int*      col   = rp + NS_TOT + 1;                           // CO_TOT
    unsigned* H0    = (unsigned*)(col + CO_TOT);                 // conv region base
    float*    h     = (float*)H0;                                // NN*32 f32
    unsigned* hsbp  = H0 + (size_t)NN * DYNF;                    // pack pool: 16*NLK rows *16 u32
    uint2*    xsb   = (uint2*)(hsbp + (size_t)16 * NLK * 16);    // NN uint2 (dedicated)
    unsigned* pairs = H0;                                        // build alias (CO_TOT u32)
    int*      hmat  = (int*)(H0 + CO_TOT);                       // HM
    int*      smat  = hmat + HM;                                 // HM
    int*      part  = smat + HM;                                 // >= 560

    // pack-buffer slots (rows of 16 u32); lifetimes verified disjoint:
    unsigned* SA  = hsbp + (size_t)0  * NLK * 16;   // {I0, I3}
    unsigned* SB  = hsbp + (size_t)1  * NLK * 16;   // {I1, i1}
    unsigned* SC  = hsbp + (size_t)2  * NLK * 16;   // {I2, i2}
    unsigned* SD  = hsbp + (size_t)3  * NLK * 16;   // {i0}
    unsigned* F0b = hsbp + (size_t)4  * NLK * 16;   // 2NLK
    unsigned* F1b = hsbp + (size_t)6  * NLK * 16;
    unsigned* F2b = hsbp + (size_t)8  * NLK * 16;
    unsigned* B0b = hsbp + (size_t)10 * NLK * 16;
    unsigned* B1b = hsbp + (size_t)12 * NLK * 16;
    unsigned* B2b = hsbp + (size_t)14 * NLK * 16;

    // ---- build: zero-global-atomic radix partition + LDS-staged grouping ----
    hist_part_kernel<<<NB, 1024, 0, stream>>>(e_up, e_in, e_f, e_b, hmat);
    scan1_kernel<<<HM / 1024, 1024, 0, stream>>>(hmat, smat, part, HM);
    scan2_kernel<<<1, 256, 0, stream>>>(part, HM / 1024);
    scan3_kernel<<<cdiv(HM, 256), 256, 0, stream>>>(smat, part, HM);
    scatter_part_kernel<<<NB, 1024, 0, stream>>>(e_up, e_in, e_f, e_b, smat, pairs);
    group_kernel<<<NBUCK, 512, 0, stream>>>(pairs, smat, col, rp, norms);

    // ---- up conv: bf16 xs; fused 8-thr/row pull4 + matmul + per-layer pack ----
    xsb_kernel<<<cdiv(NN, 256), 256, 0, stream>>>(x, norms + NS_UP, xsb, NN);
    UpEmit ue;
    ue.n0 = norms + NS_IN(0);
    ue.n1 = norms + NS_F(0);
    ue.n2 = norms + NS_F(1) - NLK;
    ue.n3 = norms + NS_F(2) - 2 * NLK;
    ue.h0 = SA;
    ue.h1 = F0b;
    ue.h2 = F1b - (size_t)NLK * 16;
    ue.h3 = F2b - (size_t)2 * NLK * 16;
    pull4mm_emit_kernel<<<(NN * 8) / 256, 256, 0, stream>>>(rp + NS_UP, col, xsb, W_up,
                                                            norms + NS_UP, b_up, W_in, W_f, stat, ue);

    // ---- fused conv chain: 13 pulls per pass, each emits its consumers' packs ----
    auto EM = [&](const float* n, unsigned* hb, const float* W, int rl) {
        EmitArg e; e.nrm = n; e.hsb = hb; e.W = W; e.relu = rl; e.on = 1; return e;
    };
    EmitArg OFF; OFF.nrm = nullptr; OFF.hsb = nullptr; OFF.W = nullptr; OFF.relu = 0; OFF.on = 0;

    auto P = [&](unsigned* buf, int ns, const float* bias, int gbase, int row_lo,
                 int wh, EmitArg a, EmitArg c) {
        pull_emit_kernel<<<(NLK * 8) / 256, 256, 0, stream>>>(
            rp + ns, col, buf, norms + ns, bias, h + (size_t)gbase * DYNF,
            stat + (size_t)(gbase + row_lo) * STATF, row_lo, wh, a, c);
    };

    for (int p = 0; p < 2; p++) {
        // A-loop
        P(SA, NS_IN(0), b_in, 0, 0, 0,
          EM(norms + NS_F(0), F0b, W_f, 0), EM(norms + NS_B(0), B0b, W_b, 1));        // I0
        P(F0b, NS_F(0), b_f, 0, NLK, 0,
          EM(norms + NS_IN(1), SB, W_in, 0), OFF);                                    // F0
        P(SB, NS_IN(1), b_in, NLK, 0, 0,
          EM(norms + NS_F(1), F1b, W_f, 0), EM(norms + NS_B(1), B1b, W_b, 1));        // I1
        P(F1b, NS_F(1), b_f, NLK, NLK, 0,
          EM(norms + NS_IN(2), SC, W_in, 0), OFF);                                    // F1
        P(SC, NS_IN(2), b_in, 2 * NLK, 0, 0,
          EM(norms + NS_F(2), F2b, W_f, 0), EM(norms + NS_B(2), B2b, W_b, 1));        // I2
        P(F2b, NS_F(2), b_f, 2 * NLK, NLK, 0,
          EM(norms + NS_IN(3), SA, W_in, 0), OFF);                                    // F2
        P(SA, NS_IN(3), b_in, 3 * NLK, 0, (p == 1),
          EM(norms + NS_B(2) + NLK, B2b + (size_t)NLK * 16, W_b, 1),
          p == 0 ? EM(norms + NS_F(2) + NLK, F2b + (size_t)NLK * 16, W_f, 1) : OFF);  // I3
        // B-loop
        P(B2b, NS_B(2), b_b, 2 * NLK, 0, 0,
          EM(norms + NS_IN(2), SC, W_in, 0), OFF);                                    // B2
        P(SC, NS_IN(2), b_in, 2 * NLK, 0, (p == 1),
          EM(norms + NS_B(1) + NLK, B1b + (size_t)NLK * 16, W_b, 0),
          p == 0 ? EM(norms + NS_F(1) + NLK, F1b + (size_t)NLK * 16, W_f, 1) : OFF);  // i2
        P(B1b, NS_B(1), b_b, NLK, 0, 0,
          EM(norms + NS_IN(1), SB, W_in, 0), OFF);                                    // B1
        P(SB, NS_IN(1), b_in, NLK, 0, (p == 1),
          EM(norms + NS_B(0) + NLK, B0b + (size_t)NLK * 16, W_b, 0),
          p == 0 ? EM(norms + NS_F(0) + NLK, F0b + (size_t)NLK * 16, W_f, 1) : OFF);  // i1
        P(B0b, NS_B(0), b_b, 0, 0, 0,
          EM(norms + NS_IN(0), SD, W_in, 0), OFF);                                    // B0
        P(SD, NS_IN(0), b_in, 0, 0, (p == 1),
          p == 0 ? EM(norms + NS_IN(0), SA, W_in, 1) : OFF, OFF);                     // i0
    }

    init_out_kernel<<<1, 64, 0, stream>>>(out, lin_b);
    pool_kernel<<<NN / 256, 256, 0, stream>>>(h, gids, lin_W, out);
}